// Round 1
// baseline (482.049 us; speedup 1.0000x reference)
//
#include <hip/hip_runtime.h>

#define D 128

// ---------------- CSR build ----------------

__global__ void count_kernel(const int* __restrict__ dst, int* __restrict__ cnt, int E) {
    int e = blockIdx.x * blockDim.x + threadIdx.x;
    if (e < E) atomicAdd(&cnt[dst[e]], 1);
}

__global__ void dinv_kernel(const int* __restrict__ cnt, float* __restrict__ dinv, int n) {
    int v = blockIdx.x * blockDim.x + threadIdx.x;
    if (v < n) dinv[v] = rsqrtf(1.0f + (float)cnt[v]);   // deg = in-count + self loop
}

__global__ __launch_bounds__(1024) void scan_kernel(const int* __restrict__ cnt,
                                                    int* __restrict__ rowstart,
                                                    int* __restrict__ cursor, int n) {
    __shared__ int sums[1024];
    int t = threadIdx.x;
    int chunk = (n + 1023) >> 10;
    int lo = t * chunk;
    int hi = min(lo + chunk, n);
    int s = 0;
    for (int i = lo; i < hi; i++) s += cnt[i];
    sums[t] = s;
    __syncthreads();
    for (int off = 1; off < 1024; off <<= 1) {
        int add = (t >= off) ? sums[t - off] : 0;
        __syncthreads();
        sums[t] += add;
        __syncthreads();
    }
    int excl = (t == 0) ? 0 : sums[t - 1];
    for (int i = lo; i < hi; i++) {
        rowstart[i] = excl;
        cursor[i] = excl;
        excl += cnt[i];
    }
    if (t == 1023) rowstart[n] = sums[1023];
}

__global__ void fill_kernel(const int* __restrict__ src, const int* __restrict__ dst,
                            int* __restrict__ cursor, int* __restrict__ csr_src, int E) {
    int e = blockIdx.x * blockDim.x + threadIdx.x;
    if (e < E) {
        int d = dst[e];
        int pos = atomicAdd(&cursor[d], 1);
        csr_src[pos] = src[e];
    }
}

// ---------------- GEMM: Y[M,128] = X[M,128] @ W[128,128] ----------------
// Persistent blocks: W staged to LDS once per block, grid-stride over 16-row tiles.

__global__ __launch_bounds__(256, 2) void gemm_kernel(const float* __restrict__ X,
                                                      const float* __restrict__ Wg,
                                                      float* __restrict__ Y, int M) {
    __shared__ float Ws[D * D];
    __shared__ float xs[16][132];   // +4 pad: breaks bank aliasing across rows
    int t = threadIdx.x;
    for (int i = t * 4; i < D * D; i += 256 * 4) {
        *(float4*)&Ws[i] = *(const float4*)&Wg[i];
    }
    int ntiles = M >> 4;            // M = 50000 is divisible by 16
    int r = t >> 4;
    int c0 = (t & 15) * 8;
    for (int tile = blockIdx.x; tile < ntiles; tile += gridDim.x) {
        int row0 = tile << 4;
        __syncthreads();            // covers W staging (iter 0) + xs reuse
        {
            int idx = t * 8;
            int rr = idx >> 7, cc = idx & 127;
            const float* px = &X[(size_t)(row0 + rr) * D + cc];
            float4 a = *(const float4*)px;
            float4 b = *(const float4*)(px + 4);
            *(float4*)&xs[rr][cc] = a;
            *(float4*)&xs[rr][cc + 4] = b;
        }
        __syncthreads();
        float acc[8];
#pragma unroll
        for (int j = 0; j < 8; j++) acc[j] = 0.f;
#pragma unroll 4
        for (int k = 0; k < D; k++) {
            float a = xs[r][k];
            float4 w0 = *(float4*)&Ws[k * D + c0];
            float4 w1 = *(float4*)&Ws[k * D + c0 + 4];
            acc[0] += a * w0.x; acc[1] += a * w0.y;
            acc[2] += a * w0.z; acc[3] += a * w0.w;
            acc[4] += a * w1.x; acc[5] += a * w1.y;
            acc[6] += a * w1.z; acc[7] += a * w1.w;
        }
        float* py = &Y[(size_t)(row0 + r) * D + c0];
        float4 o0 = {acc[0], acc[1], acc[2], acc[3]};
        float4 o1 = {acc[4], acc[5], acc[6], acc[7]};
        *(float4*)py = o0;
        *(float4*)(py + 4) = o1;
    }
}

// ---------------- Aggregation: one wave per node, 2 floats/lane ----------------
// out[v] = bias + dinv[v]^2 * xw[v] + sum_{u in N_in(v)} dinv[u]*dinv[v] * xw[u]
// RELU: apply relu before store. POOL: only is_neighbor nodes; atomicAdd into pooled.

template <int RELU, int POOL>
__global__ __launch_bounds__(256) void agg_kernel(const float* __restrict__ XW,
                                                  const float* __restrict__ bias,
                                                  const float* __restrict__ dinv,
                                                  const int* __restrict__ rowstart,
                                                  const int* __restrict__ csr_src,
                                                  const float* __restrict__ is_n,
                                                  const int* __restrict__ batch,
                                                  float* __restrict__ out, int n) {
    int wid = threadIdx.x >> 6;
    int lane = threadIdx.x & 63;
    int v = blockIdx.x * 4 + wid;
    if (v >= n) return;
    float w_is = 0.f;
    if (POOL) {
        w_is = is_n[v];
        if (w_is == 0.f) return;    // wave-uniform: whole wave exits
    }
    float dv = dinv[v];
    int c = lane * 2;
    float2 bb = *(const float2*)&bias[c];
    float2 xv = *(const float2*)&XW[(size_t)v * D + c];
    float sv = dv * dv;
    float2 acc = {bb.x + sv * xv.x, bb.y + sv * xv.y};
    int e0 = rowstart[v], e1 = rowstart[v + 1];
    int e = e0;
    for (; e + 1 < e1; e += 2) {
        int u0 = csr_src[e];
        int u1 = csr_src[e + 1];
        float n0 = dinv[u0] * dv;
        float n1 = dinv[u1] * dv;
        float2 x0 = *(const float2*)&XW[(size_t)u0 * D + c];
        float2 x1 = *(const float2*)&XW[(size_t)u1 * D + c];
        acc.x += n0 * x0.x + n1 * x1.x;
        acc.y += n0 * x0.y + n1 * x1.y;
    }
    if (e < e1) {
        int u = csr_src[e];
        float nv = dinv[u] * dv;
        float2 xu = *(const float2*)&XW[(size_t)u * D + c];
        acc.x += nv * xu.x;
        acc.y += nv * xu.y;
    }
    if (RELU) {
        acc.x = fmaxf(acc.x, 0.f);
        acc.y = fmaxf(acc.y, 0.f);
    }
    if (POOL) {
        int g = batch[v];
        float s = 0.5f * w_is;
        atomicAdd(&out[(size_t)g * D + c], acc.x * s);
        atomicAdd(&out[(size_t)g * D + c + 1], acc.y * s);
    } else {
        *(float2*)&out[(size_t)v * D + c] = acc;
    }
}

// ---------------- launch ----------------

extern "C" void kernel_launch(void* const* d_in, const int* in_sizes, int n_in,
                              void* d_out, int out_size, void* d_ws, size_t ws_size,
                              hipStream_t stream) {
    const float* x    = (const float*)d_in[0];
    const int*   edge = (const int*)d_in[1];
    const float* is_n = (const float*)d_in[2];
    const int*   batch = (const int*)d_in[3];
    const float* W1 = (const float*)d_in[4];
    const float* b1 = (const float*)d_in[5];
    const float* W2 = (const float*)d_in[6];
    const float* b2 = (const float*)d_in[7];
    const float* W3 = (const float*)d_in[8];
    const float* b3 = (const float*)d_in[9];
    float* out = (float*)d_out;

    int n = in_sizes[0] / D;       // 50000
    int E = in_sizes[1] / 2;       // 600000
    const int* esrc = edge;
    const int* edst = edge + E;

    char* p = (char*)d_ws;
    float* xw = (float*)p;       p += (size_t)n * D * sizeof(float);
    float* h  = (float*)p;       p += (size_t)n * D * sizeof(float);
    float* dinv = (float*)p;     p += (size_t)n * sizeof(float);
    int* cnt = (int*)p;          p += (size_t)n * sizeof(int);
    int* rowstart = (int*)p;     p += (size_t)(n + 1) * sizeof(int);
    int* cursor = (int*)p;       p += (size_t)n * sizeof(int);
    int* csr_src = (int*)p;      p += (size_t)E * sizeof(int);

    hipMemsetAsync(cnt, 0, (size_t)n * sizeof(int), stream);
    count_kernel<<<(E + 255) / 256, 256, 0, stream>>>(edst, cnt, E);
    dinv_kernel<<<(n + 255) / 256, 256, 0, stream>>>(cnt, dinv, n);
    scan_kernel<<<1, 1024, 0, stream>>>(cnt, rowstart, cursor, n);
    fill_kernel<<<(E + 255) / 256, 256, 0, stream>>>(esrc, edst, cursor, csr_src, E);

    const int gblocks = 512;   // persistent: 2 blocks/CU, W staged once per block
    int ablocks = (n + 3) / 4;

    // Layer 1
    gemm_kernel<<<gblocks, 256, 0, stream>>>(x, W1, xw, n);
    agg_kernel<1, 0><<<ablocks, 256, 0, stream>>>(xw, b1, dinv, rowstart, csr_src,
                                                  nullptr, nullptr, h, n);
    // Layer 2
    gemm_kernel<<<gblocks, 256, 0, stream>>>(h, W2, xw, n);
    agg_kernel<1, 0><<<ablocks, 256, 0, stream>>>(xw, b2, dinv, rowstart, csr_src,
                                                  nullptr, nullptr, h, n);
    // Layer 3: only is_neighbor nodes matter for the pooled output
    gemm_kernel<<<gblocks, 256, 0, stream>>>(h, W3, xw, n);
    hipMemsetAsync(d_out, 0, (size_t)out_size * sizeof(float), stream);
    agg_kernel<0, 1><<<ablocks, 256, 0, stream>>>(xw, b3, dinv, rowstart, csr_src,
                                                  is_n, batch, out, n);
}

// Round 2
// 379.195 us; speedup vs baseline: 1.2712x; 1.2712x over previous
//
#include <hip/hip_runtime.h>

#define D 128

// ---------------- CSR build ----------------

__global__ void count_kernel(const int* __restrict__ dst, int* __restrict__ cnt, int E) {
    int e = blockIdx.x * blockDim.x + threadIdx.x;
    if (e < E) atomicAdd(&cnt[dst[e]], 1);
}

// Stage 1: per-block (256-chunk) sums of cnt
__global__ __launch_bounds__(256) void psum_kernel(const int* __restrict__ cnt,
                                                   int* __restrict__ bsum, int n) {
    __shared__ int s[256];
    int t = threadIdx.x;
    int i = blockIdx.x * 256 + t;
    s[t] = (i < n) ? cnt[i] : 0;
    __syncthreads();
    for (int off = 128; off > 0; off >>= 1) {
        if (t < off) s[t] += s[t + off];
        __syncthreads();
    }
    if (t == 0) bsum[blockIdx.x] = s[0];
}

// Stage 2: single-block exclusive scan of block sums (PB <= 256)
__global__ __launch_bounds__(256) void bscan_kernel(const int* __restrict__ bsum,
                                                    int* __restrict__ boff, int PB) {
    __shared__ int s[256];
    int t = threadIdx.x;
    int v = (t < PB) ? bsum[t] : 0;
    s[t] = v;
    __syncthreads();
    for (int off = 1; off < 256; off <<= 1) {
        int add = (t >= off) ? s[t - off] : 0;
        __syncthreads();
        s[t] += add;
        __syncthreads();
    }
    if (t < PB) boff[t] = s[t] - v;   // exclusive
}

// Stage 3: local inclusive scan + block offset -> rowstart/cursor; fused dinv
__global__ __launch_bounds__(256) void rows_kernel(const int* __restrict__ cnt,
                                                   const int* __restrict__ boff,
                                                   int* __restrict__ rowstart,
                                                   int* __restrict__ cursor,
                                                   float* __restrict__ dinv,
                                                   int n, int E) {
    __shared__ int s[256];
    int t = threadIdx.x;
    int i = blockIdx.x * 256 + t;
    int c = (i < n) ? cnt[i] : 0;
    s[t] = c;
    __syncthreads();
    for (int off = 1; off < 256; off <<= 1) {
        int add = (t >= off) ? s[t - off] : 0;
        __syncthreads();
        s[t] += add;
        __syncthreads();
    }
    if (i < n) {
        int excl = s[t] - c + boff[blockIdx.x];
        rowstart[i] = excl;
        cursor[i] = excl;
        dinv[i] = rsqrtf(1.0f + (float)c);   // deg = in-count + self loop
    }
    if (i == 0) rowstart[n] = E;
}

__global__ void fill_kernel(const int* __restrict__ src, const int* __restrict__ dst,
                            int* __restrict__ cursor, int* __restrict__ csr_src, int E) {
    int e = blockIdx.x * blockDim.x + threadIdx.x;
    if (e < E) {
        int d = dst[e];
        int pos = atomicAdd(&cursor[d], 1);
        csr_src[pos] = src[e];
    }
}

// ---------------- GEMM: Y[M,128] = X[M,128] @ W[128,128] ----------------
// Persistent blocks: W staged to LDS once per block, grid-stride over 16-row tiles.

__global__ __launch_bounds__(256, 2) void gemm_kernel(const float* __restrict__ X,
                                                      const float* __restrict__ Wg,
                                                      float* __restrict__ Y, int M) {
    __shared__ float Ws[D * D];
    __shared__ float xs[16][132];   // +4 pad: breaks bank aliasing across rows
    int t = threadIdx.x;
    for (int i = t * 4; i < D * D; i += 256 * 4) {
        *(float4*)&Ws[i] = *(const float4*)&Wg[i];
    }
    int ntiles = M >> 4;            // M = 50000 is divisible by 16
    int r = t >> 4;
    int c0 = (t & 15) * 8;
    for (int tile = blockIdx.x; tile < ntiles; tile += gridDim.x) {
        int row0 = tile << 4;
        __syncthreads();            // covers W staging (iter 0) + xs reuse
        {
            int idx = t * 8;
            int rr = idx >> 7, cc = idx & 127;
            const float* px = &X[(size_t)(row0 + rr) * D + cc];
            float4 a = *(const float4*)px;
            float4 b = *(const float4*)(px + 4);
            *(float4*)&xs[rr][cc] = a;
            *(float4*)&xs[rr][cc + 4] = b;
        }
        __syncthreads();
        float acc[8];
#pragma unroll
        for (int j = 0; j < 8; j++) acc[j] = 0.f;
#pragma unroll 4
        for (int k = 0; k < D; k++) {
            float a = xs[r][k];
            float4 w0 = *(float4*)&Ws[k * D + c0];
            float4 w1 = *(float4*)&Ws[k * D + c0 + 4];
            acc[0] += a * w0.x; acc[1] += a * w0.y;
            acc[2] += a * w0.z; acc[3] += a * w0.w;
            acc[4] += a * w1.x; acc[5] += a * w1.y;
            acc[6] += a * w1.z; acc[7] += a * w1.w;
        }
        float* py = &Y[(size_t)(row0 + r) * D + c0];
        float4 o0 = {acc[0], acc[1], acc[2], acc[3]};
        float4 o1 = {acc[4], acc[5], acc[6], acc[7]};
        *(float4*)py = o0;
        *(float4*)(py + 4) = o1;
    }
}

// ---------------- Aggregation: one wave per node, 2 floats/lane ----------------
// out[v] = bias + dinv[v]^2 * xw[v] + sum_{u in N_in(v)} dinv[u]*dinv[v] * xw[u]

template <int RELU, int POOL>
__global__ __launch_bounds__(256) void agg_kernel(const float* __restrict__ XW,
                                                  const float* __restrict__ bias,
                                                  const float* __restrict__ dinv,
                                                  const int* __restrict__ rowstart,
                                                  const int* __restrict__ csr_src,
                                                  const float* __restrict__ is_n,
                                                  const int* __restrict__ batch,
                                                  float* __restrict__ out, int n) {
    int wid = threadIdx.x >> 6;
    int lane = threadIdx.x & 63;
    int v = blockIdx.x * 4 + wid;
    if (v >= n) return;
    float w_is = 0.f;
    if (POOL) {
        w_is = is_n[v];
        if (w_is == 0.f) return;    // wave-uniform: whole wave exits
    }
    float dv = dinv[v];
    int c = lane * 2;
    float2 bb = *(const float2*)&bias[c];
    float2 xv = *(const float2*)&XW[(size_t)v * D + c];
    float sv = dv * dv;
    float2 acc = {bb.x + sv * xv.x, bb.y + sv * xv.y};
    int e0 = rowstart[v], e1 = rowstart[v + 1];
    int e = e0;
    for (; e + 1 < e1; e += 2) {
        int u0 = csr_src[e];
        int u1 = csr_src[e + 1];
        float n0 = dinv[u0] * dv;
        float n1 = dinv[u1] * dv;
        float2 x0 = *(const float2*)&XW[(size_t)u0 * D + c];
        float2 x1 = *(const float2*)&XW[(size_t)u1 * D + c];
        acc.x += n0 * x0.x + n1 * x1.x;
        acc.y += n0 * x0.y + n1 * x1.y;
    }
    if (e < e1) {
        int u = csr_src[e];
        float nv = dinv[u] * dv;
        float2 xu = *(const float2*)&XW[(size_t)u * D + c];
        acc.x += nv * xu.x;
        acc.y += nv * xu.y;
    }
    if (RELU) {
        acc.x = fmaxf(acc.x, 0.f);
        acc.y = fmaxf(acc.y, 0.f);
    }
    if (POOL) {
        int g = batch[v];
        float s = 0.5f * w_is;
        atomicAdd(&out[(size_t)g * D + c], acc.x * s);
        atomicAdd(&out[(size_t)g * D + c + 1], acc.y * s);
    } else {
        *(float2*)&out[(size_t)v * D + c] = acc;
    }
}

// ---------------- launch ----------------

extern "C" void kernel_launch(void* const* d_in, const int* in_sizes, int n_in,
                              void* d_out, int out_size, void* d_ws, size_t ws_size,
                              hipStream_t stream) {
    const float* x    = (const float*)d_in[0];
    const int*   edge = (const int*)d_in[1];
    const float* is_n = (const float*)d_in[2];
    const int*   batch = (const int*)d_in[3];
    const float* W1 = (const float*)d_in[4];
    const float* b1 = (const float*)d_in[5];
    const float* W2 = (const float*)d_in[6];
    const float* b2 = (const float*)d_in[7];
    const float* W3 = (const float*)d_in[8];
    const float* b3 = (const float*)d_in[9];
    float* out = (float*)d_out;

    int n = in_sizes[0] / D;       // 50000
    int E = in_sizes[1] / 2;       // 600000
    const int* esrc = edge;
    const int* edst = edge + E;

    char* p = (char*)d_ws;
    float* xw = (float*)p;       p += (size_t)n * D * sizeof(float);
    float* h  = (float*)p;       p += (size_t)n * D * sizeof(float);
    float* dinv = (float*)p;     p += (size_t)n * sizeof(float);
    int* cnt = (int*)p;          p += (size_t)n * sizeof(int);
    int* rowstart = (int*)p;     p += (size_t)(n + 1) * sizeof(int);
    int* cursor = (int*)p;       p += (size_t)n * sizeof(int);
    int* csr_src = (int*)p;      p += (size_t)E * sizeof(int);
    int* bsum = (int*)p;         p += 256 * sizeof(int);
    int* boff = (int*)p;         p += 256 * sizeof(int);

    int PB = (n + 255) / 256;     // 196 blocks

    hipMemsetAsync(cnt, 0, (size_t)n * sizeof(int), stream);
    count_kernel<<<(E + 255) / 256, 256, 0, stream>>>(edst, cnt, E);
    psum_kernel<<<PB, 256, 0, stream>>>(cnt, bsum, n);
    bscan_kernel<<<1, 256, 0, stream>>>(bsum, boff, PB);
    rows_kernel<<<PB, 256, 0, stream>>>(cnt, boff, rowstart, cursor, dinv, n, E);
    fill_kernel<<<(E + 255) / 256, 256, 0, stream>>>(esrc, edst, cursor, csr_src, E);

    const int gblocks = 512;   // persistent: 2 blocks/CU, W staged once per block
    int ablocks = (n + 3) / 4;

    // Layer 1
    gemm_kernel<<<gblocks, 256, 0, stream>>>(x, W1, xw, n);
    agg_kernel<1, 0><<<ablocks, 256, 0, stream>>>(xw, b1, dinv, rowstart, csr_src,
                                                  nullptr, nullptr, h, n);
    // Layer 2
    gemm_kernel<<<gblocks, 256, 0, stream>>>(h, W2, xw, n);
    agg_kernel<1, 0><<<ablocks, 256, 0, stream>>>(xw, b2, dinv, rowstart, csr_src,
                                                  nullptr, nullptr, h, n);
    // Layer 3: only is_neighbor nodes matter for the pooled output
    gemm_kernel<<<gblocks, 256, 0, stream>>>(h, W3, xw, n);
    hipMemsetAsync(d_out, 0, (size_t)out_size * sizeof(float), stream);
    agg_kernel<0, 1><<<ablocks, 256, 0, stream>>>(xw, b3, dinv, rowstart, csr_src,
                                                  is_n, batch, out, n);
}

// Round 3
// 318.187 us; speedup vs baseline: 1.5150x; 1.1917x over previous
//
#include <hip/hip_runtime.h>

#define D 128

// ---------------- CSR build ----------------

__global__ void count_kernel(const int* __restrict__ dst, int* __restrict__ cnt, int E) {
    int e = blockIdx.x * blockDim.x + threadIdx.x;
    if (e < E) atomicAdd(&cnt[dst[e]], 1);
}

__global__ __launch_bounds__(256) void psum_kernel(const int* __restrict__ cnt,
                                                   int* __restrict__ bsum, int n) {
    __shared__ int s[256];
    int t = threadIdx.x;
    int i = blockIdx.x * 256 + t;
    s[t] = (i < n) ? cnt[i] : 0;
    __syncthreads();
    for (int off = 128; off > 0; off >>= 1) {
        if (t < off) s[t] += s[t + off];
        __syncthreads();
    }
    if (t == 0) bsum[blockIdx.x] = s[0];
}

__global__ __launch_bounds__(256) void bscan_kernel(const int* __restrict__ bsum,
                                                    int* __restrict__ boff, int PB) {
    __shared__ int s[256];
    int t = threadIdx.x;
    int v = (t < PB) ? bsum[t] : 0;
    s[t] = v;
    __syncthreads();
    for (int off = 1; off < 256; off <<= 1) {
        int add = (t >= off) ? s[t - off] : 0;
        __syncthreads();
        s[t] += add;
        __syncthreads();
    }
    if (t < PB) boff[t] = s[t] - v;   // exclusive
}

__global__ __launch_bounds__(256) void rows_kernel(const int* __restrict__ cnt,
                                                   const int* __restrict__ boff,
                                                   int* __restrict__ rowstart,
                                                   int* __restrict__ cursor,
                                                   float* __restrict__ dinv,
                                                   int n, int E) {
    __shared__ int s[256];
    int t = threadIdx.x;
    int i = blockIdx.x * 256 + t;
    int c = (i < n) ? cnt[i] : 0;
    s[t] = c;
    __syncthreads();
    for (int off = 1; off < 256; off <<= 1) {
        int add = (t >= off) ? s[t - off] : 0;
        __syncthreads();
        s[t] += add;
        __syncthreads();
    }
    if (i < n) {
        int excl = s[t] - c + boff[blockIdx.x];
        rowstart[i] = excl;
        cursor[i] = excl;
        dinv[i] = rsqrtf(1.0f + (float)c);   // deg = in-count + self loop
    }
    if (i == 0) rowstart[n] = E;
}

__global__ void fill_kernel(const int* __restrict__ src, const int* __restrict__ dst,
                            int* __restrict__ cursor, int* __restrict__ csr_src, int E) {
    int e = blockIdx.x * blockDim.x + threadIdx.x;
    if (e < E) {
        int d = dst[e];
        int pos = atomicAdd(&cursor[d], 1);
        csr_src[pos] = src[e];
    }
}

// ---------------- GEMM: Y[M,128] = X[M,128] @ W[128,128] ----------------
// 64-row x 128-col tile; thread = 4 rows x 8 cols register block (32 FMA per
// 6 LDS reads -> VALU-bound). W-cols read as two contiguous float4 groups
// (4tc, 64+4tc) -> 2-way bank alias only (free). Persistent blocks, 1/CU.

__global__ __launch_bounds__(256, 1) void gemm_kernel(const float* __restrict__ X,
                                                      const float* __restrict__ Wg,
                                                      float* __restrict__ Y, int M) {
    __shared__ float Ws[D * D];        // 64 KB
    __shared__ float xs[64][132];      // 33.8 KB, pad 4: x-reads 2-way alias only
    int t = threadIdx.x;
    for (int i = t * 4; i < D * D; i += 1024) {
        *(float4*)&Ws[i] = *(const float4*)&Wg[i];
    }
    int tc = t & 15;                   // col group: cols 4tc..+3 and 64+4tc..+3
    int rr = t >> 4;                   // row group: rows 4rr..4rr+3
    size_t MD = (size_t)M * D;
    int ntiles = (M + 63) >> 6;
    for (int tile = blockIdx.x; tile < ntiles; tile += gridDim.x) {
        int row0 = tile << 6;
        __syncthreads();               // covers Ws (iter 0) + xs reuse
        {
            size_t base = (size_t)row0 * D + t * 32;
#pragma unroll
            for (int j = 0; j < 8; j++) {
                size_t g = base + j * 4;
                if (g + 4 <= MD) {
                    float4 v = *(const float4*)&X[g];
                    int ti = t * 32 + j * 4;
                    *(float4*)&xs[ti >> 7][ti & 127] = v;
                }
            }
        }
        __syncthreads();
        float acc[4][8];
#pragma unroll
        for (int i = 0; i < 4; i++)
#pragma unroll
            for (int j = 0; j < 8; j++) acc[i][j] = 0.f;
#pragma unroll 4
        for (int k = 0; k < D; k++) {
            float4 w0 = *(float4*)&Ws[k * D + 4 * tc];
            float4 w1 = *(float4*)&Ws[k * D + 64 + 4 * tc];
            float xr[4];
#pragma unroll
            for (int i = 0; i < 4; i++) xr[i] = xs[4 * rr + i][k];
#pragma unroll
            for (int i = 0; i < 4; i++) {
                acc[i][0] += xr[i] * w0.x; acc[i][1] += xr[i] * w0.y;
                acc[i][2] += xr[i] * w0.z; acc[i][3] += xr[i] * w0.w;
                acc[i][4] += xr[i] * w1.x; acc[i][5] += xr[i] * w1.y;
                acc[i][6] += xr[i] * w1.z; acc[i][7] += xr[i] * w1.w;
            }
        }
#pragma unroll
        for (int i = 0; i < 4; i++) {
            int row = row0 + 4 * rr + i;
            if (row < M) {
                float* py = &Y[(size_t)row * D];
                float4 o0 = {acc[i][0], acc[i][1], acc[i][2], acc[i][3]};
                float4 o1 = {acc[i][4], acc[i][5], acc[i][6], acc[i][7]};
                *(float4*)&py[4 * tc] = o0;
                *(float4*)&py[64 + 4 * tc] = o1;
            }
        }
    }
}

// ---------------- Aggregation: one wave per node, 2 floats/lane ----------------

template <int RELU>
__global__ __launch_bounds__(256) void agg_kernel(const float* __restrict__ XW,
                                                  const float* __restrict__ bias,
                                                  const float* __restrict__ dinv,
                                                  const int* __restrict__ rowstart,
                                                  const int* __restrict__ csr_src,
                                                  float* __restrict__ out, int n) {
    int wid = threadIdx.x >> 6;
    int lane = threadIdx.x & 63;
    int v = blockIdx.x * 4 + wid;
    if (v >= n) return;
    float dv = dinv[v];
    int c = lane * 2;
    float2 bb = *(const float2*)&bias[c];
    float2 xv = *(const float2*)&XW[(size_t)v * D + c];
    float sv = dv * dv;
    float2 acc = {bb.x + sv * xv.x, bb.y + sv * xv.y};
    int e0 = rowstart[v], e1 = rowstart[v + 1];
    int e = e0;
    for (; e + 1 < e1; e += 2) {
        int u0 = csr_src[e];
        int u1 = csr_src[e + 1];
        float n0 = dinv[u0] * dv;
        float n1 = dinv[u1] * dv;
        float2 x0 = *(const float2*)&XW[(size_t)u0 * D + c];
        float2 x1 = *(const float2*)&XW[(size_t)u1 * D + c];
        acc.x += n0 * x0.x + n1 * x1.x;
        acc.y += n0 * x0.y + n1 * x1.y;
    }
    if (e < e1) {
        int u = csr_src[e];
        float nv = dinv[u] * dv;
        float2 xu = *(const float2*)&XW[(size_t)u * D + c];
        acc.x += nv * xu.x;
        acc.y += nv * xu.y;
    }
    if (RELU) {
        acc.x = fmaxf(acc.x, 0.f);
        acc.y = fmaxf(acc.y, 0.f);
    }
    *(float2*)&out[(size_t)v * D + c] = acc;
}

// Layer 3 pooled aggregation: P[g] += is_n[v] * (A_norm h2)[v]; cg[g] += is_n[v].
__global__ __launch_bounds__(256) void agg_pool_kernel(const float* __restrict__ H,
                                                       const float* __restrict__ dinv,
                                                       const int* __restrict__ rowstart,
                                                       const int* __restrict__ csr_src,
                                                       const float* __restrict__ is_n,
                                                       const int* __restrict__ batch,
                                                       float* __restrict__ P,
                                                       float* __restrict__ cg, int n) {
    int wid = threadIdx.x >> 6;
    int lane = threadIdx.x & 63;
    int v = blockIdx.x * 4 + wid;
    if (v >= n) return;
    float w_is = is_n[v];
    if (w_is == 0.f) return;           // wave-uniform: whole wave exits
    float dv = dinv[v];
    int c = lane * 2;
    float2 hv = *(const float2*)&H[(size_t)v * D + c];
    float sv = dv * dv;
    float2 acc = {sv * hv.x, sv * hv.y};
    int e0 = rowstart[v], e1 = rowstart[v + 1];
    for (int e = e0; e < e1; e++) {
        int u = csr_src[e];
        float nv = dinv[u] * dv;
        float2 hu = *(const float2*)&H[(size_t)u * D + c];
        acc.x += nv * hu.x;
        acc.y += nv * hu.y;
    }
    int g = batch[v];
    atomicAdd(&P[(size_t)g * D + c], w_is * acc.x);
    atomicAdd(&P[(size_t)g * D + c + 1], w_is * acc.y);
    if (lane == 0) atomicAdd(&cg[g], w_is);
}

// out[g] = 0.5 * (P[g] @ W3) + 0.5 * cg[g] * b3   (one wave per graph)
__global__ __launch_bounds__(64) void pool_gemm_kernel(const float* __restrict__ P,
                                                       const float* __restrict__ cg,
                                                       const float* __restrict__ W,
                                                       const float* __restrict__ b,
                                                       float* __restrict__ out, int G) {
    int g = blockIdx.x;
    if (g >= G) return;
    int c = threadIdx.x * 2;
    float2 acc = {0.f, 0.f};
    const float* pr = &P[(size_t)g * D];
#pragma unroll 4
    for (int k = 0; k < D; k++) {
        float pk = pr[k];
        float2 w = *(const float2*)&W[k * D + c];
        acc.x += pk * w.x;
        acc.y += pk * w.y;
    }
    float s = 0.5f * cg[g];
    float2 bb = *(const float2*)&b[c];
    out[(size_t)g * D + c]     = 0.5f * acc.x + s * bb.x;
    out[(size_t)g * D + c + 1] = 0.5f * acc.y + s * bb.y;
}

// ---------------- launch ----------------

extern "C" void kernel_launch(void* const* d_in, const int* in_sizes, int n_in,
                              void* d_out, int out_size, void* d_ws, size_t ws_size,
                              hipStream_t stream) {
    const float* x     = (const float*)d_in[0];
    const int*   edge  = (const int*)d_in[1];
    const float* is_n  = (const float*)d_in[2];
    const int*   batch = (const int*)d_in[3];
    const float* W1 = (const float*)d_in[4];
    const float* b1 = (const float*)d_in[5];
    const float* W2 = (const float*)d_in[6];
    const float* b2 = (const float*)d_in[7];
    const float* W3 = (const float*)d_in[8];
    const float* b3 = (const float*)d_in[9];
    float* out = (float*)d_out;

    int n = in_sizes[0] / D;       // 50000
    int E = in_sizes[1] / 2;       // 600000
    int G = out_size / D;          // 500
    const int* esrc = edge;
    const int* edst = edge + E;

    char* p = (char*)d_ws;
    float* xw = (float*)p;       p += (size_t)n * D * sizeof(float);
    float* h  = (float*)p;       p += (size_t)n * D * sizeof(float);
    float* dinv = (float*)p;     p += (size_t)n * sizeof(float);
    int* cnt = (int*)p;          p += (size_t)n * sizeof(int);
    int* rowstart = (int*)p;     p += (size_t)(n + 1) * sizeof(int);
    int* cursor = (int*)p;       p += (size_t)n * sizeof(int);
    int* csr_src = (int*)p;      p += (size_t)E * sizeof(int);
    int* bsum = (int*)p;         p += 256 * sizeof(int);
    int* boff = (int*)p;         p += 256 * sizeof(int);
    float* P = (float*)p;        p += (size_t)G * D * sizeof(float);
    float* cg = (float*)p;       p += (size_t)G * sizeof(float);

    int PB = (n + 255) / 256;

    hipMemsetAsync(cnt, 0, (size_t)n * sizeof(int), stream);
    hipMemsetAsync(P, 0, (size_t)G * D * sizeof(float), stream);
    hipMemsetAsync(cg, 0, (size_t)G * sizeof(float), stream);
    count_kernel<<<(E + 255) / 256, 256, 0, stream>>>(edst, cnt, E);
    psum_kernel<<<PB, 256, 0, stream>>>(cnt, bsum, n);
    bscan_kernel<<<1, 256, 0, stream>>>(bsum, boff, PB);
    rows_kernel<<<PB, 256, 0, stream>>>(cnt, boff, rowstart, cursor, dinv, n, E);
    fill_kernel<<<(E + 255) / 256, 256, 0, stream>>>(esrc, edst, cursor, csr_src, E);

    const int gblocks = 256;   // persistent, 1 block/CU (97.8 KB LDS)
    int ablocks = (n + 3) / 4;

    // Layer 1
    gemm_kernel<<<gblocks, 256, 0, stream>>>(x, W1, xw, n);
    agg_kernel<1><<<ablocks, 256, 0, stream>>>(xw, b1, dinv, rowstart, csr_src, h, n);
    // Layer 2
    gemm_kernel<<<gblocks, 256, 0, stream>>>(h, W2, xw, n);
    agg_kernel<1><<<ablocks, 256, 0, stream>>>(xw, b2, dinv, rowstart, csr_src, h, n);
    // Layer 3: pool(A h2) first (linear), then tiny 500x128 GEMM
    agg_pool_kernel<<<ablocks, 256, 0, stream>>>(h, dinv, rowstart, csr_src,
                                                 is_n, batch, P, cg, n);
    pool_gemm_kernel<<<G, 64, 0, stream>>>(P, cg, W3, b3, out, G);
}

// Round 4
// 278.534 us; speedup vs baseline: 1.7307x; 1.1424x over previous
//
#include <hip/hip_runtime.h>
#include <hip/hip_fp16.h>

#define D 128

// ---------------- CSR build ----------------

__global__ void count_kernel(const int* __restrict__ dst, int* __restrict__ cnt, int E) {
    int e = blockIdx.x * blockDim.x + threadIdx.x;
    if (e < E) atomicAdd(&cnt[dst[e]], 1);
}

__global__ __launch_bounds__(256) void psum_kernel(const int* __restrict__ cnt,
                                                   int* __restrict__ bsum, int n) {
    __shared__ int s[256];
    int t = threadIdx.x;
    int i = blockIdx.x * 256 + t;
    s[t] = (i < n) ? cnt[i] : 0;
    __syncthreads();
    for (int off = 128; off > 0; off >>= 1) {
        if (t < off) s[t] += s[t + off];
        __syncthreads();
    }
    if (t == 0) bsum[blockIdx.x] = s[0];
}

// exclusive scan of block sums; optionally writes grand total to *tot
__global__ __launch_bounds__(256) void bscan_kernel(const int* __restrict__ bsum,
                                                    int* __restrict__ boff,
                                                    int* __restrict__ tot, int PB) {
    __shared__ int s[256];
    int t = threadIdx.x;
    int v = (t < PB) ? bsum[t] : 0;
    s[t] = v;
    __syncthreads();
    for (int off = 1; off < 256; off <<= 1) {
        int add = (t >= off) ? s[t - off] : 0;
        __syncthreads();
        s[t] += add;
        __syncthreads();
    }
    if (t < PB) boff[t] = s[t] - v;   // exclusive
    if (tot && t == PB - 1) tot[0] = s[t];
}

__global__ __launch_bounds__(256) void rows_kernel(const int* __restrict__ cnt,
                                                   const int* __restrict__ boff,
                                                   int* __restrict__ rowstart,
                                                   int* __restrict__ cursor,
                                                   float* __restrict__ dinv,
                                                   int n, int E) {
    __shared__ int s[256];
    int t = threadIdx.x;
    int i = blockIdx.x * 256 + t;
    int c = (i < n) ? cnt[i] : 0;
    s[t] = c;
    __syncthreads();
    for (int off = 1; off < 256; off <<= 1) {
        int add = (t >= off) ? s[t - off] : 0;
        __syncthreads();
        s[t] += add;
        __syncthreads();
    }
    if (i < n) {
        int excl = s[t] - c + boff[blockIdx.x];
        rowstart[i] = excl;
        cursor[i] = excl;
        dinv[i] = rsqrtf(1.0f + (float)c);   // deg = in-count + self loop
    }
    if (i == 0) rowstart[n] = E;
}

__global__ void fill_kernel(const int* __restrict__ src, const int* __restrict__ dst,
                            int* __restrict__ cursor, int* __restrict__ csr_src, int E) {
    int e = blockIdx.x * blockDim.x + threadIdx.x;
    if (e < E) {
        int d = dst[e];
        int pos = atomicAdd(&cursor[d], 1);
        csr_src[pos] = src[e];
    }
}

// ---------------- Active set for layer 2: S2 = {is_n} U N_in({is_n}) ----------------

__global__ void mark_kernel(const float* __restrict__ is_n,
                            const int* __restrict__ rowstart,
                            const int* __restrict__ csr_src,
                            int* __restrict__ mark, int n) {
    int v = blockIdx.x * blockDim.x + threadIdx.x;
    if (v >= n) return;
    if (is_n[v] == 0.f) return;
    mark[v] = 1;
    int e1 = rowstart[v + 1];
    for (int e = rowstart[v]; e < e1; e++) mark[csr_src[e]] = 1;
}

__global__ __launch_bounds__(256) void compact_kernel(const int* __restrict__ mark,
                                                      const int* __restrict__ boff,
                                                      int* __restrict__ act, int n) {
    __shared__ int s[256];
    int t = threadIdx.x;
    int i = blockIdx.x * 256 + t;
    int m = (i < n) ? mark[i] : 0;
    s[t] = m;
    __syncthreads();
    for (int off = 1; off < 256; off <<= 1) {
        int add = (t >= off) ? s[t - off] : 0;
        __syncthreads();
        s[t] += add;
        __syncthreads();
    }
    if (m) act[s[t] - 1 + boff[blockIdx.x]] = i;
}

// ---------------- GEMM: Y[M,128](fp16) = X[M,128](fp32) @ W[128,128] ----------------
// 64x128 tile; thread = 4 rows x 8 cols register block. Persistent blocks, 1/CU.

union H4 { __half h[4]; float2 f2; };

__global__ __launch_bounds__(256, 1) void gemm_kernel(const float* __restrict__ X,
                                                      const float* __restrict__ Wg,
                                                      __half* __restrict__ Y, int M) {
    __shared__ float Ws[D * D];        // 64 KB
    __shared__ float xs[64][132];      // 33.8 KB, pad 4
    int t = threadIdx.x;
    for (int i = t * 4; i < D * D; i += 1024) {
        *(float4*)&Ws[i] = *(const float4*)&Wg[i];
    }
    int tc = t & 15;
    int rr = t >> 4;
    size_t MD = (size_t)M * D;
    int ntiles = (M + 63) >> 6;
    for (int tile = blockIdx.x; tile < ntiles; tile += gridDim.x) {
        int row0 = tile << 6;
        __syncthreads();
        {
            size_t base = (size_t)row0 * D + t * 32;
#pragma unroll
            for (int j = 0; j < 8; j++) {
                size_t g = base + j * 4;
                if (g + 4 <= MD) {
                    float4 v = *(const float4*)&X[g];
                    int ti = t * 32 + j * 4;
                    *(float4*)&xs[ti >> 7][ti & 127] = v;
                }
            }
        }
        __syncthreads();
        float acc[4][8];
#pragma unroll
        for (int i = 0; i < 4; i++)
#pragma unroll
            for (int j = 0; j < 8; j++) acc[i][j] = 0.f;
#pragma unroll 4
        for (int k = 0; k < D; k++) {
            float4 w0 = *(float4*)&Ws[k * D + 4 * tc];
            float4 w1 = *(float4*)&Ws[k * D + 64 + 4 * tc];
            float xr[4];
#pragma unroll
            for (int i = 0; i < 4; i++) xr[i] = xs[4 * rr + i][k];
#pragma unroll
            for (int i = 0; i < 4; i++) {
                acc[i][0] += xr[i] * w0.x; acc[i][1] += xr[i] * w0.y;
                acc[i][2] += xr[i] * w0.z; acc[i][3] += xr[i] * w0.w;
                acc[i][4] += xr[i] * w1.x; acc[i][5] += xr[i] * w1.y;
                acc[i][6] += xr[i] * w1.z; acc[i][7] += xr[i] * w1.w;
            }
        }
#pragma unroll
        for (int i = 0; i < 4; i++) {
            int row = row0 + 4 * rr + i;
            if (row < M) {
                __half* py = &Y[(size_t)row * D];
                H4 o0, o1;
#pragma unroll
                for (int j = 0; j < 4; j++) {
                    o0.h[j] = __float2half(acc[i][j]);
                    o1.h[j] = __float2half(acc[i][4 + j]);
                }
                *(float2*)&py[4 * tc] = o0.f2;
                *(float2*)&py[64 + 4 * tc] = o1.f2;
            }
        }
    }
}

// ---------------- Aggregation (full): fp16 gather, fp32 out, relu ----------------
// out[v] = relu(bias + dinv[v]^2 xw[v] + sum_u dinv[u] dinv[v] xw[u])

__global__ __launch_bounds__(256) void agg_kernel(const __half* __restrict__ XW,
                                                  const float* __restrict__ bias,
                                                  const float* __restrict__ dinv,
                                                  const int* __restrict__ rowstart,
                                                  const int* __restrict__ csr_src,
                                                  float* __restrict__ out, int n) {
    int wid = threadIdx.x >> 6;
    int lane = threadIdx.x & 63;
    int v = blockIdx.x * 4 + wid;
    if (v >= n) return;
    float dv = dinv[v];
    int c = lane * 2;
    float2 bb = *(const float2*)&bias[c];
    float2 xv = __half22float2(*(const __half2*)&XW[(size_t)v * D + c]);
    float sv = dv * dv;
    float2 acc = {bb.x + sv * xv.x, bb.y + sv * xv.y};
    int e0 = rowstart[v], e1 = rowstart[v + 1];
    int e = e0;
    for (; e + 1 < e1; e += 2) {
        int u0 = csr_src[e];
        int u1 = csr_src[e + 1];
        float n0 = dinv[u0] * dv;
        float n1 = dinv[u1] * dv;
        float2 x0 = __half22float2(*(const __half2*)&XW[(size_t)u0 * D + c]);
        float2 x1 = __half22float2(*(const __half2*)&XW[(size_t)u1 * D + c]);
        acc.x += n0 * x0.x + n1 * x1.x;
        acc.y += n0 * x0.y + n1 * x1.y;
    }
    if (e < e1) {
        int u = csr_src[e];
        float nv = dinv[u] * dv;
        float2 xu = __half22float2(*(const __half2*)&XW[(size_t)u * D + c]);
        acc.x += nv * xu.x;
        acc.y += nv * xu.y;
    }
    acc.x = fmaxf(acc.x, 0.f);
    acc.y = fmaxf(acc.y, 0.f);
    *(float2*)&out[(size_t)v * D + c] = acc;
}

// ---------------- Aggregation (active set only), grid-strided waves ----------------

__global__ __launch_bounds__(256) void agg_act_kernel(const __half* __restrict__ XW,
                                                      const float* __restrict__ bias,
                                                      const float* __restrict__ dinv,
                                                      const int* __restrict__ rowstart,
                                                      const int* __restrict__ csr_src,
                                                      const int* __restrict__ act,
                                                      const int* __restrict__ na_p,
                                                      float* __restrict__ out) {
    int wid = threadIdx.x >> 6;
    int lane = threadIdx.x & 63;
    int na = na_p[0];
    int stride = gridDim.x * 4;
    int c = lane * 2;
    float2 bb = *(const float2*)&bias[c];
    for (int i = blockIdx.x * 4 + wid; i < na; i += stride) {
        int v = act[i];
        float dv = dinv[v];
        float2 xv = __half22float2(*(const __half2*)&XW[(size_t)v * D + c]);
        float sv = dv * dv;
        float2 acc = {bb.x + sv * xv.x, bb.y + sv * xv.y};
        int e0 = rowstart[v], e1 = rowstart[v + 1];
        int e = e0;
        for (; e + 1 < e1; e += 2) {
            int u0 = csr_src[e];
            int u1 = csr_src[e + 1];
            float n0 = dinv[u0] * dv;
            float n1 = dinv[u1] * dv;
            float2 x0 = __half22float2(*(const __half2*)&XW[(size_t)u0 * D + c]);
            float2 x1 = __half22float2(*(const __half2*)&XW[(size_t)u1 * D + c]);
            acc.x += n0 * x0.x + n1 * x1.x;
            acc.y += n0 * x0.y + n1 * x1.y;
        }
        if (e < e1) {
            int u = csr_src[e];
            float nv = dinv[u] * dv;
            float2 xu = __half22float2(*(const __half2*)&XW[(size_t)u * D + c]);
            acc.x += nv * xu.x;
            acc.y += nv * xu.y;
        }
        acc.x = fmaxf(acc.x, 0.f);
        acc.y = fmaxf(acc.y, 0.f);
        *(float2*)&out[(size_t)v * D + c] = acc;
    }
}

// ---------------- Layer 3 pooled aggregation + tiny GEMM ----------------

__global__ __launch_bounds__(256) void agg_pool_kernel(const float* __restrict__ H,
                                                       const float* __restrict__ dinv,
                                                       const int* __restrict__ rowstart,
                                                       const int* __restrict__ csr_src,
                                                       const float* __restrict__ is_n,
                                                       const int* __restrict__ batch,
                                                       float* __restrict__ P,
                                                       float* __restrict__ cg, int n) {
    int wid = threadIdx.x >> 6;
    int lane = threadIdx.x & 63;
    int v = blockIdx.x * 4 + wid;
    if (v >= n) return;
    float w_is = is_n[v];
    if (w_is == 0.f) return;           // wave-uniform exit
    float dv = dinv[v];
    int c = lane * 2;
    float2 hv = *(const float2*)&H[(size_t)v * D + c];
    float sv = dv * dv;
    float2 acc = {sv * hv.x, sv * hv.y};
    int e0 = rowstart[v], e1 = rowstart[v + 1];
    for (int e = e0; e < e1; e++) {
        int u = csr_src[e];
        float nv = dinv[u] * dv;
        float2 hu = *(const float2*)&H[(size_t)u * D + c];
        acc.x += nv * hu.x;
        acc.y += nv * hu.y;
    }
    int g = batch[v];
    atomicAdd(&P[(size_t)g * D + c], w_is * acc.x);
    atomicAdd(&P[(size_t)g * D + c + 1], w_is * acc.y);
    if (lane == 0) atomicAdd(&cg[g], w_is);
}

__global__ __launch_bounds__(64) void pool_gemm_kernel(const float* __restrict__ P,
                                                       const float* __restrict__ cg,
                                                       const float* __restrict__ W,
                                                       const float* __restrict__ b,
                                                       float* __restrict__ out, int G) {
    int g = blockIdx.x;
    if (g >= G) return;
    int c = threadIdx.x * 2;
    float2 acc = {0.f, 0.f};
    const float* pr = &P[(size_t)g * D];
#pragma unroll 4
    for (int k = 0; k < D; k++) {
        float pk = pr[k];
        float2 w = *(const float2*)&W[k * D + c];
        acc.x += pk * w.x;
        acc.y += pk * w.y;
    }
    float s = 0.5f * cg[g];
    float2 bb = *(const float2*)&b[c];
    out[(size_t)g * D + c]     = 0.5f * acc.x + s * bb.x;
    out[(size_t)g * D + c + 1] = 0.5f * acc.y + s * bb.y;
}

// ---------------- launch ----------------

extern "C" void kernel_launch(void* const* d_in, const int* in_sizes, int n_in,
                              void* d_out, int out_size, void* d_ws, size_t ws_size,
                              hipStream_t stream) {
    const float* x     = (const float*)d_in[0];
    const int*   edge  = (const int*)d_in[1];
    const float* is_n  = (const float*)d_in[2];
    const int*   batch = (const int*)d_in[3];
    const float* W1 = (const float*)d_in[4];
    const float* b1 = (const float*)d_in[5];
    const float* W2 = (const float*)d_in[6];
    const float* b2 = (const float*)d_in[7];
    const float* W3 = (const float*)d_in[8];
    const float* b3 = (const float*)d_in[9];
    float* out = (float*)d_out;

    int n = in_sizes[0] / D;       // 50000
    int E = in_sizes[1] / 2;       // 600000
    int G = out_size / D;          // 500
    const int* esrc = edge;
    const int* edst = edge + E;

    char* p = (char*)d_ws;
    __half* xw = (__half*)p;     p += (size_t)n * D * sizeof(float);  // slot kept fp32-sized
    float* h  = (float*)p;       p += (size_t)n * D * sizeof(float);
    float* dinv = (float*)p;     p += (size_t)n * sizeof(float);
    int* cnt = (int*)p;          p += (size_t)n * sizeof(int);
    int* rowstart = (int*)p;     p += (size_t)(n + 1) * sizeof(int);
    int* cursor = (int*)p;       p += (size_t)n * sizeof(int);
    int* csr_src = (int*)p;      p += (size_t)E * sizeof(int);
    int* bsum = (int*)p;         p += 256 * sizeof(int);
    int* boff = (int*)p;         p += 256 * sizeof(int);
    float* P = (float*)p;        p += (size_t)G * D * sizeof(float);
    float* cg = (float*)p;       p += (size_t)G * sizeof(float);
    int* mark = (int*)p;         p += (size_t)n * sizeof(int);
    int* act = (int*)p;          p += (size_t)n * sizeof(int);
    int* na = (int*)p;           p += sizeof(int);

    int PB = (n + 255) / 256;

    hipMemsetAsync(cnt, 0, (size_t)n * sizeof(int), stream);
    hipMemsetAsync(mark, 0, (size_t)n * sizeof(int), stream);
    hipMemsetAsync(P, 0, (size_t)G * D * sizeof(float), stream);
    hipMemsetAsync(cg, 0, (size_t)G * sizeof(float), stream);
    count_kernel<<<(E + 255) / 256, 256, 0, stream>>>(edst, cnt, E);
    psum_kernel<<<PB, 256, 0, stream>>>(cnt, bsum, n);
    bscan_kernel<<<1, 256, 0, stream>>>(bsum, boff, nullptr, PB);
    rows_kernel<<<PB, 256, 0, stream>>>(cnt, boff, rowstart, cursor, dinv, n, E);
    fill_kernel<<<(E + 255) / 256, 256, 0, stream>>>(esrc, edst, cursor, csr_src, E);
    // Active set S2 for layer 2
    mark_kernel<<<(n + 255) / 256, 256, 0, stream>>>(is_n, rowstart, csr_src, mark, n);
    psum_kernel<<<PB, 256, 0, stream>>>(mark, bsum, n);
    bscan_kernel<<<1, 256, 0, stream>>>(bsum, boff, na, PB);
    compact_kernel<<<PB, 256, 0, stream>>>(mark, boff, act, n);

    const int gblocks = 256;   // persistent, 1 block/CU (97.8 KB LDS)
    int ablocks = (n + 3) / 4;

    // Layer 1
    gemm_kernel<<<gblocks, 256, 0, stream>>>(x, W1, xw, n);
    agg_kernel<<<ablocks, 256, 0, stream>>>(xw, b1, dinv, rowstart, csr_src, h, n);
    // Layer 2 (only active nodes matter downstream)
    gemm_kernel<<<gblocks, 256, 0, stream>>>(h, W2, xw, n);
    agg_act_kernel<<<1024, 256, 0, stream>>>(xw, b2, dinv, rowstart, csr_src, act, na, h);
    // Layer 3: pool(A h2) first (linear), then tiny 500x128 GEMM
    agg_pool_kernel<<<ablocks, 256, 0, stream>>>(h, dinv, rowstart, csr_src,
                                                 is_n, batch, P, cg, n);
    pool_gemm_kernel<<<G, 64, 0, stream>>>(P, cg, W3, b3, out, G);
}

// Round 5
// 258.045 us; speedup vs baseline: 1.8681x; 1.0794x over previous
//
#include <hip/hip_runtime.h>
#include <hip/hip_fp16.h>

#define D 128

// ---------------- CSR build ----------------

__global__ void count_kernel(const int* __restrict__ dst, int* __restrict__ cnt, int E) {
    int e = blockIdx.x * blockDim.x + threadIdx.x;
    if (e < E) atomicAdd(&cnt[dst[e]], 1);
}

__global__ __launch_bounds__(256) void psum_kernel(const int* __restrict__ cnt,
                                                   int* __restrict__ bsum, int n) {
    __shared__ int s[256];
    int t = threadIdx.x;
    int i = blockIdx.x * 256 + t;
    s[t] = (i < n) ? cnt[i] : 0;
    __syncthreads();
    for (int off = 128; off > 0; off >>= 1) {
        if (t < off) s[t] += s[t + off];
        __syncthreads();
    }
    if (t == 0) bsum[blockIdx.x] = s[0];
}

// exclusive scan of block sums; optionally writes grand total to *tot
__global__ __launch_bounds__(256) void bscan_kernel(const int* __restrict__ bsum,
                                                    int* __restrict__ boff,
                                                    int* __restrict__ tot, int PB) {
    __shared__ int s[256];
    int t = threadIdx.x;
    int v = (t < PB) ? bsum[t] : 0;
    s[t] = v;
    __syncthreads();
    for (int off = 1; off < 256; off <<= 1) {
        int add = (t >= off) ? s[t - off] : 0;
        __syncthreads();
        s[t] += add;
        __syncthreads();
    }
    if (t < PB) boff[t] = s[t] - v;   // exclusive
    if (tot && t == PB - 1) tot[0] = s[t];
}

__global__ __launch_bounds__(256) void rows_kernel(const int* __restrict__ cnt,
                                                   const int* __restrict__ boff,
                                                   int* __restrict__ rowstart,
                                                   int* __restrict__ cursor,
                                                   float* __restrict__ dinv,
                                                   int n, int E) {
    __shared__ int s[256];
    int t = threadIdx.x;
    int i = blockIdx.x * 256 + t;
    int c = (i < n) ? cnt[i] : 0;
    s[t] = c;
    __syncthreads();
    for (int off = 1; off < 256; off <<= 1) {
        int add = (t >= off) ? s[t - off] : 0;
        __syncthreads();
        s[t] += add;
        __syncthreads();
    }
    if (i < n) {
        int excl = s[t] - c + boff[blockIdx.x];
        rowstart[i] = excl;
        cursor[i] = excl;
        dinv[i] = rsqrtf(1.0f + (float)c);   // deg = in-count + self loop
    }
    if (i == 0) rowstart[n] = E;
}

__global__ void fill_kernel(const int* __restrict__ src, const int* __restrict__ dst,
                            int* __restrict__ cursor, int* __restrict__ csr_src, int E) {
    int e = blockIdx.x * blockDim.x + threadIdx.x;
    if (e < E) {
        int d = dst[e];
        int pos = atomicAdd(&cursor[d], 1);
        csr_src[pos] = src[e];
    }
}

// ---------------- Active set for layer 2: S2 = {is_n} U N_in({is_n}) ----------------

__global__ void mark_kernel(const float* __restrict__ is_n,
                            const int* __restrict__ rowstart,
                            const int* __restrict__ csr_src,
                            int* __restrict__ mark, int n) {
    int v = blockIdx.x * blockDim.x + threadIdx.x;
    if (v >= n) return;
    if (is_n[v] == 0.f) return;
    mark[v] = 1;
    int e1 = rowstart[v + 1];
    for (int e = rowstart[v]; e < e1; e++) mark[csr_src[e]] = 1;
}

__global__ __launch_bounds__(256) void compact_kernel(const int* __restrict__ mark,
                                                      const int* __restrict__ boff,
                                                      int* __restrict__ act, int n) {
    __shared__ int s[256];
    int t = threadIdx.x;
    int i = blockIdx.x * 256 + t;
    int m = (i < n) ? mark[i] : 0;
    s[t] = m;
    __syncthreads();
    for (int off = 1; off < 256; off <<= 1) {
        int add = (t >= off) ? s[t - off] : 0;
        __syncthreads();
        s[t] += add;
        __syncthreads();
    }
    if (m) act[s[t] - 1 + boff[blockIdx.x]] = i;
}

// ---------------- GEMM: Y[M,128](fp16) = X[M,128](fp32) @ W[128,128] ----------------
// Only W in LDS (64 KB -> 2 blocks/CU, 8 waves/CU). X read directly from global:
// the 16 lanes sharing rr read identical addresses (HW broadcast-coalesced).
// No barrier in the main loop; register double-buffer prefetches next k-chunk.

union H4 { __half h[4]; float2 f2; };

__global__ __launch_bounds__(256, 2) void gemm_kernel(const float* __restrict__ X,
                                                      const float* __restrict__ Wg,
                                                      __half* __restrict__ Y, int M) {
    __shared__ float Ws[D * D];        // 64 KB
    int t = threadIdx.x;
    for (int i = t * 4; i < D * D; i += 1024) {
        *(float4*)&Ws[i] = *(const float4*)&Wg[i];
    }
    __syncthreads();
    int tc = t & 15;                   // cols 4tc..+3 and 64+4tc..+3
    int rr = t >> 4;                   // rows 4rr..4rr+3 of the 64-row tile
    int ntiles = (M + 63) >> 6;
    for (int tile = blockIdx.x; tile < ntiles; tile += gridDim.x) {
        int row0 = (tile << 6) + rr * 4;
        const float* xp[4];
#pragma unroll
        for (int i = 0; i < 4; i++) {
            int r = row0 + i;
            if (r > M - 1) r = M - 1;          // clamp (harmless dup reads)
            xp[i] = &X[(size_t)r * D];
        }
        float acc[4][8];
#pragma unroll
        for (int i = 0; i < 4; i++)
#pragma unroll
            for (int j = 0; j < 8; j++) acc[i][j] = 0.f;
        float4 cur[4];
#pragma unroll
        for (int i = 0; i < 4; i++) cur[i] = *(const float4*)&xp[i][0];
        for (int k = 0; k < D; k += 4) {
            int kn = (k + 4) & 127;            // wraps to 0 on last iter (dead value)
            float4 nxt[4];
#pragma unroll
            for (int i = 0; i < 4; i++) nxt[i] = *(const float4*)&xp[i][kn];
#pragma unroll
            for (int kk = 0; kk < 4; kk++) {
                float4 w0 = *(float4*)&Ws[(k + kk) * D + 4 * tc];
                float4 w1 = *(float4*)&Ws[(k + kk) * D + 64 + 4 * tc];
#pragma unroll
                for (int i = 0; i < 4; i++) {
                    float xv = (kk == 0) ? cur[i].x : (kk == 1) ? cur[i].y
                             : (kk == 2) ? cur[i].z : cur[i].w;
                    acc[i][0] += xv * w0.x; acc[i][1] += xv * w0.y;
                    acc[i][2] += xv * w0.z; acc[i][3] += xv * w0.w;
                    acc[i][4] += xv * w1.x; acc[i][5] += xv * w1.y;
                    acc[i][6] += xv * w1.z; acc[i][7] += xv * w1.w;
                }
            }
#pragma unroll
            for (int i = 0; i < 4; i++) cur[i] = nxt[i];
        }
#pragma unroll
        for (int i = 0; i < 4; i++) {
            int row = row0 + i;
            if (row < M) {
                __half* py = &Y[(size_t)row * D];
                H4 o0, o1;
#pragma unroll
                for (int j = 0; j < 4; j++) {
                    o0.h[j] = __float2half(acc[i][j]);
                    o1.h[j] = __float2half(acc[i][4 + j]);
                }
                *(float2*)&py[4 * tc] = o0.f2;
                *(float2*)&py[64 + 4 * tc] = o1.f2;
            }
        }
    }
}

// ---------------- Aggregation (full): fp16 gather, fp32 out, relu ----------------

__global__ __launch_bounds__(256) void agg_kernel(const __half* __restrict__ XW,
                                                  const float* __restrict__ bias,
                                                  const float* __restrict__ dinv,
                                                  const int* __restrict__ rowstart,
                                                  const int* __restrict__ csr_src,
                                                  float* __restrict__ out, int n) {
    int wid = threadIdx.x >> 6;
    int lane = threadIdx.x & 63;
    int v = blockIdx.x * 4 + wid;
    if (v >= n) return;
    float dv = dinv[v];
    int c = lane * 2;
    float2 bb = *(const float2*)&bias[c];
    float2 xv = __half22float2(*(const __half2*)&XW[(size_t)v * D + c]);
    float sv = dv * dv;
    float2 acc = {bb.x + sv * xv.x, bb.y + sv * xv.y};
    int e0 = rowstart[v], e1 = rowstart[v + 1];
    int e = e0;
    for (; e + 1 < e1; e += 2) {
        int u0 = csr_src[e];
        int u1 = csr_src[e + 1];
        float n0 = dinv[u0] * dv;
        float n1 = dinv[u1] * dv;
        float2 x0 = __half22float2(*(const __half2*)&XW[(size_t)u0 * D + c]);
        float2 x1 = __half22float2(*(const __half2*)&XW[(size_t)u1 * D + c]);
        acc.x += n0 * x0.x + n1 * x1.x;
        acc.y += n0 * x0.y + n1 * x1.y;
    }
    if (e < e1) {
        int u = csr_src[e];
        float nv = dinv[u] * dv;
        float2 xu = __half22float2(*(const __half2*)&XW[(size_t)u * D + c]);
        acc.x += nv * xu.x;
        acc.y += nv * xu.y;
    }
    acc.x = fmaxf(acc.x, 0.f);
    acc.y = fmaxf(acc.y, 0.f);
    *(float2*)&out[(size_t)v * D + c] = acc;
}

// ---------------- Aggregation (active set only), grid-strided waves ----------------

__global__ __launch_bounds__(256) void agg_act_kernel(const __half* __restrict__ XW,
                                                      const float* __restrict__ bias,
                                                      const float* __restrict__ dinv,
                                                      const int* __restrict__ rowstart,
                                                      const int* __restrict__ csr_src,
                                                      const int* __restrict__ act,
                                                      const int* __restrict__ na_p,
                                                      float* __restrict__ out) {
    int wid = threadIdx.x >> 6;
    int lane = threadIdx.x & 63;
    int na = na_p[0];
    int stride = gridDim.x * 4;
    int c = lane * 2;
    float2 bb = *(const float2*)&bias[c];
    for (int i = blockIdx.x * 4 + wid; i < na; i += stride) {
        int v = act[i];
        float dv = dinv[v];
        float2 xv = __half22float2(*(const __half2*)&XW[(size_t)v * D + c]);
        float sv = dv * dv;
        float2 acc = {bb.x + sv * xv.x, bb.y + sv * xv.y};
        int e0 = rowstart[v], e1 = rowstart[v + 1];
        int e = e0;
        for (; e + 1 < e1; e += 2) {
            int u0 = csr_src[e];
            int u1 = csr_src[e + 1];
            float n0 = dinv[u0] * dv;
            float n1 = dinv[u1] * dv;
            float2 x0 = __half22float2(*(const __half2*)&XW[(size_t)u0 * D + c]);
            float2 x1 = __half22float2(*(const __half2*)&XW[(size_t)u1 * D + c]);
            acc.x += n0 * x0.x + n1 * x1.x;
            acc.y += n0 * x0.y + n1 * x1.y;
        }
        if (e < e1) {
            int u = csr_src[e];
            float nv = dinv[u] * dv;
            float2 xu = __half22float2(*(const __half2*)&XW[(size_t)u * D + c]);
            acc.x += nv * xu.x;
            acc.y += nv * xu.y;
        }
        acc.x = fmaxf(acc.x, 0.f);
        acc.y = fmaxf(acc.y, 0.f);
        *(float2*)&out[(size_t)v * D + c] = acc;
    }
}

// ---------------- Layer 3 pooled aggregation + tiny GEMM ----------------

__global__ __launch_bounds__(256) void agg_pool_kernel(const float* __restrict__ H,
                                                       const float* __restrict__ dinv,
                                                       const int* __restrict__ rowstart,
                                                       const int* __restrict__ csr_src,
                                                       const float* __restrict__ is_n,
                                                       const int* __restrict__ batch,
                                                       float* __restrict__ P,
                                                       float* __restrict__ cg, int n) {
    int wid = threadIdx.x >> 6;
    int lane = threadIdx.x & 63;
    int v = blockIdx.x * 4 + wid;
    if (v >= n) return;
    float w_is = is_n[v];
    if (w_is == 0.f) return;           // wave-uniform exit
    float dv = dinv[v];
    int c = lane * 2;
    float2 hv = *(const float2*)&H[(size_t)v * D + c];
    float sv = dv * dv;
    float2 acc = {sv * hv.x, sv * hv.y};
    int e0 = rowstart[v], e1 = rowstart[v + 1];
    for (int e = e0; e < e1; e++) {
        int u = csr_src[e];
        float nv = dinv[u] * dv;
        float2 hu = *(const float2*)&H[(size_t)u * D + c];
        acc.x += nv * hu.x;
        acc.y += nv * hu.y;
    }
    int g = batch[v];
    atomicAdd(&P[(size_t)g * D + c], w_is * acc.x);
    atomicAdd(&P[(size_t)g * D + c + 1], w_is * acc.y);
    if (lane == 0) atomicAdd(&cg[g], w_is);
}

__global__ __launch_bounds__(64) void pool_gemm_kernel(const float* __restrict__ P,
                                                       const float* __restrict__ cg,
                                                       const float* __restrict__ W,
                                                       const float* __restrict__ b,
                                                       float* __restrict__ out, int G) {
    int g = blockIdx.x;
    if (g >= G) return;
    int c = threadIdx.x * 2;
    float2 acc = {0.f, 0.f};
    const float* pr = &P[(size_t)g * D];
#pragma unroll 4
    for (int k = 0; k < D; k++) {
        float pk = pr[k];
        float2 w = *(const float2*)&W[k * D + c];
        acc.x += pk * w.x;
        acc.y += pk * w.y;
    }
    float s = 0.5f * cg[g];
    float2 bb = *(const float2*)&b[c];
    out[(size_t)g * D + c]     = 0.5f * acc.x + s * bb.x;
    out[(size_t)g * D + c + 1] = 0.5f * acc.y + s * bb.y;
}

// ---------------- launch ----------------

extern "C" void kernel_launch(void* const* d_in, const int* in_sizes, int n_in,
                              void* d_out, int out_size, void* d_ws, size_t ws_size,
                              hipStream_t stream) {
    const float* x     = (const float*)d_in[0];
    const int*   edge  = (const int*)d_in[1];
    const float* is_n  = (const float*)d_in[2];
    const int*   batch = (const int*)d_in[3];
    const float* W1 = (const float*)d_in[4];
    const float* b1 = (const float*)d_in[5];
    const float* W2 = (const float*)d_in[6];
    const float* b2 = (const float*)d_in[7];
    const float* W3 = (const float*)d_in[8];
    const float* b3 = (const float*)d_in[9];
    float* out = (float*)d_out;

    int n = in_sizes[0] / D;       // 50000
    int E = in_sizes[1] / 2;       // 600000
    int G = out_size / D;          // 500
    const int* esrc = edge;
    const int* edst = edge + E;

    char* p = (char*)d_ws;
    __half* xw = (__half*)p;     p += (size_t)n * D * sizeof(float);  // slot kept fp32-sized
    float* h  = (float*)p;       p += (size_t)n * D * sizeof(float);
    float* dinv = (float*)p;     p += (size_t)n * sizeof(float);
    int* cnt = (int*)p;          p += (size_t)n * sizeof(int);
    int* rowstart = (int*)p;     p += (size_t)(n + 1) * sizeof(int);
    int* cursor = (int*)p;       p += (size_t)n * sizeof(int);
    int* csr_src = (int*)p;      p += (size_t)E * sizeof(int);
    int* bsum = (int*)p;         p += 256 * sizeof(int);
    int* boff = (int*)p;         p += 256 * sizeof(int);
    float* P = (float*)p;        p += (size_t)G * D * sizeof(float);
    float* cg = (float*)p;       p += (size_t)G * sizeof(float);
    int* mark = (int*)p;         p += (size_t)n * sizeof(int);
    int* act = (int*)p;          p += (size_t)n * sizeof(int);
    int* na = (int*)p;           p += sizeof(int);

    int PB = (n + 255) / 256;

    hipMemsetAsync(cnt, 0, (size_t)n * sizeof(int), stream);
    hipMemsetAsync(mark, 0, (size_t)n * sizeof(int), stream);
    hipMemsetAsync(P, 0, (size_t)G * D * sizeof(float), stream);
    hipMemsetAsync(cg, 0, (size_t)G * sizeof(float), stream);
    count_kernel<<<(E + 255) / 256, 256, 0, stream>>>(edst, cnt, E);
    psum_kernel<<<PB, 256, 0, stream>>>(cnt, bsum, n);
    bscan_kernel<<<1, 256, 0, stream>>>(bsum, boff, nullptr, PB);
    rows_kernel<<<PB, 256, 0, stream>>>(cnt, boff, rowstart, cursor, dinv, n, E);
    fill_kernel<<<(E + 255) / 256, 256, 0, stream>>>(esrc, edst, cursor, csr_src, E);
    // Active set S2 for layer 2
    mark_kernel<<<(n + 255) / 256, 256, 0, stream>>>(is_n, rowstart, csr_src, mark, n);
    psum_kernel<<<PB, 256, 0, stream>>>(mark, bsum, n);
    bscan_kernel<<<1, 256, 0, stream>>>(bsum, boff, na, PB);
    compact_kernel<<<PB, 256, 0, stream>>>(mark, boff, act, n);

    const int gblocks = 512;   // 2 blocks/CU (64 KB LDS each)
    int ablocks = (n + 3) / 4;

    // Layer 1
    gemm_kernel<<<gblocks, 256, 0, stream>>>(x, W1, xw, n);
    agg_kernel<<<ablocks, 256, 0, stream>>>(xw, b1, dinv, rowstart, csr_src, h, n);
    // Layer 2 (only active nodes matter downstream)
    gemm_kernel<<<gblocks, 256, 0, stream>>>(h, W2, xw, n);
    agg_act_kernel<<<1024, 256, 0, stream>>>(xw, b2, dinv, rowstart, csr_src, act, na, h);
    // Layer 3: pool(A h2) first (linear), then tiny 500x128 GEMM
    agg_pool_kernel<<<ablocks, 256, 0, stream>>>(h, dinv, rowstart, csr_src,
                                                 is_n, batch, P, cg, n);
    pool_gemm_kernel<<<G, 64, 0, stream>>>(P, cg, W3, b3, out, G);
}

// Round 6
// 218.330 us; speedup vs baseline: 2.2079x; 1.1819x over previous
//
#include <hip/hip_runtime.h>
#include <hip/hip_fp16.h>
#include <type_traits>

#define D 128

typedef __attribute__((ext_vector_type(8))) _Float16 f16x8;
typedef __attribute__((ext_vector_type(4))) float f32x4;

// ---------------- CSR build ----------------

__global__ void count_kernel(const int* __restrict__ dst, int* __restrict__ cnt, int E) {
    int e = blockIdx.x * blockDim.x + threadIdx.x;
    if (e < E) atomicAdd(&cnt[dst[e]], 1);
}

__global__ __launch_bounds__(256) void psum_kernel(const int* __restrict__ cnt,
                                                   int* __restrict__ bsum, int n) {
    __shared__ int s[256];
    int t = threadIdx.x;
    int i = blockIdx.x * 256 + t;
    s[t] = (i < n) ? cnt[i] : 0;
    __syncthreads();
    for (int off = 128; off > 0; off >>= 1) {
        if (t < off) s[t] += s[t + off];
        __syncthreads();
    }
    if (t == 0) bsum[blockIdx.x] = s[0];
}

__global__ __launch_bounds__(256) void bscan_kernel(const int* __restrict__ bsum,
                                                    int* __restrict__ boff,
                                                    int* __restrict__ tot, int PB) {
    __shared__ int s[256];
    int t = threadIdx.x;
    int v = (t < PB) ? bsum[t] : 0;
    s[t] = v;
    __syncthreads();
    for (int off = 1; off < 256; off <<= 1) {
        int add = (t >= off) ? s[t - off] : 0;
        __syncthreads();
        s[t] += add;
        __syncthreads();
    }
    if (t < PB) boff[t] = s[t] - v;   // exclusive
    if (tot && t == PB - 1) tot[0] = s[t];
}

__global__ __launch_bounds__(256) void rows_kernel(const int* __restrict__ cnt,
                                                   const int* __restrict__ boff,
                                                   int* __restrict__ rowstart,
                                                   int* __restrict__ cursor,
                                                   float* __restrict__ dinv,
                                                   int n, int E) {
    __shared__ int s[256];
    int t = threadIdx.x;
    int i = blockIdx.x * 256 + t;
    int c = (i < n) ? cnt[i] : 0;
    s[t] = c;
    __syncthreads();
    for (int off = 1; off < 256; off <<= 1) {
        int add = (t >= off) ? s[t - off] : 0;
        __syncthreads();
        s[t] += add;
        __syncthreads();
    }
    if (i < n) {
        int excl = s[t] - c + boff[blockIdx.x];
        rowstart[i] = excl;
        cursor[i] = excl;
        dinv[i] = rsqrtf(1.0f + (float)c);   // deg = in-count + self loop
    }
    if (i == 0) rowstart[n] = E;
}

__global__ void fill_kernel(const int* __restrict__ src, const int* __restrict__ dst,
                            int* __restrict__ cursor, int* __restrict__ csr_src, int E) {
    int e = blockIdx.x * blockDim.x + threadIdx.x;
    if (e < E) {
        int d = dst[e];
        int pos = atomicAdd(&cursor[d], 1);
        csr_src[pos] = src[e];
    }
}

// ---------------- Active set for layer 2 ----------------

__global__ void mark_kernel(const float* __restrict__ is_n,
                            const int* __restrict__ rowstart,
                            const int* __restrict__ csr_src,
                            int* __restrict__ mark, int n) {
    int v = blockIdx.x * blockDim.x + threadIdx.x;
    if (v >= n) return;
    if (is_n[v] == 0.f) return;
    mark[v] = 1;
    int e1 = rowstart[v + 1];
    for (int e = rowstart[v]; e < e1; e++) mark[csr_src[e]] = 1;
}

__global__ __launch_bounds__(256) void compact_kernel(const int* __restrict__ mark,
                                                      const int* __restrict__ boff,
                                                      int* __restrict__ act, int n) {
    __shared__ int s[256];
    int t = threadIdx.x;
    int i = blockIdx.x * 256 + t;
    int m = (i < n) ? mark[i] : 0;
    s[t] = m;
    __syncthreads();
    for (int off = 1; off < 256; off <<= 1) {
        int add = (t >= off) ? s[t - off] : 0;
        __syncthreads();
        s[t] += add;
        __syncthreads();
    }
    if (m) act[s[t] - 1 + boff[blockIdx.x]] = i;
}

// ---------------- W pack: fragment-linear fp16 for MFMA B-operand ----------------
// Wp[((ks*8+nt)*64+l)*8 + j] = W[ks*32 + (l>>4)*8 + j][nt*16 + (l&15)]
// (B layout for mfma_f32_16x16x32: lane l holds B[k=(l>>4)*8+j][n=l&15])

__global__ __launch_bounds__(256) void packw_kernel(const float* __restrict__ W1,
                                                    const float* __restrict__ W2,
                                                    const float* __restrict__ W3,
                                                    __half* __restrict__ Wp) {
    int gid = blockIdx.x * 256 + threadIdx.x;     // 0..6143
    int m = gid >> 11;
    int idx = gid & 2047;
    const float* W = (m == 0) ? W1 : (m == 1) ? W2 : W3;
    int l = idx & 63;
    int nt = (idx >> 6) & 7;
    int ks = idx >> 9;
    int kb = ks * 32 + (l >> 4) * 8;
    int col = nt * 16 + (l & 15);
    __half tmp[8];
#pragma unroll
    for (int j = 0; j < 8; j++) tmp[j] = __float2half(W[(kb + j) * D + col]);
    *(float4*)&Wp[(size_t)gid * 8] = *(float4*)tmp;
}

// ---------------- MFMA GEMM: Y[M,128](fp16) = X[M,128] @ W ----------------
// B held entirely in VGPRs (32 frags), loaded once per persistent block.
// Per wave-tile: 16 rows; 4 k-steps x 8 n-tiles = 32 MFMA. No LDS, no barriers.

template <typename AT>
__global__ __launch_bounds__(256, 2) void gemm_mfma_kernel(const AT* __restrict__ X,
                                                           const __half* __restrict__ Wp,
                                                           __half* __restrict__ Y, int M) {
    int lane = threadIdx.x & 63;
    int wid = threadIdx.x >> 6;
    f16x8 bf[4][8];
    {
        const float4* wp = (const float4*)Wp;
#pragma unroll
        for (int ks = 0; ks < 4; ks++)
#pragma unroll
            for (int nt = 0; nt < 8; nt++) {
                float4 t = wp[(ks * 8 + nt) * 64 + lane];
                bf[ks][nt] = *(f16x8*)&t;
            }
    }
    int row_l = lane & 15;
    int kgrp = lane >> 4;          // 0..3
    int tiles = M >> 4;            // M divisible by 16
    int nw = gridDim.x * 4;
    for (int tile = blockIdx.x * 4 + wid; tile < tiles; tile += nw) {
        int row0 = tile << 4;
        const AT* ap = X + (size_t)(row0 + row_l) * D + kgrp * 8;
        f32x4 acc[8];
#pragma unroll
        for (int nt = 0; nt < 8; nt++) acc[nt] = (f32x4){0.f, 0.f, 0.f, 0.f};
#pragma unroll
        for (int ks = 0; ks < 4; ks++) {
            f16x8 a;
            if constexpr (std::is_same<AT, float>::value) {
                float4 a0 = *(const float4*)(ap + ks * 32);
                float4 a1 = *(const float4*)(ap + ks * 32 + 4);
                a[0] = (_Float16)a0.x; a[1] = (_Float16)a0.y;
                a[2] = (_Float16)a0.z; a[3] = (_Float16)a0.w;
                a[4] = (_Float16)a1.x; a[5] = (_Float16)a1.y;
                a[6] = (_Float16)a1.z; a[7] = (_Float16)a1.w;
            } else {
                float4 t = *(const float4*)(const void*)(ap + ks * 32);
                a = *(f16x8*)&t;
            }
#pragma unroll
            for (int nt = 0; nt < 8; nt++)
                acc[nt] = __builtin_amdgcn_mfma_f32_16x16x32_f16(a, bf[ks][nt],
                                                                 acc[nt], 0, 0, 0);
        }
        // C/D: col = lane&15, row = (lane>>4)*4 + reg
        __half* yb = Y + (size_t)row0 * D;
#pragma unroll
        for (int nt = 0; nt < 8; nt++)
#pragma unroll
            for (int r = 0; r < 4; r++)
                yb[(size_t)(kgrp * 4 + r) * D + nt * 16 + row_l] =
                    __float2half(acc[nt][r]);
    }
}

// ---------------- Aggregation (full): fp16 gather, fp16 out, relu ----------------

__global__ __launch_bounds__(256) void agg_kernel(const __half* __restrict__ XW,
                                                  const float* __restrict__ bias,
                                                  const float* __restrict__ dinv,
                                                  const int* __restrict__ rowstart,
                                                  const int* __restrict__ csr_src,
                                                  __half* __restrict__ out, int n) {
    int wid = threadIdx.x >> 6;
    int lane = threadIdx.x & 63;
    int v = blockIdx.x * 4 + wid;
    if (v >= n) return;
    float dv = dinv[v];
    int c = lane * 2;
    float2 bb = *(const float2*)&bias[c];
    float2 xv = __half22float2(*(const __half2*)&XW[(size_t)v * D + c]);
    float sv = dv * dv;
    float2 acc = {bb.x + sv * xv.x, bb.y + sv * xv.y};
    int e0 = rowstart[v], e1 = rowstart[v + 1];
    int e = e0;
    for (; e + 1 < e1; e += 2) {
        int u0 = csr_src[e];
        int u1 = csr_src[e + 1];
        float n0 = dinv[u0] * dv;
        float n1 = dinv[u1] * dv;
        float2 x0 = __half22float2(*(const __half2*)&XW[(size_t)u0 * D + c]);
        float2 x1 = __half22float2(*(const __half2*)&XW[(size_t)u1 * D + c]);
        acc.x += n0 * x0.x + n1 * x1.x;
        acc.y += n0 * x0.y + n1 * x1.y;
    }
    if (e < e1) {
        int u = csr_src[e];
        float nv = dinv[u] * dv;
        float2 xu = __half22float2(*(const __half2*)&XW[(size_t)u * D + c]);
        acc.x += nv * xu.x;
        acc.y += nv * xu.y;
    }
    __half2 o;
    o.x = __float2half(fmaxf(acc.x, 0.f));
    o.y = __float2half(fmaxf(acc.y, 0.f));
    *(__half2*)&out[(size_t)v * D + c] = o;
}

// ---------------- Aggregation (active set only) ----------------

__global__ __launch_bounds__(256) void agg_act_kernel(const __half* __restrict__ XW,
                                                      const float* __restrict__ bias,
                                                      const float* __restrict__ dinv,
                                                      const int* __restrict__ rowstart,
                                                      const int* __restrict__ csr_src,
                                                      const int* __restrict__ act,
                                                      const int* __restrict__ na_p,
                                                      __half* __restrict__ out) {
    int wid = threadIdx.x >> 6;
    int lane = threadIdx.x & 63;
    int na = na_p[0];
    int stride = gridDim.x * 4;
    int c = lane * 2;
    float2 bb = *(const float2*)&bias[c];
    for (int i = blockIdx.x * 4 + wid; i < na; i += stride) {
        int v = act[i];
        float dv = dinv[v];
        float2 xv = __half22float2(*(const __half2*)&XW[(size_t)v * D + c]);
        float sv = dv * dv;
        float2 acc = {bb.x + sv * xv.x, bb.y + sv * xv.y};
        int e0 = rowstart[v], e1 = rowstart[v + 1];
        int e = e0;
        for (; e + 1 < e1; e += 2) {
            int u0 = csr_src[e];
            int u1 = csr_src[e + 1];
            float n0 = dinv[u0] * dv;
            float n1 = dinv[u1] * dv;
            float2 x0 = __half22float2(*(const __half2*)&XW[(size_t)u0 * D + c]);
            float2 x1 = __half22float2(*(const __half2*)&XW[(size_t)u1 * D + c]);
            acc.x += n0 * x0.x + n1 * x1.x;
            acc.y += n0 * x0.y + n1 * x1.y;
        }
        if (e < e1) {
            int u = csr_src[e];
            float nv = dinv[u] * dv;
            float2 xu = __half22float2(*(const __half2*)&XW[(size_t)u * D + c]);
            acc.x += nv * xu.x;
            acc.y += nv * xu.y;
        }
        __half2 o;
        o.x = __float2half(fmaxf(acc.x, 0.f));
        o.y = __float2half(fmaxf(acc.y, 0.f));
        *(__half2*)&out[(size_t)v * D + c] = o;
    }
}

// ---------------- Layer 3 pooled aggregation + tiny GEMM ----------------

__global__ __launch_bounds__(256) void agg_pool_kernel(const __half* __restrict__ H,
                                                       const float* __restrict__ dinv,
                                                       const int* __restrict__ rowstart,
                                                       const int* __restrict__ csr_src,
                                                       const float* __restrict__ is_n,
                                                       const int* __restrict__ batch,
                                                       float* __restrict__ P,
                                                       float* __restrict__ cg, int n) {
    int wid = threadIdx.x >> 6;
    int lane = threadIdx.x & 63;
    int v = blockIdx.x * 4 + wid;
    if (v >= n) return;
    float w_is = is_n[v];
    if (w_is == 0.f) return;           // wave-uniform exit
    float dv = dinv[v];
    int c = lane * 2;
    float2 hv = __half22float2(*(const __half2*)&H[(size_t)v * D + c]);
    float sv = dv * dv;
    float2 acc = {sv * hv.x, sv * hv.y};
    int e0 = rowstart[v], e1 = rowstart[v + 1];
    for (int e = e0; e < e1; e++) {
        int u = csr_src[e];
        float nv = dinv[u] * dv;
        float2 hu = __half22float2(*(const __half2*)&H[(size_t)u * D + c]);
        acc.x += nv * hu.x;
        acc.y += nv * hu.y;
    }
    int g = batch[v];
    atomicAdd(&P[(size_t)g * D + c], w_is * acc.x);
    atomicAdd(&P[(size_t)g * D + c + 1], w_is * acc.y);
    if (lane == 0) atomicAdd(&cg[g], w_is);
}

__global__ __launch_bounds__(64) void pool_gemm_kernel(const float* __restrict__ P,
                                                       const float* __restrict__ cg,
                                                       const float* __restrict__ W,
                                                       const float* __restrict__ b,
                                                       float* __restrict__ out, int G) {
    int g = blockIdx.x;
    if (g >= G) return;
    int c = threadIdx.x * 2;
    float2 acc = {0.f, 0.f};
    const float* pr = &P[(size_t)g * D];
#pragma unroll 4
    for (int k = 0; k < D; k++) {
        float pk = pr[k];
        float2 w = *(const float2*)&W[k * D + c];
        acc.x += pk * w.x;
        acc.y += pk * w.y;
    }
    float s = 0.5f * cg[g];
    float2 bb = *(const float2*)&b[c];
    out[(size_t)g * D + c]     = 0.5f * acc.x + s * bb.x;
    out[(size_t)g * D + c + 1] = 0.5f * acc.y + s * bb.y;
}

// ---------------- launch ----------------

extern "C" void kernel_launch(void* const* d_in, const int* in_sizes, int n_in,
                              void* d_out, int out_size, void* d_ws, size_t ws_size,
                              hipStream_t stream) {
    const float* x     = (const float*)d_in[0];
    const int*   edge  = (const int*)d_in[1];
    const float* is_n  = (const float*)d_in[2];
    const int*   batch = (const int*)d_in[3];
    const float* W1 = (const float*)d_in[4];
    const float* b1 = (const float*)d_in[5];
    const float* W2 = (const float*)d_in[6];
    const float* b2 = (const float*)d_in[7];
    const float* W3 = (const float*)d_in[8];
    const float* b3 = (const float*)d_in[9];
    float* out = (float*)d_out;

    int n = in_sizes[0] / D;       // 50000
    int E = in_sizes[1] / 2;       // 600000
    int G = out_size / D;          // 500
    const int* esrc = edge;
    const int* edst = edge + E;

    char* p = (char*)d_ws;
    __half* xw = (__half*)p;     p += (size_t)n * D * sizeof(float);
    __half* h  = (__half*)p;     p += (size_t)n * D * sizeof(float);
    float* dinv = (float*)p;     p += (size_t)n * sizeof(float);
    int* cnt = (int*)p;          p += (size_t)n * sizeof(int);
    int* rowstart = (int*)p;     p += (size_t)(n + 1) * sizeof(int);
    int* cursor = (int*)p;       p += (size_t)n * sizeof(int);
    int* csr_src = (int*)p;      p += (size_t)E * sizeof(int);
    int* bsum = (int*)p;         p += 256 * sizeof(int);
    int* boff = (int*)p;         p += 256 * sizeof(int);
    float* P = (float*)p;        p += (size_t)G * D * sizeof(float);
    float* cg = (float*)p;       p += (size_t)G * sizeof(float);
    int* mark = (int*)p;         p += (size_t)n * sizeof(int);
    int* act = (int*)p;          p += (size_t)n * sizeof(int);
    int* na = (int*)p;           p += 4 * sizeof(int);
    __half* Wp = (__half*)p;     p += (size_t)3 * D * D * sizeof(__half);

    int PB = (n + 255) / 256;

    hipMemsetAsync(cnt, 0, (size_t)n * sizeof(int), stream);
    hipMemsetAsync(mark, 0, (size_t)n * sizeof(int), stream);
    hipMemsetAsync(P, 0, (size_t)G * D * sizeof(float), stream);
    hipMemsetAsync(cg, 0, (size_t)G * sizeof(float), stream);
    packw_kernel<<<24, 256, 0, stream>>>(W1, W2, W3, Wp);
    count_kernel<<<(E + 255) / 256, 256, 0, stream>>>(edst, cnt, E);
    psum_kernel<<<PB, 256, 0, stream>>>(cnt, bsum, n);
    bscan_kernel<<<1, 256, 0, stream>>>(bsum, boff, nullptr, PB);
    rows_kernel<<<PB, 256, 0, stream>>>(cnt, boff, rowstart, cursor, dinv, n, E);
    fill_kernel<<<(E + 255) / 256, 256, 0, stream>>>(esrc, edst, cursor, csr_src, E);
    // Active set S2 for layer 2
    mark_kernel<<<(n + 255) / 256, 256, 0, stream>>>(is_n, rowstart, csr_src, mark, n);
    psum_kernel<<<PB, 256, 0, stream>>>(mark, bsum, n);
    bscan_kernel<<<1, 256, 0, stream>>>(bsum, boff, na, PB);
    compact_kernel<<<PB, 256, 0, stream>>>(mark, boff, act, n);

    int ablocks = (n + 3) / 4;

    // Layer 1 (A = fp32 x, converted in-register)
    gemm_mfma_kernel<float><<<512, 256, 0, stream>>>(x, Wp, xw, n);
    agg_kernel<<<ablocks, 256, 0, stream>>>(xw, b1, dinv, rowstart, csr_src, h, n);
    // Layer 2 (A = fp16 h1)
    gemm_mfma_kernel<__half><<<512, 256, 0, stream>>>(h, Wp + D * D, xw, n);
    agg_act_kernel<<<1024, 256, 0, stream>>>(xw, b2, dinv, rowstart, csr_src, act, na, h);
    // Layer 3: pool(A h2) first (linear), then tiny 500x128 GEMM (fp32 W3)
    agg_pool_kernel<<<ablocks, 256, 0, stream>>>(h, dinv, rowstart, csr_src,
                                                 is_n, batch, P, cg, n);
    pool_gemm_kernel<<<G, 64, 0, stream>>>(P, cg, W3, b3, out, G);
}

// Round 7
// 185.358 us; speedup vs baseline: 2.6006x; 1.1779x over previous
//
#include <hip/hip_runtime.h>
#include <hip/hip_fp16.h>
#include <type_traits>

#define D 128

typedef __attribute__((ext_vector_type(8))) _Float16 f16x8;
typedef __attribute__((ext_vector_type(4))) float f32x4;

// ---------------- CSR build ----------------

// count in-degree; also mark src nodes of edges whose dst is a neighbor-node
__global__ void count_kernel(const int* __restrict__ src, const int* __restrict__ dst,
                             const float* __restrict__ is_n,
                             int* __restrict__ cnt, int* __restrict__ mark, int E) {
    int e = blockIdx.x * blockDim.x + threadIdx.x;
    if (e < E) {
        int d = dst[e];
        atomicAdd(&cnt[d], 1);
        if (is_n[d] != 0.f) mark[src[e]] = 1;
    }
}

__global__ __launch_bounds__(256) void psum_kernel(const int* __restrict__ cnt,
                                                   int* __restrict__ bsum, int n) {
    __shared__ int s[256];
    int t = threadIdx.x;
    int i = blockIdx.x * 256 + t;
    s[t] = (i < n) ? cnt[i] : 0;
    __syncthreads();
    for (int off = 128; off > 0; off >>= 1) {
        if (t < off) s[t] += s[t + off];
        __syncthreads();
    }
    if (t == 0) bsum[blockIdx.x] = s[0];
}

// psum over (mark[i] | is_n[i]!=0)
__global__ __launch_bounds__(256) void psum2_kernel(const int* __restrict__ mark,
                                                    const float* __restrict__ is_n,
                                                    int* __restrict__ bsum, int n) {
    __shared__ int s[256];
    int t = threadIdx.x;
    int i = blockIdx.x * 256 + t;
    s[t] = (i < n) ? (mark[i] | (is_n[i] != 0.f ? 1 : 0)) : 0;
    __syncthreads();
    for (int off = 128; off > 0; off >>= 1) {
        if (t < off) s[t] += s[t + off];
        __syncthreads();
    }
    if (t == 0) bsum[blockIdx.x] = s[0];
}

__global__ __launch_bounds__(256) void bscan_kernel(const int* __restrict__ bsum,
                                                    int* __restrict__ boff,
                                                    int* __restrict__ tot, int PB) {
    __shared__ int s[256];
    int t = threadIdx.x;
    int v = (t < PB) ? bsum[t] : 0;
    s[t] = v;
    __syncthreads();
    for (int off = 1; off < 256; off <<= 1) {
        int add = (t >= off) ? s[t - off] : 0;
        __syncthreads();
        s[t] += add;
        __syncthreads();
    }
    if (t < PB) boff[t] = s[t] - v;   // exclusive
    if (tot && t == PB - 1) tot[0] = s[t];
}

__global__ __launch_bounds__(256) void rows_kernel(const int* __restrict__ cnt,
                                                   const int* __restrict__ boff,
                                                   int* __restrict__ rowstart,
                                                   int* __restrict__ cursor,
                                                   float* __restrict__ dinv,
                                                   int n, int E) {
    __shared__ int s[256];
    int t = threadIdx.x;
    int i = blockIdx.x * 256 + t;
    int c = (i < n) ? cnt[i] : 0;
    s[t] = c;
    __syncthreads();
    for (int off = 1; off < 256; off <<= 1) {
        int add = (t >= off) ? s[t - off] : 0;
        __syncthreads();
        s[t] += add;
        __syncthreads();
    }
    if (i < n) {
        int excl = s[t] - c + boff[blockIdx.x];
        rowstart[i] = excl;
        cursor[i] = excl;
        dinv[i] = rsqrtf(1.0f + (float)c);   // deg = in-count + self loop
    }
    if (i == 0) rowstart[n] = E;
}

__global__ void fill_kernel(const int* __restrict__ src, const int* __restrict__ dst,
                            int* __restrict__ cursor, int* __restrict__ csr_src, int E) {
    int e = blockIdx.x * blockDim.x + threadIdx.x;
    if (e < E) {
        int d = dst[e];
        int pos = atomicAdd(&cursor[d], 1);
        csr_src[pos] = src[e];
    }
}

__global__ __launch_bounds__(256) void compact_kernel(const int* __restrict__ mark,
                                                      const float* __restrict__ is_n,
                                                      const int* __restrict__ boff,
                                                      int* __restrict__ act, int n) {
    __shared__ int s[256];
    int t = threadIdx.x;
    int i = blockIdx.x * 256 + t;
    int m = (i < n) ? (mark[i] | (is_n[i] != 0.f ? 1 : 0)) : 0;
    s[t] = m;
    __syncthreads();
    for (int off = 1; off < 256; off <<= 1) {
        int add = (t >= off) ? s[t - off] : 0;
        __syncthreads();
        s[t] += add;
        __syncthreads();
    }
    if (m) act[s[t] - 1 + boff[blockIdx.x]] = i;
}

// ---------------- W pack: fragment-linear fp16 for MFMA B-operand ----------------

__global__ __launch_bounds__(256) void packw_kernel(const float* __restrict__ W1,
                                                    const float* __restrict__ W2,
                                                    const float* __restrict__ W3,
                                                    __half* __restrict__ Wp) {
    int gid = blockIdx.x * 256 + threadIdx.x;     // 0..6143
    int m = gid >> 11;
    int idx = gid & 2047;
    const float* W = (m == 0) ? W1 : (m == 1) ? W2 : W3;
    int l = idx & 63;
    int nt = (idx >> 6) & 7;
    int ks = idx >> 9;
    int kb = ks * 32 + (l >> 4) * 8;
    int col = nt * 16 + (l & 15);
    __half tmp[8];
#pragma unroll
    for (int j = 0; j < 8; j++) tmp[j] = __float2half(W[(kb + j) * D + col]);
    *(float4*)&Wp[(size_t)gid * 8] = *(float4*)tmp;
}

// ---------------- MFMA GEMM: Y[M,128](fp16) = dinv[r] * (X[M,128] @ W) ----------------
// B in VGPRs; epilogue scales each output row by dinv[row] (pre-scaled aggregation).

template <typename AT>
__global__ __launch_bounds__(256, 2) void gemm_mfma_kernel(const AT* __restrict__ X,
                                                           const __half* __restrict__ Wp,
                                                           const float* __restrict__ dinv,
                                                           __half* __restrict__ Y, int M) {
    int lane = threadIdx.x & 63;
    int wid = threadIdx.x >> 6;
    f16x8 bf[4][8];
    {
        const float4* wp = (const float4*)Wp;
#pragma unroll
        for (int ks = 0; ks < 4; ks++)
#pragma unroll
            for (int nt = 0; nt < 8; nt++) {
                float4 t = wp[(ks * 8 + nt) * 64 + lane];
                bf[ks][nt] = *(f16x8*)&t;
            }
    }
    int row_l = lane & 15;
    int kgrp = lane >> 4;          // 0..3
    int tiles = M >> 4;            // M divisible by 16
    int nw = gridDim.x * 4;
    for (int tile = blockIdx.x * 4 + wid; tile < tiles; tile += nw) {
        int row0 = tile << 4;
        const AT* ap = X + (size_t)(row0 + row_l) * D + kgrp * 8;
        f32x4 acc[8];
#pragma unroll
        for (int nt = 0; nt < 8; nt++) acc[nt] = (f32x4){0.f, 0.f, 0.f, 0.f};
#pragma unroll
        for (int ks = 0; ks < 4; ks++) {
            f16x8 a;
            if constexpr (std::is_same<AT, float>::value) {
                float4 a0 = *(const float4*)(ap + ks * 32);
                float4 a1 = *(const float4*)(ap + ks * 32 + 4);
                a[0] = (_Float16)a0.x; a[1] = (_Float16)a0.y;
                a[2] = (_Float16)a0.z; a[3] = (_Float16)a0.w;
                a[4] = (_Float16)a1.x; a[5] = (_Float16)a1.y;
                a[6] = (_Float16)a1.z; a[7] = (_Float16)a1.w;
            } else {
                float4 t = *(const float4*)(const void*)(ap + ks * 32);
                a = *(f16x8*)&t;
            }
#pragma unroll
            for (int nt = 0; nt < 8; nt++)
                acc[nt] = __builtin_amdgcn_mfma_f32_16x16x32_f16(a, bf[ks][nt],
                                                                 acc[nt], 0, 0, 0);
        }
        // C/D: col = lane&15, row = (lane>>4)*4 + reg;  scale rows by dinv
        float ds[4];
#pragma unroll
        for (int r = 0; r < 4; r++) ds[r] = dinv[row0 + kgrp * 4 + r];
        __half* yb = Y + (size_t)row0 * D;
#pragma unroll
        for (int nt = 0; nt < 8; nt++)
#pragma unroll
            for (int r = 0; r < 4; r++)
                yb[(size_t)(kgrp * 4 + r) * D + nt * 16 + row_l] =
                    __float2half(ds[r] * acc[nt][r]);
    }
}

// ---------------- Aggregation (full): pure fp16 row-sum, 4-edge unroll ----------------
// h1[v] = relu(b + dv*(xws[v] + sum_u xws[u]))   (xws pre-scaled by dinv)

__global__ __launch_bounds__(256) void agg_kernel(const __half* __restrict__ XWs,
                                                  const float* __restrict__ bias,
                                                  const float* __restrict__ dinv,
                                                  const int* __restrict__ rowstart,
                                                  const int* __restrict__ csr_src,
                                                  __half* __restrict__ out, int n) {
    int wid = threadIdx.x >> 6;
    int lane = threadIdx.x & 63;
    int v = blockIdx.x * 4 + wid;
    if (v >= n) return;
    int c = lane * 2;
    float2 acc0 = __half22float2(*(const __half2*)&XWs[(size_t)v * D + c]);
    float2 acc1 = {0.f, 0.f};
    int e = rowstart[v], e1 = rowstart[v + 1];
    for (; e + 3 < e1; e += 4) {
        int u0 = csr_src[e], u1 = csr_src[e + 1];
        int u2 = csr_src[e + 2], u3 = csr_src[e + 3];
        float2 r0 = __half22float2(*(const __half2*)&XWs[(size_t)u0 * D + c]);
        float2 r1 = __half22float2(*(const __half2*)&XWs[(size_t)u1 * D + c]);
        float2 r2 = __half22float2(*(const __half2*)&XWs[(size_t)u2 * D + c]);
        float2 r3 = __half22float2(*(const __half2*)&XWs[(size_t)u3 * D + c]);
        acc0.x += r0.x + r2.x; acc0.y += r0.y + r2.y;
        acc1.x += r1.x + r3.x; acc1.y += r1.y + r3.y;
    }
    for (; e < e1; e++) {
        int u = csr_src[e];
        float2 r = __half22float2(*(const __half2*)&XWs[(size_t)u * D + c]);
        acc0.x += r.x; acc0.y += r.y;
    }
    float dv = dinv[v];
    float2 bb = *(const float2*)&bias[c];
    __half2 o;
    o.x = __float2half(fmaxf(bb.x + dv * (acc0.x + acc1.x), 0.f));
    o.y = __float2half(fmaxf(bb.y + dv * (acc0.y + acc1.y), 0.f));
    *(__half2*)&out[(size_t)v * D + c] = o;
}

// ---------------- Aggregation (active set): writes dinv-prescaled output ----------------
// h2s[v] = dinv[v] * relu(b + dv*(xws[v] + sum_u xws[u]))

__global__ __launch_bounds__(256) void agg_act_kernel(const __half* __restrict__ XWs,
                                                      const float* __restrict__ bias,
                                                      const float* __restrict__ dinv,
                                                      const int* __restrict__ rowstart,
                                                      const int* __restrict__ csr_src,
                                                      const int* __restrict__ act,
                                                      const int* __restrict__ na_p,
                                                      __half* __restrict__ out) {
    int wid = threadIdx.x >> 6;
    int lane = threadIdx.x & 63;
    int na = na_p[0];
    int stride = gridDim.x * 4;
    int c = lane * 2;
    float2 bb = *(const float2*)&bias[c];
    for (int i = blockIdx.x * 4 + wid; i < na; i += stride) {
        int v = act[i];
        float2 acc0 = __half22float2(*(const __half2*)&XWs[(size_t)v * D + c]);
        float2 acc1 = {0.f, 0.f};
        int e = rowstart[v], e1 = rowstart[v + 1];
        for (; e + 3 < e1; e += 4) {
            int u0 = csr_src[e], u1 = csr_src[e + 1];
            int u2 = csr_src[e + 2], u3 = csr_src[e + 3];
            float2 r0 = __half22float2(*(const __half2*)&XWs[(size_t)u0 * D + c]);
            float2 r1 = __half22float2(*(const __half2*)&XWs[(size_t)u1 * D + c]);
            float2 r2 = __half22float2(*(const __half2*)&XWs[(size_t)u2 * D + c]);
            float2 r3 = __half22float2(*(const __half2*)&XWs[(size_t)u3 * D + c]);
            acc0.x += r0.x + r2.x; acc0.y += r0.y + r2.y;
            acc1.x += r1.x + r3.x; acc1.y += r1.y + r3.y;
        }
        for (; e < e1; e++) {
            int u = csr_src[e];
            float2 r = __half22float2(*(const __half2*)&XWs[(size_t)u * D + c]);
            acc0.x += r.x; acc0.y += r.y;
        }
        float dv = dinv[v];
        __half2 o;
        o.x = __float2half(dv * fmaxf(bb.x + dv * (acc0.x + acc1.x), 0.f));
        o.y = __float2half(dv * fmaxf(bb.y + dv * (acc0.y + acc1.y), 0.f));
        *(__half2*)&out[(size_t)v * D + c] = o;
    }
}

// ---------------- Layer 3 pooled aggregation (h2s pre-scaled) + tiny GEMM ----------------

__global__ __launch_bounds__(256) void agg_pool_kernel(const __half* __restrict__ Hs,
                                                       const float* __restrict__ dinv,
                                                       const int* __restrict__ rowstart,
                                                       const int* __restrict__ csr_src,
                                                       const float* __restrict__ is_n,
                                                       const int* __restrict__ batch,
                                                       float* __restrict__ P,
                                                       float* __restrict__ cg, int n) {
    int wid = threadIdx.x >> 6;
    int lane = threadIdx.x & 63;
    int v = blockIdx.x * 4 + wid;
    if (v >= n) return;
    float w_is = is_n[v];
    if (w_is == 0.f) return;           // wave-uniform exit
    int c = lane * 2;
    float2 acc0 = __half22float2(*(const __half2*)&Hs[(size_t)v * D + c]);
    float2 acc1 = {0.f, 0.f};
    int e = rowstart[v], e1 = rowstart[v + 1];
    for (; e + 3 < e1; e += 4) {
        int u0 = csr_src[e], u1 = csr_src[e + 1];
        int u2 = csr_src[e + 2], u3 = csr_src[e + 3];
        float2 r0 = __half22float2(*(const __half2*)&Hs[(size_t)u0 * D + c]);
        float2 r1 = __half22float2(*(const __half2*)&Hs[(size_t)u1 * D + c]);
        float2 r2 = __half22float2(*(const __half2*)&Hs[(size_t)u2 * D + c]);
        float2 r3 = __half22float2(*(const __half2*)&Hs[(size_t)u3 * D + c]);
        acc0.x += r0.x + r2.x; acc0.y += r0.y + r2.y;
        acc1.x += r1.x + r3.x; acc1.y += r1.y + r3.y;
    }
    for (; e < e1; e++) {
        int u = csr_src[e];
        float2 r = __half22float2(*(const __half2*)&Hs[(size_t)u * D + c]);
        acc0.x += r.x; acc0.y += r.y;
    }
    float s = w_is * dinv[v];
    int g = batch[v];
    atomicAdd(&P[(size_t)g * D + c], s * (acc0.x + acc1.x));
    atomicAdd(&P[(size_t)g * D + c + 1], s * (acc0.y + acc1.y));
    if (lane == 0) atomicAdd(&cg[g], w_is);
}

__global__ __launch_bounds__(64) void pool_gemm_kernel(const float* __restrict__ P,
                                                       const float* __restrict__ cg,
                                                       const float* __restrict__ W,
                                                       const float* __restrict__ b,
                                                       float* __restrict__ out, int G) {
    int g = blockIdx.x;
    if (g >= G) return;
    int c = threadIdx.x * 2;
    float2 acc = {0.f, 0.f};
    const float* pr = &P[(size_t)g * D];
#pragma unroll 4
    for (int k = 0; k < D; k++) {
        float pk = pr[k];
        float2 w = *(const float2*)&W[k * D + c];
        acc.x += pk * w.x;
        acc.y += pk * w.y;
    }
    float s = 0.5f * cg[g];
    float2 bb = *(const float2*)&b[c];
    out[(size_t)g * D + c]     = 0.5f * acc.x + s * bb.x;
    out[(size_t)g * D + c + 1] = 0.5f * acc.y + s * bb.y;
}

// ---------------- launch ----------------

extern "C" void kernel_launch(void* const* d_in, const int* in_sizes, int n_in,
                              void* d_out, int out_size, void* d_ws, size_t ws_size,
                              hipStream_t stream) {
    const float* x     = (const float*)d_in[0];
    const int*   edge  = (const int*)d_in[1];
    const float* is_n  = (const float*)d_in[2];
    const int*   batch = (const int*)d_in[3];
    const float* W1 = (const float*)d_in[4];
    const float* b1 = (const float*)d_in[5];
    const float* W2 = (const float*)d_in[6];
    const float* b2 = (const float*)d_in[7];
    const float* W3 = (const float*)d_in[8];
    const float* b3 = (const float*)d_in[9];
    float* out = (float*)d_out;

    int n = in_sizes[0] / D;       // 50000
    int E = in_sizes[1] / 2;       // 600000
    int G = out_size / D;          // 500
    const int* esrc = edge;
    const int* edst = edge + E;

    char* p = (char*)d_ws;
    __half* xw = (__half*)p;     p += (size_t)n * D * sizeof(float);
    __half* h  = (__half*)p;     p += (size_t)n * D * sizeof(float);
    float* dinv = (float*)p;     p += (size_t)n * sizeof(float);
    int* rowstart = (int*)p;     p += (size_t)(n + 1) * sizeof(int);
    int* cursor = (int*)p;       p += (size_t)n * sizeof(int);
    int* csr_src = (int*)p;      p += (size_t)E * sizeof(int);
    int* bsum = (int*)p;         p += 256 * sizeof(int);
    int* boff = (int*)p;         p += 256 * sizeof(int);
    int* act = (int*)p;          p += (size_t)n * sizeof(int);
    int* na = (int*)p;           p += 4 * sizeof(int);
    __half* Wp = (__half*)p;     p += (size_t)3 * D * D * sizeof(__half);
    // contiguous zero-init region: cnt | mark | P | cg
    int* cnt = (int*)p;          p += (size_t)n * sizeof(int);
    int* mark = (int*)p;         p += (size_t)n * sizeof(int);
    float* P = (float*)p;        p += (size_t)G * D * sizeof(float);
    float* cg = (float*)p;       p += (size_t)G * sizeof(float);
    size_t zbytes = (size_t)(2 * n) * sizeof(int) + (size_t)(G * D + G) * sizeof(float);

    int PB = (n + 255) / 256;

    hipMemsetAsync(cnt, 0, zbytes, stream);
    packw_kernel<<<24, 256, 0, stream>>>(W1, W2, W3, Wp);
    count_kernel<<<(E + 255) / 256, 256, 0, stream>>>(esrc, edst, is_n, cnt, mark, E);
    psum_kernel<<<PB, 256, 0, stream>>>(cnt, bsum, n);
    bscan_kernel<<<1, 256, 0, stream>>>(bsum, boff, nullptr, PB);
    rows_kernel<<<PB, 256, 0, stream>>>(cnt, boff, rowstart, cursor, dinv, n, E);
    fill_kernel<<<(E + 255) / 256, 256, 0, stream>>>(esrc, edst, cursor, csr_src, E);
    // Active set S2 = {is_n} U N_in({is_n})
    psum2_kernel<<<PB, 256, 0, stream>>>(mark, is_n, bsum, n);
    bscan_kernel<<<1, 256, 0, stream>>>(bsum, boff, na, PB);
    compact_kernel<<<PB, 256, 0, stream>>>(mark, is_n, boff, act, n);

    int ablocks = (n + 3) / 4;

    // Layer 1: xw1s = dinv * (x @ W1)
    gemm_mfma_kernel<float><<<512, 256, 0, stream>>>(x, Wp, dinv, xw, n);
    agg_kernel<<<ablocks, 256, 0, stream>>>(xw, b1, dinv, rowstart, csr_src, h, n);
    // Layer 2: xw2s = dinv * (h1 @ W2); h2s (pre-scaled) at active nodes only
    gemm_mfma_kernel<__half><<<512, 256, 0, stream>>>(h, Wp + D * D, dinv, xw, n);
    agg_act_kernel<<<1024, 256, 0, stream>>>(xw, b2, dinv, rowstart, csr_src, act, na, h);
    // Layer 3: pooled aggregation of h2s, then tiny 500x128 GEMM
    agg_pool_kernel<<<ablocks, 256, 0, stream>>>(h, dinv, rowstart, csr_src,
                                                 is_n, batch, P, cg, n);
    pool_gemm_kernel<<<G, 64, 0, stream>>>(P, cg, W3, b3, out, G);
}

// Round 8
// 181.640 us; speedup vs baseline: 2.6539x; 1.0205x over previous
//
#include <hip/hip_runtime.h>
#include <hip/hip_fp16.h>
#include <type_traits>

#define D 128

typedef __attribute__((ext_vector_type(8))) _Float16 f16x8;
typedef __attribute__((ext_vector_type(4))) float f32x4;

// ---------------- CSR build ----------------

// count in-degree; also mark src nodes of edges whose dst is a neighbor-node
__global__ void count_kernel(const int* __restrict__ src, const int* __restrict__ dst,
                             const float* __restrict__ is_n,
                             int* __restrict__ cnt, int* __restrict__ mark, int E) {
    int e = blockIdx.x * blockDim.x + threadIdx.x;
    if (e < E) {
        int d = dst[e];
        atomicAdd(&cnt[d], 1);
        if (is_n[d] != 0.f) mark[src[e]] = 1;
    }
}

// block sums of cnt AND of (mark|is_n) in one pass
__global__ __launch_bounds__(256) void psumB_kernel(const int* __restrict__ cnt,
                                                    const int* __restrict__ mark,
                                                    const float* __restrict__ is_n,
                                                    int* __restrict__ bsum_c,
                                                    int* __restrict__ bsum_m, int n) {
    __shared__ int s[256], s2[256];
    int t = threadIdx.x;
    int i = blockIdx.x * 256 + t;
    s[t] = (i < n) ? cnt[i] : 0;
    s2[t] = (i < n) ? (mark[i] | (is_n[i] != 0.f ? 1 : 0)) : 0;
    __syncthreads();
    for (int off = 128; off > 0; off >>= 1) {
        if (t < off) { s[t] += s[t + off]; s2[t] += s2[t + off]; }
        __syncthreads();
    }
    if (t == 0) { bsum_c[blockIdx.x] = s[0]; bsum_m[blockIdx.x] = s2[0]; }
}

// exclusive scan of both block-sum arrays; writes total mark count to *na
__global__ __launch_bounds__(256) void bscanB_kernel(const int* __restrict__ bsum_c,
                                                     const int* __restrict__ bsum_m,
                                                     int* __restrict__ boff_c,
                                                     int* __restrict__ boff_m,
                                                     int* __restrict__ na, int PB) {
    __shared__ int s[256];
    int t = threadIdx.x;
    int v = (t < PB) ? bsum_c[t] : 0;
    s[t] = v;
    __syncthreads();
    for (int off = 1; off < 256; off <<= 1) {
        int add = (t >= off) ? s[t - off] : 0;
        __syncthreads();
        s[t] += add;
        __syncthreads();
    }
    if (t < PB) boff_c[t] = s[t] - v;
    __syncthreads();
    int v2 = (t < PB) ? bsum_m[t] : 0;
    s[t] = v2;
    __syncthreads();
    for (int off = 1; off < 256; off <<= 1) {
        int add = (t >= off) ? s[t - off] : 0;
        __syncthreads();
        s[t] += add;
        __syncthreads();
    }
    if (t < PB) boff_m[t] = s[t] - v2;
    if (t == PB - 1) na[0] = s[t];
}

// finalize: rowstart/cursor/dinv from cnt-scan, act from mark-scan
__global__ __launch_bounds__(256) void finB_kernel(const int* __restrict__ cnt,
                                                   const int* __restrict__ mark,
                                                   const float* __restrict__ is_n,
                                                   const int* __restrict__ boff_c,
                                                   const int* __restrict__ boff_m,
                                                   int* __restrict__ rowstart,
                                                   int* __restrict__ cursor,
                                                   float* __restrict__ dinv,
                                                   int* __restrict__ act, int n, int E) {
    __shared__ int s[256];
    int t = threadIdx.x;
    int i = blockIdx.x * 256 + t;
    int c = (i < n) ? cnt[i] : 0;
    s[t] = c;
    __syncthreads();
    for (int off = 1; off < 256; off <<= 1) {
        int add = (t >= off) ? s[t - off] : 0;
        __syncthreads();
        s[t] += add;
        __syncthreads();
    }
    if (i < n) {
        int excl = s[t] - c + boff_c[blockIdx.x];
        rowstart[i] = excl;
        cursor[i] = excl;
        dinv[i] = rsqrtf(1.0f + (float)c);
    }
    if (i == 0) rowstart[n] = E;
    __syncthreads();
    int m = (i < n) ? (mark[i] | (is_n[i] != 0.f ? 1 : 0)) : 0;
    s[t] = m;
    __syncthreads();
    for (int off = 1; off < 256; off <<= 1) {
        int add = (t >= off) ? s[t - off] : 0;
        __syncthreads();
        s[t] += add;
        __syncthreads();
    }
    if (m) act[s[t] - 1 + boff_m[blockIdx.x]] = i;
}

__global__ void fill_kernel(const int* __restrict__ src, const int* __restrict__ dst,
                            int* __restrict__ cursor, int* __restrict__ csr_src, int E) {
    int e = blockIdx.x * blockDim.x + threadIdx.x;
    if (e < E) {
        int d = dst[e];
        int pos = atomicAdd(&cursor[d], 1);
        csr_src[pos] = src[e];
    }
}

// ---------------- W pack: fragment-linear fp16 for MFMA B-operand ----------------

__global__ __launch_bounds__(256) void packw_kernel(const float* __restrict__ W1,
                                                    const float* __restrict__ W2,
                                                    const float* __restrict__ W3,
                                                    __half* __restrict__ Wp) {
    int gid = blockIdx.x * 256 + threadIdx.x;     // 0..6143
    int m = gid >> 11;
    int idx = gid & 2047;
    const float* W = (m == 0) ? W1 : (m == 1) ? W2 : W3;
    int l = idx & 63;
    int nt = (idx >> 6) & 7;
    int ks = idx >> 9;
    int kb = ks * 32 + (l >> 4) * 8;
    int col = nt * 16 + (l & 15);
    __half tmp[8];
#pragma unroll
    for (int j = 0; j < 8; j++) tmp[j] = __float2half(W[(kb + j) * D + col]);
    *(float4*)&Wp[(size_t)gid * 8] = *(float4*)tmp;
}

// ---------------- MFMA GEMM: Y[M,128](fp16) = dinv[r] * (X[M,128] @ W) ----------------

template <typename AT>
__global__ __launch_bounds__(256, 2) void gemm_mfma_kernel(const AT* __restrict__ X,
                                                           const __half* __restrict__ Wp,
                                                           const float* __restrict__ dinv,
                                                           __half* __restrict__ Y, int M) {
    int lane = threadIdx.x & 63;
    int wid = threadIdx.x >> 6;
    f16x8 bf[4][8];
    {
        const float4* wp = (const float4*)Wp;
#pragma unroll
        for (int ks = 0; ks < 4; ks++)
#pragma unroll
            for (int nt = 0; nt < 8; nt++) {
                float4 t = wp[(ks * 8 + nt) * 64 + lane];
                bf[ks][nt] = *(f16x8*)&t;
            }
    }
    int row_l = lane & 15;
    int kgrp = lane >> 4;
    int tiles = M >> 4;
    int nw = gridDim.x * 4;
    for (int tile = blockIdx.x * 4 + wid; tile < tiles; tile += nw) {
        int row0 = tile << 4;
        const AT* ap = X + (size_t)(row0 + row_l) * D + kgrp * 8;
        f32x4 acc[8];
#pragma unroll
        for (int nt = 0; nt < 8; nt++) acc[nt] = (f32x4){0.f, 0.f, 0.f, 0.f};
#pragma unroll
        for (int ks = 0; ks < 4; ks++) {
            f16x8 a;
            if constexpr (std::is_same<AT, float>::value) {
                float4 a0 = *(const float4*)(ap + ks * 32);
                float4 a1 = *(const float4*)(ap + ks * 32 + 4);
                a[0] = (_Float16)a0.x; a[1] = (_Float16)a0.y;
                a[2] = (_Float16)a0.z; a[3] = (_Float16)a0.w;
                a[4] = (_Float16)a1.x; a[5] = (_Float16)a1.y;
                a[6] = (_Float16)a1.z; a[7] = (_Float16)a1.w;
            } else {
                float4 t = *(const float4*)(const void*)(ap + ks * 32);
                a = *(f16x8*)&t;
            }
#pragma unroll
            for (int nt = 0; nt < 8; nt++)
                acc[nt] = __builtin_amdgcn_mfma_f32_16x16x32_f16(a, bf[ks][nt],
                                                                 acc[nt], 0, 0, 0);
        }
        float ds[4];
#pragma unroll
        for (int r = 0; r < 4; r++) ds[r] = dinv[row0 + kgrp * 4 + r];
        __half* yb = Y + (size_t)row0 * D;
#pragma unroll
        for (int nt = 0; nt < 8; nt++)
#pragma unroll
            for (int r = 0; r < 4; r++)
                yb[(size_t)(kgrp * 4 + r) * D + nt * 16 + row_l] =
                    __float2half(ds[r] * acc[nt][r]);
    }
}

// ---------------- Fused layer-1 aggregation + layer-2 GEMM ----------------
// Block = 4 waves x 4 nodes = 16-row tile. Gather h1 rows into LDS (fp16),
// sync once, MFMA with W2 frags, write xw2s = dinv * (h1 @ W2).

__global__ __launch_bounds__(256) void agg_gemm_kernel(const __half* __restrict__ XWs,
                                                       const float* __restrict__ bias,
                                                       const float* __restrict__ dinv,
                                                       const int* __restrict__ rowstart,
                                                       const int* __restrict__ csr_src,
                                                       const __half* __restrict__ Wp2,
                                                       __half* __restrict__ Y) {
    __shared__ __half hs[16][136];     // +8 pad: 2-way bank alias only on b128 reads
    int t = threadIdx.x;
    int wid = t >> 6, lane = t & 63;
    int block0 = blockIdx.x * 16;
    // B frags for this wave's 2 n-tiles (W2 is L2-hot: 32 KB)
    f16x8 bf[4][2];
    {
        const float4* wp = (const float4*)Wp2;
#pragma unroll
        for (int ks = 0; ks < 4; ks++)
#pragma unroll
            for (int j = 0; j < 2; j++) {
                float4 tmp = wp[(ks * 8 + wid * 2 + j) * 64 + lane];
                bf[ks][j] = *(f16x8*)&tmp;
            }
    }
    int c = lane * 2;
    float2 bb = *(const float2*)&bias[c];
    // gather phase: 4 nodes per wave (n divisible by 16 -> all v valid)
#pragma unroll
    for (int i = 0; i < 4; i++) {
        int v = block0 + wid * 4 + i;
        float2 acc0 = __half22float2(*(const __half2*)&XWs[(size_t)v * D + c]);
        float2 acc1 = {0.f, 0.f};
        int e = rowstart[v], e1 = rowstart[v + 1];
        for (; e + 3 < e1; e += 4) {
            int u0 = csr_src[e], u1 = csr_src[e + 1];
            int u2 = csr_src[e + 2], u3 = csr_src[e + 3];
            float2 r0 = __half22float2(*(const __half2*)&XWs[(size_t)u0 * D + c]);
            float2 r1 = __half22float2(*(const __half2*)&XWs[(size_t)u1 * D + c]);
            float2 r2 = __half22float2(*(const __half2*)&XWs[(size_t)u2 * D + c]);
            float2 r3 = __half22float2(*(const __half2*)&XWs[(size_t)u3 * D + c]);
            acc0.x += r0.x + r2.x; acc0.y += r0.y + r2.y;
            acc1.x += r1.x + r3.x; acc1.y += r1.y + r3.y;
        }
        for (; e < e1; e++) {
            int u = csr_src[e];
            float2 r = __half22float2(*(const __half2*)&XWs[(size_t)u * D + c]);
            acc0.x += r.x; acc0.y += r.y;
        }
        float dv = dinv[v];
        __half2 o;
        o.x = __float2half(fmaxf(bb.x + dv * (acc0.x + acc1.x), 0.f));
        o.y = __float2half(fmaxf(bb.y + dv * (acc0.y + acc1.y), 0.f));
        *(__half2*)&hs[wid * 4 + i][c] = o;
    }
    __syncthreads();
    // MFMA phase: 16x128 tile @ W2
    int row_l = lane & 15, kgrp = lane >> 4;
    f32x4 acc[2];
    acc[0] = (f32x4){0.f, 0.f, 0.f, 0.f};
    acc[1] = (f32x4){0.f, 0.f, 0.f, 0.f};
#pragma unroll
    for (int ks = 0; ks < 4; ks++) {
        f16x8 a = *(f16x8*)&hs[row_l][ks * 32 + kgrp * 8];
#pragma unroll
        for (int j = 0; j < 2; j++)
            acc[j] = __builtin_amdgcn_mfma_f32_16x16x32_f16(a, bf[ks][j],
                                                            acc[j], 0, 0, 0);
    }
    float ds[4];
#pragma unroll
    for (int r = 0; r < 4; r++) ds[r] = dinv[block0 + kgrp * 4 + r];
    __half* yb = Y + (size_t)block0 * D;
#pragma unroll
    for (int j = 0; j < 2; j++)
#pragma unroll
        for (int r = 0; r < 4; r++)
            yb[(size_t)(kgrp * 4 + r) * D + (wid * 2 + j) * 16 + row_l] =
                __float2half(ds[r] * acc[j][r]);
}

// ---------------- Aggregation (active set): writes dinv-prescaled output ----------------

__global__ __launch_bounds__(256) void agg_act_kernel(const __half* __restrict__ XWs,
                                                      const float* __restrict__ bias,
                                                      const float* __restrict__ dinv,
                                                      const int* __restrict__ rowstart,
                                                      const int* __restrict__ csr_src,
                                                      const int* __restrict__ act,
                                                      const int* __restrict__ na_p,
                                                      __half* __restrict__ out) {
    int wid = threadIdx.x >> 6;
    int lane = threadIdx.x & 63;
    int na = na_p[0];
    int stride = gridDim.x * 4;
    int c = lane * 2;
    float2 bb = *(const float2*)&bias[c];
    for (int i = blockIdx.x * 4 + wid; i < na; i += stride) {
        int v = act[i];
        float2 acc0 = __half22float2(*(const __half2*)&XWs[(size_t)v * D + c]);
        float2 acc1 = {0.f, 0.f};
        int e = rowstart[v], e1 = rowstart[v + 1];
        for (; e + 3 < e1; e += 4) {
            int u0 = csr_src[e], u1 = csr_src[e + 1];
            int u2 = csr_src[e + 2], u3 = csr_src[e + 3];
            float2 r0 = __half22float2(*(const __half2*)&XWs[(size_t)u0 * D + c]);
            float2 r1 = __half22float2(*(const __half2*)&XWs[(size_t)u1 * D + c]);
            float2 r2 = __half22float2(*(const __half2*)&XWs[(size_t)u2 * D + c]);
            float2 r3 = __half22float2(*(const __half2*)&XWs[(size_t)u3 * D + c]);
            acc0.x += r0.x + r2.x; acc0.y += r0.y + r2.y;
            acc1.x += r1.x + r3.x; acc1.y += r1.y + r3.y;
        }
        for (; e < e1; e++) {
            int u = csr_src[e];
            float2 r = __half22float2(*(const __half2*)&XWs[(size_t)u * D + c]);
            acc0.x += r.x; acc0.y += r.y;
        }
        float dv = dinv[v];
        __half2 o;
        o.x = __float2half(dv * fmaxf(bb.x + dv * (acc0.x + acc1.x), 0.f));
        o.y = __float2half(dv * fmaxf(bb.y + dv * (acc0.y + acc1.y), 0.f));
        *(__half2*)&out[(size_t)v * D + c] = o;
    }
}

// ---------------- Layer 3 pooled aggregation (h2s pre-scaled) + tiny GEMM ----------------

__global__ __launch_bounds__(256) void agg_pool_kernel(const __half* __restrict__ Hs,
                                                       const float* __restrict__ dinv,
                                                       const int* __restrict__ rowstart,
                                                       const int* __restrict__ csr_src,
                                                       const float* __restrict__ is_n,
                                                       const int* __restrict__ batch,
                                                       float* __restrict__ P,
                                                       float* __restrict__ cg, int n) {
    int wid = threadIdx.x >> 6;
    int lane = threadIdx.x & 63;
    int v = blockIdx.x * 4 + wid;
    if (v >= n) return;
    float w_is = is_n[v];
    if (w_is == 0.f) return;           // wave-uniform exit
    int c = lane * 2;
    float2 acc0 = __half22float2(*(const __half2*)&Hs[(size_t)v * D + c]);
    float2 acc1 = {0.f, 0.f};
    int e = rowstart[v], e1 = rowstart[v + 1];
    for (; e + 3 < e1; e += 4) {
        int u0 = csr_src[e], u1 = csr_src[e + 1];
        int u2 = csr_src[e + 2], u3 = csr_src[e + 3];
        float2 r0 = __half22float2(*(const __half2*)&Hs[(size_t)u0 * D + c]);
        float2 r1 = __half22float2(*(const __half2*)&Hs[(size_t)u1 * D + c]);
        float2 r2 = __half22float2(*(const __half2*)&Hs[(size_t)u2 * D + c]);
        float2 r3 = __half22float2(*(const __half2*)&Hs[(size_t)u3 * D + c]);
        acc0.x += r0.x + r2.x; acc0.y += r0.y + r2.y;
        acc1.x += r1.x + r3.x; acc1.y += r1.y + r3.y;
    }
    for (; e < e1; e++) {
        int u = csr_src[e];
        float2 r = __half22float2(*(const __half2*)&Hs[(size_t)u * D + c]);
        acc0.x += r.x; acc0.y += r.y;
    }
    float s = w_is * dinv[v];
    int g = batch[v];
    atomicAdd(&P[(size_t)g * D + c], s * (acc0.x + acc1.x));
    atomicAdd(&P[(size_t)g * D + c + 1], s * (acc0.y + acc1.y));
    if (lane == 0) atomicAdd(&cg[g], w_is);
}

__global__ __launch_bounds__(64) void pool_gemm_kernel(const float* __restrict__ P,
                                                       const float* __restrict__ cg,
                                                       const float* __restrict__ W,
                                                       const float* __restrict__ b,
                                                       float* __restrict__ out, int G) {
    int g = blockIdx.x;
    if (g >= G) return;
    int c = threadIdx.x * 2;
    float2 acc = {0.f, 0.f};
    const float* pr = &P[(size_t)g * D];
#pragma unroll 4
    for (int k = 0; k < D; k++) {
        float pk = pr[k];
        float2 w = *(const float2*)&W[k * D + c];
        acc.x += pk * w.x;
        acc.y += pk * w.y;
    }
    float s = 0.5f * cg[g];
    float2 bb = *(const float2*)&b[c];
    out[(size_t)g * D + c]     = 0.5f * acc.x + s * bb.x;
    out[(size_t)g * D + c + 1] = 0.5f * acc.y + s * bb.y;
}

// ---------------- launch ----------------

extern "C" void kernel_launch(void* const* d_in, const int* in_sizes, int n_in,
                              void* d_out, int out_size, void* d_ws, size_t ws_size,
                              hipStream_t stream) {
    const float* x     = (const float*)d_in[0];
    const int*   edge  = (const int*)d_in[1];
    const float* is_n  = (const float*)d_in[2];
    const int*   batch = (const int*)d_in[3];
    const float* W1 = (const float*)d_in[4];
    const float* b1 = (const float*)d_in[5];
    const float* W2 = (const float*)d_in[6];
    const float* b2 = (const float*)d_in[7];
    const float* W3 = (const float*)d_in[8];
    const float* b3 = (const float*)d_in[9];
    float* out = (float*)d_out;

    int n = in_sizes[0] / D;       // 50000
    int E = in_sizes[1] / 2;       // 600000
    int G = out_size / D;          // 500
    const int* esrc = edge;
    const int* edst = edge + E;

    char* p = (char*)d_ws;
    __half* xw = (__half*)p;     p += (size_t)n * D * sizeof(float);
    __half* h  = (__half*)p;     p += (size_t)n * D * sizeof(float);
    float* dinv = (float*)p;     p += (size_t)n * sizeof(float);
    int* rowstart = (int*)p;     p += (size_t)(n + 1) * sizeof(int);
    int* cursor = (int*)p;       p += (size_t)n * sizeof(int);
    int* csr_src = (int*)p;      p += (size_t)E * sizeof(int);
    int* bsum_c = (int*)p;       p += 256 * sizeof(int);
    int* bsum_m = (int*)p;       p += 256 * sizeof(int);
    int* boff_c = (int*)p;       p += 256 * sizeof(int);
    int* boff_m = (int*)p;       p += 256 * sizeof(int);
    int* act = (int*)p;          p += (size_t)n * sizeof(int);
    int* na = (int*)p;           p += 4 * sizeof(int);
    __half* Wp = (__half*)p;     p += (size_t)3 * D * D * sizeof(__half);
    // contiguous zero-init region: cnt | mark | P | cg
    int* cnt = (int*)p;          p += (size_t)n * sizeof(int);
    int* mark = (int*)p;         p += (size_t)n * sizeof(int);
    float* P = (float*)p;        p += (size_t)G * D * sizeof(float);
    float* cg = (float*)p;       p += (size_t)G * sizeof(float);
    size_t zbytes = (size_t)(2 * n) * sizeof(int) + (size_t)(G * D + G) * sizeof(float);

    int PB = (n + 255) / 256;

    hipMemsetAsync(cnt, 0, zbytes, stream);
    packw_kernel<<<24, 256, 0, stream>>>(W1, W2, W3, Wp);
    count_kernel<<<(E + 255) / 256, 256, 0, stream>>>(esrc, edst, is_n, cnt, mark, E);
    psumB_kernel<<<PB, 256, 0, stream>>>(cnt, mark, is_n, bsum_c, bsum_m, n);
    bscanB_kernel<<<1, 256, 0, stream>>>(bsum_c, bsum_m, boff_c, boff_m, na, PB);
    finB_kernel<<<PB, 256, 0, stream>>>(cnt, mark, is_n, boff_c, boff_m,
                                        rowstart, cursor, dinv, act, n, E);
    fill_kernel<<<(E + 255) / 256, 256, 0, stream>>>(esrc, edst, cursor, csr_src, E);

    // Layer 1: xw1s = dinv * (x @ W1)
    gemm_mfma_kernel<float><<<512, 256, 0, stream>>>(x, Wp, dinv, xw, n);
    // Fused layer-1 agg + layer-2 GEMM: h <- xw2s = dinv * (h1 @ W2)
    agg_gemm_kernel<<<n / 16, 256, 0, stream>>>(xw, b1, dinv, rowstart, csr_src,
                                                Wp + D * D, h);
    // Layer 2 aggregation at active nodes: xw <- h2s (pre-scaled)
    agg_act_kernel<<<1024, 256, 0, stream>>>(h, b2, dinv, rowstart, csr_src, act, na, xw);
    // Layer 3: pooled aggregation of h2s, then tiny 500x128 GEMM
    agg_pool_kernel<<<(n + 3) / 4, 256, 0, stream>>>(xw, dinv, rowstart, csr_src,
                                                     is_n, batch, P, cg, n);
    pool_gemm_kernel<<<G, 64, 0, stream>>>(P, cg, W3, b3, out, G);
}

// Round 9
// 174.296 us; speedup vs baseline: 2.7657x; 1.0421x over previous
//
#include <hip/hip_runtime.h>
#include <hip/hip_fp16.h>
#include <type_traits>

#define D 128

typedef __attribute__((ext_vector_type(8))) _Float16 f16x8;
typedef __attribute__((ext_vector_type(4))) float f32x4;

// ---------------- CSR build ----------------

__global__ void count_kernel(const int* __restrict__ src, const int* __restrict__ dst,
                             const float* __restrict__ is_n,
                             int* __restrict__ cnt, int* __restrict__ mark, int E) {
    int e = blockIdx.x * blockDim.x + threadIdx.x;
    if (e < E) {
        int d = dst[e];
        atomicAdd(&cnt[d], 1);
        if (is_n[d] != 0.f) mark[src[e]] = 1;
    }
}

__global__ __launch_bounds__(256) void psumB_kernel(const int* __restrict__ cnt,
                                                    const int* __restrict__ mark,
                                                    const float* __restrict__ is_n,
                                                    int* __restrict__ bsum_c,
                                                    int* __restrict__ bsum_m, int n) {
    __shared__ int s[256], s2[256];
    int t = threadIdx.x;
    int i = blockIdx.x * 256 + t;
    s[t] = (i < n) ? cnt[i] : 0;
    s2[t] = (i < n) ? (mark[i] | (is_n[i] != 0.f ? 1 : 0)) : 0;
    __syncthreads();
    for (int off = 128; off > 0; off >>= 1) {
        if (t < off) { s[t] += s[t + off]; s2[t] += s2[t + off]; }
        __syncthreads();
    }
    if (t == 0) { bsum_c[blockIdx.x] = s[0]; bsum_m[blockIdx.x] = s2[0]; }
}

__global__ __launch_bounds__(256) void bscanB_kernel(const int* __restrict__ bsum_c,
                                                     const int* __restrict__ bsum_m,
                                                     int* __restrict__ boff_c,
                                                     int* __restrict__ boff_m,
                                                     int* __restrict__ na, int PB) {
    __shared__ int s[256];
    int t = threadIdx.x;
    int v = (t < PB) ? bsum_c[t] : 0;
    s[t] = v;
    __syncthreads();
    for (int off = 1; off < 256; off <<= 1) {
        int add = (t >= off) ? s[t - off] : 0;
        __syncthreads();
        s[t] += add;
        __syncthreads();
    }
    if (t < PB) boff_c[t] = s[t] - v;
    __syncthreads();
    int v2 = (t < PB) ? bsum_m[t] : 0;
    s[t] = v2;
    __syncthreads();
    for (int off = 1; off < 256; off <<= 1) {
        int add = (t >= off) ? s[t - off] : 0;
        __syncthreads();
        s[t] += add;
        __syncthreads();
    }
    if (t < PB) boff_m[t] = s[t] - v2;
    if (t == PB - 1) na[0] = s[t];
}

__global__ __launch_bounds__(256) void finB_kernel(const int* __restrict__ cnt,
                                                   const int* __restrict__ mark,
                                                   const float* __restrict__ is_n,
                                                   const int* __restrict__ boff_c,
                                                   const int* __restrict__ boff_m,
                                                   int* __restrict__ rowstart,
                                                   int* __restrict__ cursor,
                                                   float* __restrict__ dinv,
                                                   int* __restrict__ act, int n, int E) {
    __shared__ int s[256];
    int t = threadIdx.x;
    int i = blockIdx.x * 256 + t;
    int c = (i < n) ? cnt[i] : 0;
    s[t] = c;
    __syncthreads();
    for (int off = 1; off < 256; off <<= 1) {
        int add = (t >= off) ? s[t - off] : 0;
        __syncthreads();
        s[t] += add;
        __syncthreads();
    }
    if (i < n) {
        int excl = s[t] - c + boff_c[blockIdx.x];
        rowstart[i] = excl;
        cursor[i] = excl;
        dinv[i] = rsqrtf(1.0f + (float)c);
    }
    if (i == 0) rowstart[n] = E;
    __syncthreads();
    int m = (i < n) ? (mark[i] | (is_n[i] != 0.f ? 1 : 0)) : 0;
    s[t] = m;
    __syncthreads();
    for (int off = 1; off < 256; off <<= 1) {
        int add = (t >= off) ? s[t - off] : 0;
        __syncthreads();
        s[t] += add;
        __syncthreads();
    }
    if (m) act[s[t] - 1 + boff_m[blockIdx.x]] = i;
}

__global__ void fill_kernel(const int* __restrict__ src, const int* __restrict__ dst,
                            int* __restrict__ cursor, int* __restrict__ csr_src, int E) {
    int e = blockIdx.x * blockDim.x + threadIdx.x;
    if (e < E) {
        int d = dst[e];
        int pos = atomicAdd(&cursor[d], 1);
        csr_src[pos] = src[e];
    }
}

// ---------------- W pack: fragment-linear fp16 for MFMA B-operand ----------------

__global__ __launch_bounds__(256) void packw_kernel(const float* __restrict__ W1,
                                                    const float* __restrict__ W2,
                                                    const float* __restrict__ W3,
                                                    __half* __restrict__ Wp) {
    int gid = blockIdx.x * 256 + threadIdx.x;     // 0..6143
    int m = gid >> 11;
    int idx = gid & 2047;
    const float* W = (m == 0) ? W1 : (m == 1) ? W2 : W3;
    int l = idx & 63;
    int nt = (idx >> 6) & 7;
    int ks = idx >> 9;
    int kb = ks * 32 + (l >> 4) * 8;
    int col = nt * 16 + (l & 15);
    __half tmp[8];
#pragma unroll
    for (int j = 0; j < 8; j++) tmp[j] = __float2half(W[(kb + j) * D + col]);
    *(float4*)&Wp[(size_t)gid * 8] = *(float4*)tmp;
}

// ---------------- MFMA GEMM: Y[M,128](fp16) = dinv[r] * (X[M,128] @ W) ----------------

template <typename AT>
__global__ __launch_bounds__(256, 2) void gemm_mfma_kernel(const AT* __restrict__ X,
                                                           const __half* __restrict__ Wp,
                                                           const float* __restrict__ dinv,
                                                           __half* __restrict__ Y, int M) {
    int lane = threadIdx.x & 63;
    int wid = threadIdx.x >> 6;
    f16x8 bf[4][8];
    {
        const float4* wp = (const float4*)Wp;
#pragma unroll
        for (int ks = 0; ks < 4; ks++)
#pragma unroll
            for (int nt = 0; nt < 8; nt++) {
                float4 t = wp[(ks * 8 + nt) * 64 + lane];
                bf[ks][nt] = *(f16x8*)&t;
            }
    }
    int row_l = lane & 15;
    int kgrp = lane >> 4;
    int tiles = M >> 4;
    int nw = gridDim.x * 4;
    for (int tile = blockIdx.x * 4 + wid; tile < tiles; tile += nw) {
        int row0 = tile << 4;
        const AT* ap = X + (size_t)(row0 + row_l) * D + kgrp * 8;
        f32x4 acc[8];
#pragma unroll
        for (int nt = 0; nt < 8; nt++) acc[nt] = (f32x4){0.f, 0.f, 0.f, 0.f};
#pragma unroll
        for (int ks = 0; ks < 4; ks++) {
            f16x8 a;
            if constexpr (std::is_same<AT, float>::value) {
                float4 a0 = *(const float4*)(ap + ks * 32);
                float4 a1 = *(const float4*)(ap + ks * 32 + 4);
                a[0] = (_Float16)a0.x; a[1] = (_Float16)a0.y;
                a[2] = (_Float16)a0.z; a[3] = (_Float16)a0.w;
                a[4] = (_Float16)a1.x; a[5] = (_Float16)a1.y;
                a[6] = (_Float16)a1.z; a[7] = (_Float16)a1.w;
            } else {
                float4 t = *(const float4*)(const void*)(ap + ks * 32);
                a = *(f16x8*)&t;
            }
#pragma unroll
            for (int nt = 0; nt < 8; nt++)
                acc[nt] = __builtin_amdgcn_mfma_f32_16x16x32_f16(a, bf[ks][nt],
                                                                 acc[nt], 0, 0, 0);
        }
        float ds[4];
#pragma unroll
        for (int r = 0; r < 4; r++) ds[r] = dinv[row0 + kgrp * 4 + r];
        __half* yb = Y + (size_t)row0 * D;
#pragma unroll
        for (int nt = 0; nt < 8; nt++)
#pragma unroll
            for (int r = 0; r < 4; r++)
                yb[(size_t)(kgrp * 4 + r) * D + nt * 16 + row_l] =
                    __float2half(ds[r] * acc[nt][r]);
    }
}

// ---------------- group-gather core: 4 edge-groups x 16 lanes x float4 ----------------
// Wave layout: g = lane>>4 (edge subgroup), l16 = lane&15 (8 halves per lane).
// One load instruction fetches 4 rows (1 KB). Butterfly-combine groups at the end.

__device__ __forceinline__ void acc_row8(float acc[8], const __half* __restrict__ row,
                                         int l16) {
    float4 r = ((const float4*)row)[l16];
    const __half2* h2 = (const __half2*)&r;
#pragma unroll
    for (int k = 0; k < 4; k++) {
        float2 f = __half22float2(h2[k]);
        acc[2 * k]     += f.x;
        acc[2 * k + 1] += f.y;
    }
}

// returns acc[8] = sum over self + in-neighbors of XWs rows (cols l16*8..+7), all lanes
__device__ __forceinline__ void gather_node(const __half* __restrict__ XWs,
                                            const int* __restrict__ rowstart,
                                            const int* __restrict__ csr_src,
                                            int v, int g, int l16, float acc[8]) {
#pragma unroll
    for (int k = 0; k < 8; k++) acc[k] = 0.f;
    int e0 = rowstart[v];
    int deg = rowstart[v + 1] - e0;
    int j = g;
    for (; j + 4 < deg; j += 8) {
        int u0 = csr_src[e0 + j];
        int u1 = csr_src[e0 + j + 4];
        acc_row8(acc, XWs + (size_t)u0 * D, l16);
        acc_row8(acc, XWs + (size_t)u1 * D, l16);
    }
    if (j < deg) acc_row8(acc, XWs + (size_t)csr_src[e0 + j] * D, l16);
#pragma unroll
    for (int k = 0; k < 8; k++) acc[k] += __shfl_xor(acc[k], 16);
#pragma unroll
    for (int k = 0; k < 8; k++) acc[k] += __shfl_xor(acc[k], 32);
    acc_row8(acc, XWs + (size_t)v * D, l16);   // self loop (once, post-reduce)
}

// ---------------- Fused layer-1 aggregation + layer-2 GEMM ----------------

__global__ __launch_bounds__(256) void agg_gemm_kernel(const __half* __restrict__ XWs,
                                                       const float* __restrict__ bias,
                                                       const float* __restrict__ dinv,
                                                       const int* __restrict__ rowstart,
                                                       const int* __restrict__ csr_src,
                                                       const __half* __restrict__ Wp2,
                                                       __half* __restrict__ Y) {
    __shared__ __half hs[16][136];     // +8 pad
    int t = threadIdx.x;
    int wid = t >> 6, lane = t & 63;
    int g = lane >> 4, l16 = lane & 15;
    int block0 = blockIdx.x * 16;
    f16x8 bf[4][2];
    {
        const float4* wp = (const float4*)Wp2;
#pragma unroll
        for (int ks = 0; ks < 4; ks++)
#pragma unroll
            for (int j = 0; j < 2; j++) {
                float4 tmp = wp[(ks * 8 + wid * 2 + j) * 64 + lane];
                bf[ks][j] = *(f16x8*)&tmp;
            }
    }
    float4 b0 = ((const float4*)bias)[l16 * 2];
    float4 b1 = ((const float4*)bias)[l16 * 2 + 1];
#pragma unroll
    for (int i = 0; i < 4; i++) {
        int v = block0 + wid * 4 + i;
        float acc[8];
        gather_node(XWs, rowstart, csr_src, v, g, l16, acc);
        float dv = dinv[v];
        __half o[8];
        o[0] = __float2half(fmaxf(b0.x + dv * acc[0], 0.f));
        o[1] = __float2half(fmaxf(b0.y + dv * acc[1], 0.f));
        o[2] = __float2half(fmaxf(b0.z + dv * acc[2], 0.f));
        o[3] = __float2half(fmaxf(b0.w + dv * acc[3], 0.f));
        o[4] = __float2half(fmaxf(b1.x + dv * acc[4], 0.f));
        o[5] = __float2half(fmaxf(b1.y + dv * acc[5], 0.f));
        o[6] = __float2half(fmaxf(b1.z + dv * acc[6], 0.f));
        o[7] = __float2half(fmaxf(b1.w + dv * acc[7], 0.f));
        if (g == 0) *(float4*)&hs[wid * 4 + i][l16 * 8] = *(float4*)o;
    }
    __syncthreads();
    // MFMA phase: 16x128 tile @ W2
    int row_l = l16, kgrp = g;
    f32x4 acc2[2];
    acc2[0] = (f32x4){0.f, 0.f, 0.f, 0.f};
    acc2[1] = (f32x4){0.f, 0.f, 0.f, 0.f};
#pragma unroll
    for (int ks = 0; ks < 4; ks++) {
        f16x8 a = *(f16x8*)&hs[row_l][ks * 32 + kgrp * 8];
#pragma unroll
        for (int j = 0; j < 2; j++)
            acc2[j] = __builtin_amdgcn_mfma_f32_16x16x32_f16(a, bf[ks][j],
                                                             acc2[j], 0, 0, 0);
    }
    float ds[4];
#pragma unroll
    for (int r = 0; r < 4; r++) ds[r] = dinv[block0 + kgrp * 4 + r];
    __half* yb = Y + (size_t)block0 * D;
#pragma unroll
    for (int j = 0; j < 2; j++)
#pragma unroll
        for (int r = 0; r < 4; r++)
            yb[(size_t)(kgrp * 4 + r) * D + (wid * 2 + j) * 16 + row_l] =
                __float2half(ds[r] * acc2[j][r]);
}

// ---------------- Aggregation (active set): h2s = dinv * relu(b + dinv*sum) ----------------

__global__ __launch_bounds__(256) void agg_act_kernel(const __half* __restrict__ XWs,
                                                      const float* __restrict__ bias,
                                                      const float* __restrict__ dinv,
                                                      const int* __restrict__ rowstart,
                                                      const int* __restrict__ csr_src,
                                                      const int* __restrict__ act,
                                                      const int* __restrict__ na_p,
                                                      __half* __restrict__ out) {
    int wid = threadIdx.x >> 6;
    int lane = threadIdx.x & 63;
    int g = lane >> 4, l16 = lane & 15;
    int na = na_p[0];
    int stride = gridDim.x * 4;
    float4 b0 = ((const float4*)bias)[l16 * 2];
    float4 b1 = ((const float4*)bias)[l16 * 2 + 1];
    for (int i = blockIdx.x * 4 + wid; i < na; i += stride) {
        int v = act[i];
        float acc[8];
        gather_node(XWs, rowstart, csr_src, v, g, l16, acc);
        float dv = dinv[v];
        if (g == 0) {
            __half o[8];
            o[0] = __float2half(dv * fmaxf(b0.x + dv * acc[0], 0.f));
            o[1] = __float2half(dv * fmaxf(b0.y + dv * acc[1], 0.f));
            o[2] = __float2half(dv * fmaxf(b0.z + dv * acc[2], 0.f));
            o[3] = __float2half(dv * fmaxf(b0.w + dv * acc[3], 0.f));
            o[4] = __float2half(dv * fmaxf(b1.x + dv * acc[4], 0.f));
            o[5] = __float2half(dv * fmaxf(b1.y + dv * acc[5], 0.f));
            o[6] = __float2half(dv * fmaxf(b1.z + dv * acc[6], 0.f));
            o[7] = __float2half(dv * fmaxf(b1.w + dv * acc[7], 0.f));
            *(float4*)&out[(size_t)v * D + l16 * 8] = *(float4*)o;
        }
    }
}

// ---------------- Layer 3 pooled aggregation + tiny GEMM ----------------

__global__ __launch_bounds__(256) void agg_pool_kernel(const __half* __restrict__ Hs,
                                                       const float* __restrict__ dinv,
                                                       const int* __restrict__ rowstart,
                                                       const int* __restrict__ csr_src,
                                                       const float* __restrict__ is_n,
                                                       const int* __restrict__ batch,
                                                       float* __restrict__ P,
                                                       float* __restrict__ cg, int n) {
    int wid = threadIdx.x >> 6;
    int lane = threadIdx.x & 63;
    int g = lane >> 4, l16 = lane & 15;
    int v = blockIdx.x * 4 + wid;
    if (v >= n) return;
    float w_is = is_n[v];
    if (w_is == 0.f) return;           // wave-uniform exit
    float acc[8];
    gather_node(Hs, rowstart, csr_src, v, g, l16, acc);
    float s = w_is * dinv[v];
    int gr = batch[v];
    if (g == 0) {
        float* pb = &P[(size_t)gr * D + l16 * 8];
#pragma unroll
        for (int k = 0; k < 8; k++) atomicAdd(&pb[k], s * acc[k]);
    }
    if (lane == 0) atomicAdd(&cg[gr], w_is);
}

__global__ __launch_bounds__(64) void pool_gemm_kernel(const float* __restrict__ P,
                                                       const float* __restrict__ cg,
                                                       const float* __restrict__ W,
                                                       const float* __restrict__ b,
                                                       float* __restrict__ out, int G) {
    int g = blockIdx.x;
    if (g >= G) return;
    int c = threadIdx.x * 2;
    float2 acc = {0.f, 0.f};
    const float* pr = &P[(size_t)g * D];
#pragma unroll 4
    for (int k = 0; k < D; k++) {
        float pk = pr[k];
        float2 w = *(const float2*)&W[k * D + c];
        acc.x += pk * w.x;
        acc.y += pk * w.y;
    }
    float s = 0.5f * cg[g];
    float2 bb = *(const float2*)&b[c];
    out[(size_t)g * D + c]     = 0.5f * acc.x + s * bb.x;
    out[(size_t)g * D + c + 1] = 0.5f * acc.y + s * bb.y;
}

// ---------------- launch ----------------

extern "C" void kernel_launch(void* const* d_in, const int* in_sizes, int n_in,
                              void* d_out, int out_size, void* d_ws, size_t ws_size,
                              hipStream_t stream) {
    const float* x     = (const float*)d_in[0];
    const int*   edge  = (const int*)d_in[1];
    const float* is_n  = (const float*)d_in[2];
    const int*   batch = (const int*)d_in[3];
    const float* W1 = (const float*)d_in[4];
    const float* b1 = (const float*)d_in[5];
    const float* W2 = (const float*)d_in[6];
    const float* b2 = (const float*)d_in[7];
    const float* W3 = (const float*)d_in[8];
    const float* b3 = (const float*)d_in[9];
    float* out = (float*)d_out;

    int n = in_sizes[0] / D;       // 50000
    int E = in_sizes[1] / 2;       // 600000
    int G = out_size / D;          // 500
    const int* esrc = edge;
    const int* edst = edge + E;

    char* p = (char*)d_ws;
    __half* xw = (__half*)p;     p += (size_t)n * D * sizeof(float);
    __half* h  = (__half*)p;     p += (size_t)n * D * sizeof(float);
    float* dinv = (float*)p;     p += (size_t)n * sizeof(float);
    int* rowstart = (int*)p;     p += (size_t)(n + 1) * sizeof(int);
    int* cursor = (int*)p;       p += (size_t)n * sizeof(int);
    int* csr_src = (int*)p;      p += (size_t)E * sizeof(int);
    int* bsum_c = (int*)p;       p += 256 * sizeof(int);
    int* bsum_m = (int*)p;       p += 256 * sizeof(int);
    int* boff_c = (int*)p;       p += 256 * sizeof(int);
    int* boff_m = (int*)p;       p += 256 * sizeof(int);
    int* act = (int*)p;          p += (size_t)n * sizeof(int);
    int* na = (int*)p;           p += 4 * sizeof(int);
    __half* Wp = (__half*)p;     p += (size_t)3 * D * D * sizeof(__half);
    // contiguous zero-init region: cnt | mark | P | cg
    int* cnt = (int*)p;          p += (size_t)n * sizeof(int);
    int* mark = (int*)p;         p += (size_t)n * sizeof(int);
    float* P = (float*)p;        p += (size_t)G * D * sizeof(float);
    float* cg = (float*)p;       p += (size_t)G * sizeof(float);
    size_t zbytes = (size_t)(2 * n) * sizeof(int) + (size_t)(G * D + G) * sizeof(float);

    int PB = (n + 255) / 256;

    hipMemsetAsync(cnt, 0, zbytes, stream);
    packw_kernel<<<24, 256, 0, stream>>>(W1, W2, W3, Wp);
    count_kernel<<<(E + 255) / 256, 256, 0, stream>>>(esrc, edst, is_n, cnt, mark, E);
    psumB_kernel<<<PB, 256, 0, stream>>>(cnt, mark, is_n, bsum_c, bsum_m, n);
    bscanB_kernel<<<1, 256, 0, stream>>>(bsum_c, bsum_m, boff_c, boff_m, na, PB);
    finB_kernel<<<PB, 256, 0, stream>>>(cnt, mark, is_n, boff_c, boff_m,
                                        rowstart, cursor, dinv, act, n, E);
    fill_kernel<<<(E + 255) / 256, 256, 0, stream>>>(esrc, edst, cursor, csr_src, E);

    // Layer 1: xw1s = dinv * (x @ W1)
    gemm_mfma_kernel<float><<<512, 256, 0, stream>>>(x, Wp, dinv, xw, n);
    // Fused layer-1 agg + layer-2 GEMM: h <- xw2s = dinv * (h1 @ W2)
    agg_gemm_kernel<<<n / 16, 256, 0, stream>>>(xw, b1, dinv, rowstart, csr_src,
                                                Wp + D * D, h);
    // Layer 2 aggregation at active nodes: xw <- h2s (pre-scaled)
    agg_act_kernel<<<1024, 256, 0, stream>>>(h, b2, dinv, rowstart, csr_src, act, na, xw);
    // Layer 3: pooled aggregation of h2s, then tiny 500x128 GEMM
    agg_pool_kernel<<<(n + 3) / 4, 256, 0, stream>>>(xw, dinv, rowstart, csr_src,
                                                     is_n, batch, P, cg, n);
    pool_gemm_kernel<<<G, 64, 0, stream>>>(P, cg, W3, b3, out, G);
}

// Round 10
// 167.090 us; speedup vs baseline: 2.8850x; 1.0431x over previous
//
#include <hip/hip_runtime.h>
#include <hip/hip_fp16.h>
#include <type_traits>

#define D 128

typedef __attribute__((ext_vector_type(8))) _Float16 f16x8;
typedef __attribute__((ext_vector_type(4))) float f32x4;

// ---------------- CSR build ----------------

__global__ void count_kernel(const int* __restrict__ src, const int* __restrict__ dst,
                             const float* __restrict__ is_n,
                             int* __restrict__ cnt, int* __restrict__ mark, int E) {
    int e = blockIdx.x * blockDim.x + threadIdx.x;
    if (e < E) {
        int d = dst[e];
        atomicAdd(&cnt[d], 1);
        if (is_n[d] != 0.f) mark[src[e]] = 1;
    }
}

__global__ __launch_bounds__(256) void psumB_kernel(const int* __restrict__ cnt,
                                                    const int* __restrict__ mark,
                                                    const float* __restrict__ is_n,
                                                    int* __restrict__ bsum_c,
                                                    int* __restrict__ bsum_m, int n) {
    __shared__ int s[256], s2[256];
    int t = threadIdx.x;
    int i = blockIdx.x * 256 + t;
    s[t] = (i < n) ? cnt[i] : 0;
    s2[t] = (i < n) ? (mark[i] | (is_n[i] != 0.f ? 1 : 0)) : 0;
    __syncthreads();
    for (int off = 128; off > 0; off >>= 1) {
        if (t < off) { s[t] += s[t + off]; s2[t] += s2[t + off]; }
        __syncthreads();
    }
    if (t == 0) { bsum_c[blockIdx.x] = s[0]; bsum_m[blockIdx.x] = s2[0]; }
}

__global__ __launch_bounds__(256) void bscanB_kernel(const int* __restrict__ bsum_c,
                                                     const int* __restrict__ bsum_m,
                                                     int* __restrict__ boff_c,
                                                     int* __restrict__ boff_m,
                                                     int* __restrict__ na, int PB) {
    __shared__ int s[256];
    int t = threadIdx.x;
    int v = (t < PB) ? bsum_c[t] : 0;
    s[t] = v;
    __syncthreads();
    for (int off = 1; off < 256; off <<= 1) {
        int add = (t >= off) ? s[t - off] : 0;
        __syncthreads();
        s[t] += add;
        __syncthreads();
    }
    if (t < PB) boff_c[t] = s[t] - v;
    __syncthreads();
    int v2 = (t < PB) ? bsum_m[t] : 0;
    s[t] = v2;
    __syncthreads();
    for (int off = 1; off < 256; off <<= 1) {
        int add = (t >= off) ? s[t - off] : 0;
        __syncthreads();
        s[t] += add;
        __syncthreads();
    }
    if (t < PB) boff_m[t] = s[t] - v2;
    if (t == PB - 1) na[0] = s[t];
}

__global__ __launch_bounds__(256) void finB_kernel(const int* __restrict__ cnt,
                                                   const int* __restrict__ mark,
                                                   const float* __restrict__ is_n,
                                                   const int* __restrict__ boff_c,
                                                   const int* __restrict__ boff_m,
                                                   int* __restrict__ rowstart,
                                                   int* __restrict__ cursor,
                                                   float* __restrict__ dinv,
                                                   int* __restrict__ act, int n, int E) {
    __shared__ int s[256];
    int t = threadIdx.x;
    int i = blockIdx.x * 256 + t;
    int c = (i < n) ? cnt[i] : 0;
    s[t] = c;
    __syncthreads();
    for (int off = 1; off < 256; off <<= 1) {
        int add = (t >= off) ? s[t - off] : 0;
        __syncthreads();
        s[t] += add;
        __syncthreads();
    }
    if (i < n) {
        int excl = s[t] - c + boff_c[blockIdx.x];
        rowstart[i] = excl;
        cursor[i] = excl;
        dinv[i] = rsqrtf(1.0f + (float)c);
    }
    if (i == 0) rowstart[n] = E;
    __syncthreads();
    int m = (i < n) ? (mark[i] | (is_n[i] != 0.f ? 1 : 0)) : 0;
    s[t] = m;
    __syncthreads();
    for (int off = 1; off < 256; off <<= 1) {
        int add = (t >= off) ? s[t - off] : 0;
        __syncthreads();
        s[t] += add;
        __syncthreads();
    }
    if (m) act[s[t] - 1 + boff_m[blockIdx.x]] = i;
}

__global__ void fill_kernel(const int* __restrict__ src, const int* __restrict__ dst,
                            int* __restrict__ cursor, int* __restrict__ csr_src, int E) {
    int e = blockIdx.x * blockDim.x + threadIdx.x;
    if (e < E) {
        int d = dst[e];
        int pos = atomicAdd(&cursor[d], 1);
        csr_src[pos] = src[e];
    }
}

// ---------------- W pack: fragment-linear fp16 for MFMA B-operand ----------------

__global__ __launch_bounds__(256) void packw_kernel(const float* __restrict__ W1,
                                                    const float* __restrict__ W2,
                                                    const float* __restrict__ W3,
                                                    __half* __restrict__ Wp) {
    int gid = blockIdx.x * 256 + threadIdx.x;     // 0..6143
    int m = gid >> 11;
    int idx = gid & 2047;
    const float* W = (m == 0) ? W1 : (m == 1) ? W2 : W3;
    int l = idx & 63;
    int nt = (idx >> 6) & 7;
    int ks = idx >> 9;
    int kb = ks * 32 + (l >> 4) * 8;
    int col = nt * 16 + (l & 15);
    __half tmp[8];
#pragma unroll
    for (int j = 0; j < 8; j++) tmp[j] = __float2half(W[(kb + j) * D + col]);
    *(float4*)&Wp[(size_t)gid * 8] = *(float4*)tmp;
}

// ---------------- MFMA GEMM: Y[M,128](fp16) = dinv[r] * (X[M,128] @ W) ----------------

template <typename AT>
__global__ __launch_bounds__(256, 2) void gemm_mfma_kernel(const AT* __restrict__ X,
                                                           const __half* __restrict__ Wp,
                                                           const float* __restrict__ dinv,
                                                           __half* __restrict__ Y, int M) {
    int lane = threadIdx.x & 63;
    int wid = threadIdx.x >> 6;
    f16x8 bf[4][8];
    {
        const float4* wp = (const float4*)Wp;
#pragma unroll
        for (int ks = 0; ks < 4; ks++)
#pragma unroll
            for (int nt = 0; nt < 8; nt++) {
                float4 t = wp[(ks * 8 + nt) * 64 + lane];
                bf[ks][nt] = *(f16x8*)&t;
            }
    }
    int row_l = lane & 15;
    int kgrp = lane >> 4;
    int tiles = M >> 4;
    int nw = gridDim.x * 4;
    for (int tile = blockIdx.x * 4 + wid; tile < tiles; tile += nw) {
        int row0 = tile << 4;
        const AT* ap = X + (size_t)(row0 + row_l) * D + kgrp * 8;
        f32x4 acc[8];
#pragma unroll
        for (int nt = 0; nt < 8; nt++) acc[nt] = (f32x4){0.f, 0.f, 0.f, 0.f};
#pragma unroll
        for (int ks = 0; ks < 4; ks++) {
            f16x8 a;
            if constexpr (std::is_same<AT, float>::value) {
                float4 a0 = *(const float4*)(ap + ks * 32);
                float4 a1 = *(const float4*)(ap + ks * 32 + 4);
                a[0] = (_Float16)a0.x; a[1] = (_Float16)a0.y;
                a[2] = (_Float16)a0.z; a[3] = (_Float16)a0.w;
                a[4] = (_Float16)a1.x; a[5] = (_Float16)a1.y;
                a[6] = (_Float16)a1.z; a[7] = (_Float16)a1.w;
            } else {
                float4 t = *(const float4*)(const void*)(ap + ks * 32);
                a = *(f16x8*)&t;
            }
#pragma unroll
            for (int nt = 0; nt < 8; nt++)
                acc[nt] = __builtin_amdgcn_mfma_f32_16x16x32_f16(a, bf[ks][nt],
                                                                 acc[nt], 0, 0, 0);
        }
        float ds[4];
#pragma unroll
        for (int r = 0; r < 4; r++) ds[r] = dinv[row0 + kgrp * 4 + r];
        __half* yb = Y + (size_t)row0 * D;
#pragma unroll
        for (int nt = 0; nt < 8; nt++)
#pragma unroll
            for (int r = 0; r < 4; r++)
                yb[(size_t)(kgrp * 4 + r) * D + nt * 16 + row_l] =
                    __float2half(ds[r] * acc[nt][r]);
    }
}

// ---------------- group-gather core: ONE node per 16-lane group ----------------
// Per lane: node v (=group's node), cols l16*8..+7 (float4 = 8 halves).
// A wave carries 4 independent node-streams; one load instr fetches 4 rows.
// Divergence across groups is exec-masking only (masked lanes fetch nothing).

__device__ __forceinline__ void add_row(float acc[8], const __half* __restrict__ XWs,
                                        int u, int l16) {
    float4 r = ((const float4*)(XWs + (size_t)u * D))[l16];
    const __half2* h2 = (const __half2*)&r;
#pragma unroll
    for (int k = 0; k < 4; k++) {
        float2 f = __half22float2(h2[k]);
        acc[2 * k]     += f.x;
        acc[2 * k + 1] += f.y;
    }
}

__device__ __forceinline__ void gather_grp(const __half* __restrict__ XWs,
                                           const int* __restrict__ csr_src,
                                           int v, int e0, int e1, int l16,
                                           float acc[8]) {
#pragma unroll
    for (int k = 0; k < 8; k++) acc[k] = 0.f;
    int j = e0;
    for (; j + 1 < e1; j += 2) {
        int u0 = csr_src[j];
        int u1 = csr_src[j + 1];
        float4 r0 = ((const float4*)(XWs + (size_t)u0 * D))[l16];
        float4 r1 = ((const float4*)(XWs + (size_t)u1 * D))[l16];
        const __half2* a0 = (const __half2*)&r0;
        const __half2* a1 = (const __half2*)&r1;
#pragma unroll
        for (int k = 0; k < 4; k++) {
            float2 f0 = __half22float2(a0[k]);
            float2 f1 = __half22float2(a1[k]);
            acc[2 * k]     += f0.x + f1.x;
            acc[2 * k + 1] += f0.y + f1.y;
        }
    }
    if (j < e1) add_row(acc, XWs, csr_src[j], l16);
    add_row(acc, XWs, v, l16);     // self loop
}

// ---------------- Fused layer-1 aggregation + layer-2 GEMM ----------------
// 16 nodes/block = 4 waves x 4 groups. Gather into LDS tile, sync, MFMA @ W2.

__global__ __launch_bounds__(256) void agg_gemm_kernel(const __half* __restrict__ XWs,
                                                       const float* __restrict__ bias,
                                                       const float* __restrict__ dinv,
                                                       const int* __restrict__ rowstart,
                                                       const int* __restrict__ csr_src,
                                                       const __half* __restrict__ Wp2,
                                                       __half* __restrict__ Y) {
    __shared__ __half hs[16][136];     // +8 pad
    int t = threadIdx.x;
    int wid = t >> 6, lane = t & 63;
    int g = lane >> 4, l16 = lane & 15;
    int block0 = blockIdx.x * 16;
    int v = block0 + wid * 4 + g;       // per-group node (n divisible by 16)
    int e0 = rowstart[v], e1 = rowstart[v + 1];
    float acc[8];
    gather_grp(XWs, csr_src, v, e0, e1, l16, acc);
    float dv = dinv[v];
    float4 b0 = ((const float4*)bias)[l16 * 2];
    float4 b1 = ((const float4*)bias)[l16 * 2 + 1];
    __half o[8];
    o[0] = __float2half(fmaxf(b0.x + dv * acc[0], 0.f));
    o[1] = __float2half(fmaxf(b0.y + dv * acc[1], 0.f));
    o[2] = __float2half(fmaxf(b0.z + dv * acc[2], 0.f));
    o[3] = __float2half(fmaxf(b0.w + dv * acc[3], 0.f));
    o[4] = __float2half(fmaxf(b1.x + dv * acc[4], 0.f));
    o[5] = __float2half(fmaxf(b1.y + dv * acc[5], 0.f));
    o[6] = __float2half(fmaxf(b1.z + dv * acc[6], 0.f));
    o[7] = __float2half(fmaxf(b1.w + dv * acc[7], 0.f));
    *(float4*)&hs[wid * 4 + g][l16 * 8] = *(float4*)o;
    // B frags loaded after gather (short live range; Wp2 is L2-hot)
    f16x8 bf[4][2];
    {
        const float4* wp = (const float4*)Wp2;
#pragma unroll
        for (int ks = 0; ks < 4; ks++)
#pragma unroll
            for (int j = 0; j < 2; j++) {
                float4 tmp = wp[(ks * 8 + wid * 2 + j) * 64 + lane];
                bf[ks][j] = *(f16x8*)&tmp;
            }
    }
    __syncthreads();
    // MFMA phase: 16x128 tile @ W2
    int row_l = l16, kgrp = g;
    f32x4 acc2[2];
    acc2[0] = (f32x4){0.f, 0.f, 0.f, 0.f};
    acc2[1] = (f32x4){0.f, 0.f, 0.f, 0.f};
#pragma unroll
    for (int ks = 0; ks < 4; ks++) {
        f16x8 a = *(f16x8*)&hs[row_l][ks * 32 + kgrp * 8];
#pragma unroll
        for (int j = 0; j < 2; j++)
            acc2[j] = __builtin_amdgcn_mfma_f32_16x16x32_f16(a, bf[ks][j],
                                                             acc2[j], 0, 0, 0);
    }
    float ds[4];
#pragma unroll
    for (int r = 0; r < 4; r++) ds[r] = dinv[block0 + kgrp * 4 + r];
    __half* yb = Y + (size_t)block0 * D;
#pragma unroll
    for (int j = 0; j < 2; j++)
#pragma unroll
        for (int r = 0; r < 4; r++)
            yb[(size_t)(kgrp * 4 + r) * D + (wid * 2 + j) * 16 + row_l] =
                __float2half(ds[r] * acc2[j][r]);
}

// ---------------- Aggregation (active set): h2s = dinv * relu(b + dinv*sum) ----------------
// One act-node per 16-lane group, grid-strided.

__global__ __launch_bounds__(256) void agg_act_kernel(const __half* __restrict__ XWs,
                                                      const float* __restrict__ bias,
                                                      const float* __restrict__ dinv,
                                                      const int* __restrict__ rowstart,
                                                      const int* __restrict__ csr_src,
                                                      const int* __restrict__ act,
                                                      const int* __restrict__ na_p,
                                                      __half* __restrict__ out) {
    int t = threadIdx.x;
    int wid = t >> 6, lane = t & 63;
    int g = lane >> 4, l16 = lane & 15;
    int na = na_p[0];
    int stride = gridDim.x * 16;
    float4 b0 = ((const float4*)bias)[l16 * 2];
    float4 b1 = ((const float4*)bias)[l16 * 2 + 1];
    for (int i = blockIdx.x * 16 + wid * 4 + g; i < na; i += stride) {
        int v = act[i];
        int e0 = rowstart[v], e1 = rowstart[v + 1];
        float acc[8];
        gather_grp(XWs, csr_src, v, e0, e1, l16, acc);
        float dv = dinv[v];
        __half o[8];
        o[0] = __float2half(dv * fmaxf(b0.x + dv * acc[0], 0.f));
        o[1] = __float2half(dv * fmaxf(b0.y + dv * acc[1], 0.f));
        o[2] = __float2half(dv * fmaxf(b0.z + dv * acc[2], 0.f));
        o[3] = __float2half(dv * fmaxf(b0.w + dv * acc[3], 0.f));
        o[4] = __float2half(dv * fmaxf(b1.x + dv * acc[4], 0.f));
        o[5] = __float2half(dv * fmaxf(b1.y + dv * acc[5], 0.f));
        o[6] = __float2half(dv * fmaxf(b1.z + dv * acc[6], 0.f));
        o[7] = __float2half(dv * fmaxf(b1.w + dv * acc[7], 0.f));
        *(float4*)&out[(size_t)v * D + l16 * 8] = *(float4*)o;
    }
}

// ---------------- Layer 3 pooled aggregation + tiny GEMM ----------------

__global__ __launch_bounds__(256) void agg_pool_kernel(const __half* __restrict__ Hs,
                                                       const float* __restrict__ dinv,
                                                       const int* __restrict__ rowstart,
                                                       const int* __restrict__ csr_src,
                                                       const float* __restrict__ is_n,
                                                       const int* __restrict__ batch,
                                                       float* __restrict__ P,
                                                       float* __restrict__ cg, int n) {
    int t = threadIdx.x;
    int wid = t >> 6, lane = t & 63;
    int g = lane >> 4, l16 = lane & 15;
    int v = blockIdx.x * 16 + wid * 4 + g;     // n divisible by 16
    float w_is = is_n[v];
    if (__ballot(w_is != 0.f) == 0ULL) return; // wave-uniform exit
    if (w_is != 0.f) {
        int e0 = rowstart[v], e1 = rowstart[v + 1];
        float acc[8];
        gather_grp(Hs, csr_src, v, e0, e1, l16, acc);
        float s = w_is * dinv[v];
        int gr = batch[v];
        float* pb = &P[(size_t)gr * D + l16 * 8];
#pragma unroll
        for (int k = 0; k < 8; k++) atomicAdd(&pb[k], s * acc[k]);
        if (l16 == 0) atomicAdd(&cg[gr], w_is);
    }
}

__global__ __launch_bounds__(64) void pool_gemm_kernel(const float* __restrict__ P,
                                                       const float* __restrict__ cg,
                                                       const float* __restrict__ W,
                                                       const float* __restrict__ b,
                                                       float* __restrict__ out, int G) {
    int g = blockIdx.x;
    if (g >= G) return;
    int c = threadIdx.x * 2;
    float2 acc = {0.f, 0.f};
    const float* pr = &P[(size_t)g * D];
#pragma unroll 4
    for (int k = 0; k < D; k++) {
        float pk = pr[k];
        float2 w = *(const float2*)&W[k * D + c];
        acc.x += pk * w.x;
        acc.y += pk * w.y;
    }
    float s = 0.5f * cg[g];
    float2 bb = *(const float2*)&b[c];
    out[(size_t)g * D + c]     = 0.5f * acc.x + s * bb.x;
    out[(size_t)g * D + c + 1] = 0.5f * acc.y + s * bb.y;
}

// ---------------- launch ----------------

extern "C" void kernel_launch(void* const* d_in, const int* in_sizes, int n_in,
                              void* d_out, int out_size, void* d_ws, size_t ws_size,
                              hipStream_t stream) {
    const float* x     = (const float*)d_in[0];
    const int*   edge  = (const int*)d_in[1];
    const float* is_n  = (const float*)d_in[2];
    const int*   batch = (const int*)d_in[3];
    const float* W1 = (const float*)d_in[4];
    const float* b1 = (const float*)d_in[5];
    const float* W2 = (const float*)d_in[6];
    const float* b2 = (const float*)d_in[7];
    const float* W3 = (const float*)d_in[8];
    const float* b3 = (const float*)d_in[9];
    float* out = (float*)d_out;

    int n = in_sizes[0] / D;       // 50000
    int E = in_sizes[1] / 2;       // 600000
    int G = out_size / D;          // 500
    const int* esrc = edge;
    const int* edst = edge + E;

    char* p = (char*)d_ws;
    __half* xw = (__half*)p;     p += (size_t)n * D * sizeof(float);
    __half* h  = (__half*)p;     p += (size_t)n * D * sizeof(float);
    float* dinv = (float*)p;     p += (size_t)n * sizeof(float);
    int* rowstart = (int*)p;     p += (size_t)(n + 1) * sizeof(int);
    int* cursor = (int*)p;       p += (size_t)n * sizeof(int);
    int* csr_src = (int*)p;      p += (size_t)E * sizeof(int);
    int* bsum_c = (int*)p;       p += 256 * sizeof(int);
    int* bsum_m = (int*)p;       p += 256 * sizeof(int);
    int* boff_c = (int*)p;       p += 256 * sizeof(int);
    int* boff_m = (int*)p;       p += 256 * sizeof(int);
    int* act = (int*)p;          p += (size_t)n * sizeof(int);
    int* na = (int*)p;           p += 4 * sizeof(int);
    __half* Wp = (__half*)p;     p += (size_t)3 * D * D * sizeof(__half);
    // contiguous zero-init region: cnt | mark | P | cg
    int* cnt = (int*)p;          p += (size_t)n * sizeof(int);
    int* mark = (int*)p;         p += (size_t)n * sizeof(int);
    float* P = (float*)p;        p += (size_t)G * D * sizeof(float);
    float* cg = (float*)p;       p += (size_t)G * sizeof(float);
    size_t zbytes = (size_t)(2 * n) * sizeof(int) + (size_t)(G * D + G) * sizeof(float);

    int PB = (n + 255) / 256;

    hipMemsetAsync(cnt, 0, zbytes, stream);
    packw_kernel<<<24, 256, 0, stream>>>(W1, W2, W3, Wp);
    count_kernel<<<(E + 255) / 256, 256, 0, stream>>>(esrc, edst, is_n, cnt, mark, E);
    psumB_kernel<<<PB, 256, 0, stream>>>(cnt, mark, is_n, bsum_c, bsum_m, n);
    bscanB_kernel<<<1, 256, 0, stream>>>(bsum_c, bsum_m, boff_c, boff_m, na, PB);
    finB_kernel<<<PB, 256, 0, stream>>>(cnt, mark, is_n, boff_c, boff_m,
                                        rowstart, cursor, dinv, act, n, E);
    fill_kernel<<<(E + 255) / 256, 256, 0, stream>>>(esrc, edst, cursor, csr_src, E);

    // Layer 1: xw1s = dinv * (x @ W1)
    gemm_mfma_kernel<float><<<512, 256, 0, stream>>>(x, Wp, dinv, xw, n);
    // Fused layer-1 agg + layer-2 GEMM: h <- xw2s = dinv * (h1 @ W2)
    agg_gemm_kernel<<<n / 16, 256, 0, stream>>>(xw, b1, dinv, rowstart, csr_src,
                                                Wp + D * D, h);
    // Layer 2 aggregation at active nodes: xw <- h2s (pre-scaled)
    agg_act_kernel<<<1024, 256, 0, stream>>>(h, b2, dinv, rowstart, csr_src, act, na, xw);
    // Layer 3: pooled aggregation of h2s, then tiny 500x128 GEMM
    agg_pool_kernel<<<n / 16, 256, 0, stream>>>(xw, dinv, rowstart, csr_src,
                                                is_n, batch, P, cg, n);
    pool_gemm_kernel<<<G, 64, 0, stream>>>(P, cg, W3, b3, out, G);
}

// Round 11
// 166.629 us; speedup vs baseline: 2.8929x; 1.0028x over previous
//
#include <hip/hip_runtime.h>
#include <hip/hip_fp16.h>
#include <type_traits>

#define D 128

typedef __attribute__((ext_vector_type(8))) _Float16 f16x8;
typedef __attribute__((ext_vector_type(4))) float f32x4;

// ---------------- CSR build ----------------

// count in-degree; mark src of edges whose dst is a neighbor-node (bitmap test)
__global__ void count_kernel(const int* __restrict__ src, const int* __restrict__ dst,
                             const unsigned int* __restrict__ bm,
                             int* __restrict__ cnt, int* __restrict__ mark, int E) {
    int e = blockIdx.x * blockDim.x + threadIdx.x;
    if (e < E) {
        int d = dst[e];
        atomicAdd(&cnt[d], 1);
        if ((bm[d >> 5] >> (d & 31)) & 1u) mark[src[e]] = 1;
    }
}

// block sums of padded cnt ((c+3)&~3) AND of (mark|is_n)
__global__ __launch_bounds__(256) void psumB_kernel(const int* __restrict__ cnt,
                                                    const int* __restrict__ mark,
                                                    const float* __restrict__ is_n,
                                                    int* __restrict__ bsum_c,
                                                    int* __restrict__ bsum_m, int n) {
    __shared__ int s[256], s2[256];
    int t = threadIdx.x;
    int i = blockIdx.x * 256 + t;
    int c = (i < n) ? cnt[i] : 0;
    s[t] = (c + 3) & ~3;
    s2[t] = (i < n) ? (mark[i] | (is_n[i] != 0.f ? 1 : 0)) : 0;
    __syncthreads();
    for (int off = 128; off > 0; off >>= 1) {
        if (t < off) { s[t] += s[t + off]; s2[t] += s2[t + off]; }
        __syncthreads();
    }
    if (t == 0) { bsum_c[blockIdx.x] = s[0]; bsum_m[blockIdx.x] = s2[0]; }
}

// exclusive scans; na[0]=total marks, na[1]=total padded edges
__global__ __launch_bounds__(256) void bscanB_kernel(const int* __restrict__ bsum_c,
                                                     const int* __restrict__ bsum_m,
                                                     int* __restrict__ boff_c,
                                                     int* __restrict__ boff_m,
                                                     int* __restrict__ na, int PB) {
    __shared__ int s[256];
    int t = threadIdx.x;
    int v = (t < PB) ? bsum_c[t] : 0;
    s[t] = v;
    __syncthreads();
    for (int off = 1; off < 256; off <<= 1) {
        int add = (t >= off) ? s[t - off] : 0;
        __syncthreads();
        s[t] += add;
        __syncthreads();
    }
    if (t < PB) boff_c[t] = s[t] - v;
    if (t == PB - 1) na[1] = s[t];
    __syncthreads();
    int v2 = (t < PB) ? bsum_m[t] : 0;
    s[t] = v2;
    __syncthreads();
    for (int off = 1; off < 256; off <<= 1) {
        int add = (t >= off) ? s[t - off] : 0;
        __syncthreads();
        s[t] += add;
        __syncthreads();
    }
    if (t < PB) boff_m[t] = s[t] - v2;
    if (t == PB - 1) na[0] = s[t];
}

__global__ __launch_bounds__(256) void finB_kernel(const int* __restrict__ cnt,
                                                   const int* __restrict__ mark,
                                                   const float* __restrict__ is_n,
                                                   const int* __restrict__ boff_c,
                                                   const int* __restrict__ boff_m,
                                                   const int* __restrict__ na,
                                                   int* __restrict__ rowstart,
                                                   int* __restrict__ cursor,
                                                   float* __restrict__ dinv,
                                                   int* __restrict__ act, int n) {
    __shared__ int s[256];
    int t = threadIdx.x;
    int i = blockIdx.x * 256 + t;
    int c = (i < n) ? cnt[i] : 0;
    int c4 = (c + 3) & ~3;
    s[t] = c4;
    __syncthreads();
    for (int off = 1; off < 256; off <<= 1) {
        int add = (t >= off) ? s[t - off] : 0;
        __syncthreads();
        s[t] += add;
        __syncthreads();
    }
    if (i < n) {
        int excl = s[t] - c4 + boff_c[blockIdx.x];
        rowstart[i] = excl;
        cursor[i] = excl;
        dinv[i] = rsqrtf(1.0f + (float)c);
    }
    if (i == 0) rowstart[n] = na[1];
    __syncthreads();
    int m = (i < n) ? (mark[i] | (is_n[i] != 0.f ? 1 : 0)) : 0;
    s[t] = m;
    __syncthreads();
    for (int off = 1; off < 256; off <<= 1) {
        int add = (t >= off) ? s[t - off] : 0;
        __syncthreads();
        s[t] += add;
        __syncthreads();
    }
    if (m) act[s[t] - 1 + boff_m[blockIdx.x]] = i;
}

__global__ void fill_kernel(const int* __restrict__ src, const int* __restrict__ dst,
                            int* __restrict__ cursor, int* __restrict__ csr_src, int E) {
    int e = blockIdx.x * blockDim.x + threadIdx.x;
    if (e < E) {
        int d = dst[e];
        int pos = atomicAdd(&cursor[d], 1);
        csr_src[pos] = src[e];
    }
}

// fill padded slots with sentinel node n (zero row)
__global__ void pad_kernel(const int* __restrict__ cursor,
                           const int* __restrict__ rowstart,
                           int* __restrict__ csr_src, int n) {
    int v = blockIdx.x * blockDim.x + threadIdx.x;
    if (v < n) {
        int p = cursor[v], pe = rowstart[v + 1];
        for (; p < pe; p++) csr_src[p] = n;   // <=3 iterations
    }
}

// ---------------- W pack + is_n bitmap + sentinel-row zeroing ----------------

__global__ __launch_bounds__(256) void packw_kernel(const float* __restrict__ W1,
                                                    const float* __restrict__ W2,
                                                    const float* __restrict__ W3,
                                                    __half* __restrict__ Wp,
                                                    const float* __restrict__ is_n,
                                                    unsigned int* __restrict__ bm,
                                                    __half* __restrict__ xw,
                                                    __half* __restrict__ h, int n) {
    int gid = blockIdx.x * 256 + threadIdx.x;
    if (gid < 6144) {
        int m = gid >> 11;
        int idx = gid & 2047;
        const float* W = (m == 0) ? W1 : (m == 1) ? W2 : W3;
        int l = idx & 63;
        int nt = (idx >> 6) & 7;
        int ks = idx >> 9;
        int kb = ks * 32 + (l >> 4) * 8;
        int col = nt * 16 + (l & 15);
        __half tmp[8];
#pragma unroll
        for (int j = 0; j < 8; j++) tmp[j] = __float2half(W[(kb + j) * D + col]);
        *(float4*)&Wp[(size_t)gid * 8] = *(float4*)tmp;
    } else if (gid < 6144 + 1563) {
        int w = gid - 6144;                 // bitmap word: nodes 32w..32w+31
        unsigned int bits = 0;
        int base = w << 5;
#pragma unroll 4
        for (int k = 0; k < 32; k++) {
            int i = base + k;
            if (i < n && is_n[i] != 0.f) bits |= (1u << k);
        }
        bm[w] = bits;
    } else if (gid < 6144 + 1563 + 16) {    // zero sentinel row of xw
        int k = gid - (6144 + 1563);
        float4 z = {0.f, 0.f, 0.f, 0.f};
        *(float4*)&xw[(size_t)n * D + k * 8] = z;
    } else if (gid < 6144 + 1563 + 32) {    // zero sentinel row of h
        int k = gid - (6144 + 1563 + 16);
        float4 z = {0.f, 0.f, 0.f, 0.f};
        *(float4*)&h[(size_t)n * D + k * 8] = z;
    }
}

// ---------------- MFMA GEMM: Y[M,128](fp16) = dinv[r] * (X[M,128] @ W) ----------------

template <typename AT>
__global__ __launch_bounds__(256, 2) void gemm_mfma_kernel(const AT* __restrict__ X,
                                                           const __half* __restrict__ Wp,
                                                           const float* __restrict__ dinv,
                                                           __half* __restrict__ Y, int M) {
    int lane = threadIdx.x & 63;
    int wid = threadIdx.x >> 6;
    f16x8 bf[4][8];
    {
        const float4* wp = (const float4*)Wp;
#pragma unroll
        for (int ks = 0; ks < 4; ks++)
#pragma unroll
            for (int nt = 0; nt < 8; nt++) {
                float4 t = wp[(ks * 8 + nt) * 64 + lane];
                bf[ks][nt] = *(f16x8*)&t;
            }
    }
    int row_l = lane & 15;
    int kgrp = lane >> 4;
    int tiles = M >> 4;
    int nw = gridDim.x * 4;
    for (int tile = blockIdx.x * 4 + wid; tile < tiles; tile += nw) {
        int row0 = tile << 4;
        const AT* ap = X + (size_t)(row0 + row_l) * D + kgrp * 8;
        f32x4 acc[8];
#pragma unroll
        for (int nt = 0; nt < 8; nt++) acc[nt] = (f32x4){0.f, 0.f, 0.f, 0.f};
#pragma unroll
        for (int ks = 0; ks < 4; ks++) {
            f16x8 a;
            if constexpr (std::is_same<AT, float>::value) {
                float4 a0 = *(const float4*)(ap + ks * 32);
                float4 a1 = *(const float4*)(ap + ks * 32 + 4);
                a[0] = (_Float16)a0.x; a[1] = (_Float16)a0.y;
                a[2] = (_Float16)a0.z; a[3] = (_Float16)a0.w;
                a[4] = (_Float16)a1.x; a[5] = (_Float16)a1.y;
                a[6] = (_Float16)a1.z; a[7] = (_Float16)a1.w;
            } else {
                float4 t = *(const float4*)(const void*)(ap + ks * 32);
                a = *(f16x8*)&t;
            }
#pragma unroll
            for (int nt = 0; nt < 8; nt++)
                acc[nt] = __builtin_amdgcn_mfma_f32_16x16x32_f16(a, bf[ks][nt],
                                                                 acc[nt], 0, 0, 0);
        }
        float ds[4];
#pragma unroll
        for (int r = 0; r < 4; r++) ds[r] = dinv[row0 + kgrp * 4 + r];
        __half* yb = Y + (size_t)row0 * D;
#pragma unroll
        for (int nt = 0; nt < 8; nt++)
#pragma unroll
            for (int r = 0; r < 4; r++)
                yb[(size_t)(kgrp * 4 + r) * D + nt * 16 + row_l] =
                    __float2half(ds[r] * acc[nt][r]);
    }
}

// ---------------- padded group-gather: one node per 16-lane group ----------------
// Padded CSR (deg multiple of 4, sentinel n -> zero row): uniform int4 index
// load + 4 independent float4 row loads per iteration; unroll 2 -> 8 in flight.

__device__ __forceinline__ void gather_grp(const __half* __restrict__ XWs,
                                           const int* __restrict__ csr,
                                           int v, int e0, int e1, int l16,
                                           float acc[8]) {
    float4 rs = ((const float4*)(XWs + (size_t)v * D))[l16];   // self, issued early
#pragma unroll
    for (int k = 0; k < 8; k++) acc[k] = 0.f;
#pragma unroll 2
    for (int j = e0; j < e1; j += 4) {
        int4 u = *(const int4*)&csr[j];
        float4 r0 = ((const float4*)(XWs + (size_t)u.x * D))[l16];
        float4 r1 = ((const float4*)(XWs + (size_t)u.y * D))[l16];
        float4 r2 = ((const float4*)(XWs + (size_t)u.z * D))[l16];
        float4 r3 = ((const float4*)(XWs + (size_t)u.w * D))[l16];
        const __half2* a0 = (const __half2*)&r0;
        const __half2* a1 = (const __half2*)&r1;
        const __half2* a2 = (const __half2*)&r2;
        const __half2* a3 = (const __half2*)&r3;
#pragma unroll
        for (int k = 0; k < 4; k++) {
            float2 f0 = __half22float2(a0[k]);
            float2 f1 = __half22float2(a1[k]);
            float2 f2 = __half22float2(a2[k]);
            float2 f3 = __half22float2(a3[k]);
            acc[2 * k]     += (f0.x + f1.x) + (f2.x + f3.x);
            acc[2 * k + 1] += (f0.y + f1.y) + (f2.y + f3.y);
        }
    }
    const __half2* as = (const __half2*)&rs;
#pragma unroll
    for (int k = 0; k < 4; k++) {
        float2 f = __half22float2(as[k]);
        acc[2 * k] += f.x;
        acc[2 * k + 1] += f.y;
    }
}

// ---------------- Fused layer-1 aggregation + layer-2 GEMM ----------------

__global__ __launch_bounds__(256) void agg_gemm_kernel(const __half* __restrict__ XWs,
                                                       const float* __restrict__ bias,
                                                       const float* __restrict__ dinv,
                                                       const int* __restrict__ rowstart,
                                                       const int* __restrict__ csr_src,
                                                       const __half* __restrict__ Wp2,
                                                       __half* __restrict__ Y) {
    __shared__ __half hs[16][136];     // +8 pad
    int t = threadIdx.x;
    int wid = t >> 6, lane = t & 63;
    int g = lane >> 4, l16 = lane & 15;
    int block0 = blockIdx.x * 16;
    int v = block0 + wid * 4 + g;       // per-group node (n divisible by 16)
    int e0 = rowstart[v], e1 = rowstart[v + 1];
    float acc[8];
    gather_grp(XWs, csr_src, v, e0, e1, l16, acc);
    float dv = dinv[v];
    float4 b0 = ((const float4*)bias)[l16 * 2];
    float4 b1 = ((const float4*)bias)[l16 * 2 + 1];
    __half o[8];
    o[0] = __float2half(fmaxf(b0.x + dv * acc[0], 0.f));
    o[1] = __float2half(fmaxf(b0.y + dv * acc[1], 0.f));
    o[2] = __float2half(fmaxf(b0.z + dv * acc[2], 0.f));
    o[3] = __float2half(fmaxf(b0.w + dv * acc[3], 0.f));
    o[4] = __float2half(fmaxf(b1.x + dv * acc[4], 0.f));
    o[5] = __float2half(fmaxf(b1.y + dv * acc[5], 0.f));
    o[6] = __float2half(fmaxf(b1.z + dv * acc[6], 0.f));
    o[7] = __float2half(fmaxf(b1.w + dv * acc[7], 0.f));
    *(float4*)&hs[wid * 4 + g][l16 * 8] = *(float4*)o;
    f16x8 bf[4][2];
    {
        const float4* wp = (const float4*)Wp2;
#pragma unroll
        for (int ks = 0; ks < 4; ks++)
#pragma unroll
            for (int j = 0; j < 2; j++) {
                float4 tmp = wp[(ks * 8 + wid * 2 + j) * 64 + lane];
                bf[ks][j] = *(f16x8*)&tmp;
            }
    }
    __syncthreads();
    int row_l = l16, kgrp = g;
    f32x4 acc2[2];
    acc2[0] = (f32x4){0.f, 0.f, 0.f, 0.f};
    acc2[1] = (f32x4){0.f, 0.f, 0.f, 0.f};
#pragma unroll
    for (int ks = 0; ks < 4; ks++) {
        f16x8 a = *(f16x8*)&hs[row_l][ks * 32 + kgrp * 8];
#pragma unroll
        for (int j = 0; j < 2; j++)
            acc2[j] = __builtin_amdgcn_mfma_f32_16x16x32_f16(a, bf[ks][j],
                                                             acc2[j], 0, 0, 0);
    }
    float ds[4];
#pragma unroll
    for (int r = 0; r < 4; r++) ds[r] = dinv[block0 + kgrp * 4 + r];
    __half* yb = Y + (size_t)block0 * D;
#pragma unroll
    for (int j = 0; j < 2; j++)
#pragma unroll
        for (int r = 0; r < 4; r++)
            yb[(size_t)(kgrp * 4 + r) * D + (wid * 2 + j) * 16 + row_l] =
                __float2half(ds[r] * acc2[j][r]);
}

// ---------------- Aggregation (active set): h2s = dinv * relu(b + dinv*sum) ----------------

__global__ __launch_bounds__(256) void agg_act_kernel(const __half* __restrict__ XWs,
                                                      const float* __restrict__ bias,
                                                      const float* __restrict__ dinv,
                                                      const int* __restrict__ rowstart,
                                                      const int* __restrict__ csr_src,
                                                      const int* __restrict__ act,
                                                      const int* __restrict__ na_p,
                                                      __half* __restrict__ out) {
    int t = threadIdx.x;
    int wid = t >> 6, lane = t & 63;
    int g = lane >> 4, l16 = lane & 15;
    int na = na_p[0];
    int stride = gridDim.x * 16;
    float4 b0 = ((const float4*)bias)[l16 * 2];
    float4 b1 = ((const float4*)bias)[l16 * 2 + 1];
    for (int i = blockIdx.x * 16 + wid * 4 + g; i < na; i += stride) {
        int v = act[i];
        int e0 = rowstart[v], e1 = rowstart[v + 1];
        float acc[8];
        gather_grp(XWs, csr_src, v, e0, e1, l16, acc);
        float dv = dinv[v];
        __half o[8];
        o[0] = __float2half(dv * fmaxf(b0.x + dv * acc[0], 0.f));
        o[1] = __float2half(dv * fmaxf(b0.y + dv * acc[1], 0.f));
        o[2] = __float2half(dv * fmaxf(b0.z + dv * acc[2], 0.f));
        o[3] = __float2half(dv * fmaxf(b0.w + dv * acc[3], 0.f));
        o[4] = __float2half(dv * fmaxf(b1.x + dv * acc[4], 0.f));
        o[5] = __float2half(dv * fmaxf(b1.y + dv * acc[5], 0.f));
        o[6] = __float2half(dv * fmaxf(b1.z + dv * acc[6], 0.f));
        o[7] = __float2half(dv * fmaxf(b1.w + dv * acc[7], 0.f));
        *(float4*)&out[(size_t)v * D + l16 * 8] = *(float4*)o;
    }
}

// ---------------- Layer 3 pooled aggregation + tiny GEMM ----------------

__global__ __launch_bounds__(256) void agg_pool_kernel(const __half* __restrict__ Hs,
                                                       const float* __restrict__ dinv,
                                                       const int* __restrict__ rowstart,
                                                       const int* __restrict__ csr_src,
                                                       const float* __restrict__ is_n,
                                                       const int* __restrict__ batch,
                                                       float* __restrict__ P,
                                                       float* __restrict__ cg, int n) {
    int t = threadIdx.x;
    int wid = t >> 6, lane = t & 63;
    int g = lane >> 4, l16 = lane & 15;
    int v = blockIdx.x * 16 + wid * 4 + g;     // n divisible by 16
    float w_is = is_n[v];
    if (__ballot(w_is != 0.f) == 0ULL) return; // wave-uniform exit
    if (w_is != 0.f) {
        int e0 = rowstart[v], e1 = rowstart[v + 1];
        float acc[8];
        gather_grp(Hs, csr_src, v, e0, e1, l16, acc);
        float s = w_is * dinv[v];
        int gr = batch[v];
        float* pb = &P[(size_t)gr * D + l16 * 8];
#pragma unroll
        for (int k = 0; k < 8; k++) atomicAdd(&pb[k], s * acc[k]);
        if (l16 == 0) atomicAdd(&cg[gr], w_is);
    }
}

__global__ __launch_bounds__(64) void pool_gemm_kernel(const float* __restrict__ P,
                                                       const float* __restrict__ cg,
                                                       const float* __restrict__ W,
                                                       const float* __restrict__ b,
                                                       float* __restrict__ out, int G) {
    int g = blockIdx.x;
    if (g >= G) return;
    int c = threadIdx.x * 2;
    float2 acc = {0.f, 0.f};
    const float* pr = &P[(size_t)g * D];
#pragma unroll 4
    for (int k = 0; k < D; k++) {
        float pk = pr[k];
        float2 w = *(const float2*)&W[k * D + c];
        acc.x += pk * w.x;
        acc.y += pk * w.y;
    }
    float s = 0.5f * cg[g];
    float2 bb = *(const float2*)&b[c];
    out[(size_t)g * D + c]     = 0.5f * acc.x + s * bb.x;
    out[(size_t)g * D + c + 1] = 0.5f * acc.y + s * bb.y;
}

// ---------------- launch ----------------

extern "C" void kernel_launch(void* const* d_in, const int* in_sizes, int n_in,
                              void* d_out, int out_size, void* d_ws, size_t ws_size,
                              hipStream_t stream) {
    const float* x     = (const float*)d_in[0];
    const int*   edge  = (const int*)d_in[1];
    const float* is_n  = (const float*)d_in[2];
    const int*   batch = (const int*)d_in[3];
    const float* W1 = (const float*)d_in[4];
    const float* b1 = (const float*)d_in[5];
    const float* W2 = (const float*)d_in[6];
    const float* b2 = (const float*)d_in[7];
    const float* W3 = (const float*)d_in[8];
    const float* b3 = (const float*)d_in[9];
    float* out = (float*)d_out;

    int n = in_sizes[0] / D;       // 50000
    int E = in_sizes[1] / 2;       // 600000
    int G = out_size / D;          // 500
    const int* esrc = edge;
    const int* edst = edge + E;

    char* p = (char*)d_ws;
    __half* xw = (__half*)p;     p += (size_t)n * D * sizeof(float);   // (n+1) rows used
    __half* h  = (__half*)p;     p += (size_t)n * D * sizeof(float);   // (n+1) rows used
    float* dinv = (float*)p;     p += (size_t)n * sizeof(float);
    int* rowstart = (int*)p;     p += (size_t)(n + 1) * sizeof(int);
    int* cursor = (int*)p;       p += (size_t)n * sizeof(int);
    int* csr_src = (int*)p;      p += ((size_t)E + 3 * n) * sizeof(int);  // padded
    int* bsum_c = (int*)p;       p += 256 * sizeof(int);
    int* bsum_m = (int*)p;       p += 256 * sizeof(int);
    int* boff_c = (int*)p;       p += 256 * sizeof(int);
    int* boff_m = (int*)p;       p += 256 * sizeof(int);
    int* act = (int*)p;          p += (size_t)n * sizeof(int);
    int* na = (int*)p;           p += 4 * sizeof(int);
    __half* Wp = (__half*)p;     p += (size_t)3 * D * D * sizeof(__half);
    unsigned int* bm = (unsigned int*)p; p += 1600 * sizeof(unsigned int);
    // contiguous zero-init region: cnt | mark | P | cg
    int* cnt = (int*)p;          p += (size_t)n * sizeof(int);
    int* mark = (int*)p;         p += (size_t)n * sizeof(int);
    float* P = (float*)p;        p += (size_t)G * D * sizeof(float);
    float* cg = (float*)p;       p += (size_t)G * sizeof(float);
    size_t zbytes = (size_t)(2 * n) * sizeof(int) + (size_t)(G * D + G) * sizeof(float);

    int PB = (n + 255) / 256;

    hipMemsetAsync(cnt, 0, zbytes, stream);
    packw_kernel<<<31, 256, 0, stream>>>(W1, W2, W3, Wp, is_n, bm, xw, h, n);
    count_kernel<<<(E + 255) / 256, 256, 0, stream>>>(esrc, edst, bm, cnt, mark, E);
    psumB_kernel<<<PB, 256, 0, stream>>>(cnt, mark, is_n, bsum_c, bsum_m, n);
    bscanB_kernel<<<1, 256, 0, stream>>>(bsum_c, bsum_m, boff_c, boff_m, na, PB);
    finB_kernel<<<PB, 256, 0, stream>>>(cnt, mark, is_n, boff_c, boff_m, na,
                                        rowstart, cursor, dinv, act, n);
    fill_kernel<<<(E + 255) / 256, 256, 0, stream>>>(esrc, edst, cursor, csr_src, E);
    pad_kernel<<<PB, 256, 0, stream>>>(cursor, rowstart, csr_src, n);

    // Layer 1: xw1s = dinv * (x @ W1)
    gemm_mfma_kernel<float><<<512, 256, 0, stream>>>(x, Wp, dinv, xw, n);
    // Fused layer-1 agg + layer-2 GEMM: h <- xw2s = dinv * (h1 @ W2)
    agg_gemm_kernel<<<n / 16, 256, 0, stream>>>(xw, b1, dinv, rowstart, csr_src,
                                                Wp + D * D, h);
    // Layer 2 aggregation at active nodes: xw <- h2s (pre-scaled)
    agg_act_kernel<<<1024, 256, 0, stream>>>(h, b2, dinv, rowstart, csr_src, act, na, xw);
    // Layer 3: pooled aggregation of h2s, then tiny 500x128 GEMM
    agg_pool_kernel<<<n / 16, 256, 0, stream>>>(xw, dinv, rowstart, csr_src,
                                                is_n, batch, P, cg, n);
    pool_gemm_kernel<<<G, 64, 0, stream>>>(P, cg, W3, b3, out, G);
}